// Round 13
// baseline (782.309 us; speedup 1.0000x reference)
//
#include <hip/hip_runtime.h>
#include <hip/hip_bf16.h>
#include <math.h>

// ---------------------------------------------------------------------------
// Problem constants
// ---------------------------------------------------------------------------
#define NNODES 100000
#define NEDGES 400000
#define NB     1024
#define SEQ    1000
#define HID    300
#define NBLK1  ((NNODES + 255) / 256)   // 391

typedef __attribute__((ext_vector_type(8))) short short8;   // 8 bf16 (4 VGPRs)
typedef __attribute__((ext_vector_type(4))) float f32x4;    // MFMA acc

__device__ __forceinline__ float bf_lo(unsigned int v) { return __uint_as_float(v << 16); }
__device__ __forceinline__ float bf_hi(unsigned int v) { return __uint_as_float(v & 0xffff0000u); }
__device__ __forceinline__ unsigned int bf_pack(float lo, float hi) {
    __hip_bfloat16 a = __float2bfloat16(lo), b = __float2bfloat16(hi);
    unsigned short ua = *(unsigned short*)&a, ub = *(unsigned short*)&b;
    return (unsigned int)ua | ((unsigned int)ub << 16);
}

// ---------------------------------------------------------------------------
// fp32 [M][K] -> bf16 [M][Kpad] (zero-padded)
// ---------------------------------------------------------------------------
__global__ void cvt_pad_kernel(const float* __restrict__ in, __hip_bfloat16* __restrict__ out,
                               int M, int K, int Kpad)
{
    long idx = (long)blockIdx.x * 256 + threadIdx.x;
    if (idx >= (long)M * Kpad) return;
    int m = idx / Kpad, k = idx % Kpad;
    out[idx] = __float2bfloat16(k < K ? in[(long)m * K + k] : 0.f);
}

// fp32 [K][N] row-major -> bf16 Bt [N][Kpad] (zero-padded)
__global__ void transpose_cvt_kernel(const float* __restrict__ in, __hip_bfloat16* __restrict__ out,
                                     int K, int N, int Kpad)
{
    long idx = (long)blockIdx.x * 256 + threadIdx.x;
    if (idx >= (long)N * Kpad) return;
    int n = idx / Kpad, k = idx % Kpad;
    out[idx] = __float2bfloat16(k < K ? in[(long)k * N + n] : 0.f);
}

// Batched weight transpose: 12 descriptors in one launch
struct TBatch {
    const float* src[12];
    __hip_bfloat16* dst[12];
    int K[12]; int N[12]; int Kpad[12];
    int bstart[13];
};

__global__ __launch_bounds__(256) void transpose_batch_kernel(TBatch tb)
{
    int blk = blockIdx.x;
    int d = 0;
    while (d < 11 && blk >= tb.bstart[d + 1]) ++d;
    long idx = (long)(blk - tb.bstart[d]) * 256 + threadIdx.x;
    long tot = (long)tb.N[d] * tb.Kpad[d];
    if (idx >= tot) return;
    int Kpad = tb.Kpad[d];
    int n = idx / Kpad, k = idx % Kpad;
    tb.dst[d][idx] = __float2bfloat16(k < tb.K[d] ? tb.src[d][(long)k * tb.N[d] + n] : 0.f);
}

// bias fold from TRANSPOSED bf16 weights: out[n] = sum_k b[k] * Wt[n][k]
__global__ __launch_bounds__(256) void bias_fold_t_kernel(
    const float* __restrict__ b, const __hip_bfloat16* __restrict__ Wt,
    float* __restrict__ out, int K, int Kpad, int N)
{
    int n = blockIdx.x;
    if (n >= N) return;
    __shared__ float red[256];
    int tid = threadIdx.x;
    float s = 0.f;
    for (int k = tid; k < K; k += 256)
        s += b[k] * __bfloat162float(Wt[(size_t)n * Kpad + k]);
    red[tid] = s;
    __syncthreads();
    #pragma unroll
    for (int st = 128; st > 0; st >>= 1) {
        if (tid < st) red[tid] += red[tid + st];
        __syncthreads();
    }
    if (tid == 0) out[n] = red[0];
}

// ---------------------------------------------------------------------------
// BF16 MFMA GEMM (TN), 64x64 tile: C = act(A @ Bt^T + bias)
// ---------------------------------------------------------------------------
__global__ __launch_bounds__(256) void gemm_bf16_kernel(
    const __hip_bfloat16* __restrict__ A, const __hip_bfloat16* __restrict__ Bt,
    const float* __restrict__ bias, void* __restrict__ C,
    int M, int N, int Kpad, int lda, int ldc, int Npad_out,
    int relu, int outbf, int chunk)
{
    __shared__ __align__(16) __hip_bfloat16 As[64][40];
    __shared__ __align__(16) __hip_bfloat16 Bs[64][40];
    int tid = threadIdx.x;
    int wave = tid >> 6, lane = tid & 63;
    int wm = wave >> 1, wn = wave & 1;
    int quad = lane >> 4, l16 = lane & 15;
    int row0 = blockIdx.y * 64, col0 = blockIdx.x * 64;

    int kbeg = 0, kend = Kpad;
    if (chunk > 0) { kbeg = blockIdx.z * chunk; kend = kbeg + chunk; if (kend > Kpad) kend = Kpad; }

    f32x4 acc[2][2];
    #pragma unroll
    for (int i = 0; i < 2; ++i)
        #pragma unroll
        for (int j = 0; j < 2; ++j) acc[i][j] = (f32x4){0.f, 0.f, 0.f, 0.f};

    int r = tid >> 2, cch = (tid & 3) * 8;

    for (int k0 = kbeg; k0 < kend; k0 += 32) {
        uint4 av = {0u, 0u, 0u, 0u};
        if (row0 + r < M) av = *(const uint4*)(A + (size_t)(row0 + r) * lda + k0 + cch);
        *(uint4*)(&As[r][cch]) = av;
        uint4 bv = {0u, 0u, 0u, 0u};
        if (col0 + r < N) bv = *(const uint4*)(Bt + (size_t)(col0 + r) * Kpad + k0 + cch);
        *(uint4*)(&Bs[r][cch]) = bv;
        __syncthreads();

        short8 a0 = *(const short8*)(&As[wm * 32 + l16][quad * 8]);
        short8 a1 = *(const short8*)(&As[wm * 32 + 16 + l16][quad * 8]);
        short8 b0 = *(const short8*)(&Bs[wn * 32 + l16][quad * 8]);
        short8 b1 = *(const short8*)(&Bs[wn * 32 + 16 + l16][quad * 8]);
        acc[0][0] = __builtin_amdgcn_mfma_f32_16x16x32_bf16(a0, b0, acc[0][0], 0, 0, 0);
        acc[0][1] = __builtin_amdgcn_mfma_f32_16x16x32_bf16(a0, b1, acc[0][1], 0, 0, 0);
        acc[1][0] = __builtin_amdgcn_mfma_f32_16x16x32_bf16(a1, b0, acc[1][0], 0, 0, 0);
        acc[1][1] = __builtin_amdgcn_mfma_f32_16x16x32_bf16(a1, b1, acc[1][1], 0, 0, 0);
        __syncthreads();
    }

    #pragma unroll
    for (int ti = 0; ti < 2; ++ti) {
        int rbase = row0 + wm * 32 + ti * 16 + quad * 4;
        #pragma unroll
        for (int tj = 0; tj < 2; ++tj) {
            int cc = col0 + wn * 32 + tj * 16 + l16;
            if (cc >= Npad_out) continue;
            #pragma unroll
            for (int reg = 0; reg < 4; ++reg) {
                int rr = rbase + reg;
                if (rr >= M) continue;
                float v = acc[ti][tj][reg];
                if (chunk > 0) {
                    if (cc < N) atomicAdd((float*)C + (size_t)rr * ldc + cc, v);
                } else {
                    float ov = 0.f;
                    if (cc < N) {
                        if (bias) v += bias[cc];
                        if (relu) v = fmaxf(v, 0.f);
                        ov = v;
                    }
                    if (outbf) ((__hip_bfloat16*)C)[(size_t)rr * ldc + cc] = __float2bfloat16(ov);
                    else       ((float*)C)[(size_t)rr * ldc + cc] = ov;
                }
            }
        }
    }
}

static void launch_gemm_bf16(const __hip_bfloat16* A, const __hip_bfloat16* Bt, const float* bias,
                             void* C, int M, int N, int Kpad, int lda, int ldc, int Npad_out,
                             int relu, int outbf, int splitz, hipStream_t stream)
{
    int cover = N > Npad_out ? N : Npad_out;
    int chunk = (splitz > 1) ? (Kpad / splitz) : 0;
    dim3 grid((cover + 63) / 64, (M + 63) / 64, splitz > 1 ? splitz : 1);
    gemm_bf16_kernel<<<grid, 256, 0, stream>>>(A, Bt, bias, C, M, N, Kpad, lda, ldc, Npad_out,
                                               relu, outbf, chunk);
}

// ---------------------------------------------------------------------------
// BF16 MFMA GEMM (TN), 128x64 tile, 2D grid (FG branch, M=13312)
// ---------------------------------------------------------------------------
__global__ __launch_bounds__(256) void gemm_mt_kernel(
    const __hip_bfloat16* __restrict__ A, const __hip_bfloat16* __restrict__ Bt,
    const float* __restrict__ bias, __hip_bfloat16* __restrict__ C,
    int M, int N, int Kpad, int lda, int ldc, int Npad_out, int relu)
{
    __shared__ __align__(16) __hip_bfloat16 As[128][40];
    __shared__ __align__(16) __hip_bfloat16 Bs[64][40];
    int tid = threadIdx.x;
    int wave = tid >> 6, lane = tid & 63;
    int wm = wave >> 1, wn = wave & 1;
    int quad = lane >> 4, l16 = lane & 15;
    int row0 = blockIdx.y * 128, col0 = blockIdx.x * 64;

    f32x4 acc[4][2];
    #pragma unroll
    for (int i = 0; i < 4; ++i)
        #pragma unroll
        for (int j = 0; j < 2; ++j) acc[i][j] = (f32x4){0.f, 0.f, 0.f, 0.f};

    int r = tid >> 2, cch = (tid & 3) * 8;

    for (int k0 = 0; k0 < Kpad; k0 += 32) {
        uint4 av0 = {0u, 0u, 0u, 0u}, av1 = {0u, 0u, 0u, 0u}, bv = {0u, 0u, 0u, 0u};
        if (row0 + r < M)      av0 = *(const uint4*)(A + (size_t)(row0 + r) * lda + k0 + cch);
        if (row0 + r + 64 < M) av1 = *(const uint4*)(A + (size_t)(row0 + r + 64) * lda + k0 + cch);
        if (col0 + r < N)      bv  = *(const uint4*)(Bt + (size_t)(col0 + r) * Kpad + k0 + cch);
        *(uint4*)(&As[r][cch]) = av0;
        *(uint4*)(&As[r + 64][cch]) = av1;
        *(uint4*)(&Bs[r][cch]) = bv;
        __syncthreads();

        short8 af[4], bfr[2];
        #pragma unroll
        for (int i = 0; i < 4; ++i)
            af[i] = *(const short8*)(&As[wm * 64 + i * 16 + l16][quad * 8]);
        #pragma unroll
        for (int j = 0; j < 2; ++j)
            bfr[j] = *(const short8*)(&Bs[wn * 32 + j * 16 + l16][quad * 8]);
        #pragma unroll
        for (int i = 0; i < 4; ++i)
            #pragma unroll
            for (int j = 0; j < 2; ++j)
                acc[i][j] = __builtin_amdgcn_mfma_f32_16x16x32_bf16(af[i], bfr[j], acc[i][j], 0, 0, 0);
        __syncthreads();
    }

    #pragma unroll
    for (int ti = 0; ti < 4; ++ti) {
        int rbase = row0 + wm * 64 + ti * 16 + quad * 4;
        #pragma unroll
        for (int tj = 0; tj < 2; ++tj) {
            int cc = col0 + wn * 32 + tj * 16 + l16;
            if (cc >= Npad_out) continue;
            #pragma unroll
            for (int reg = 0; reg < 4; ++reg) {
                int rr = rbase + reg;
                if (rr >= M) continue;
                float v = acc[ti][tj][reg];
                float ov = 0.f;
                if (cc < N) {
                    if (bias) v += bias[cc];
                    if (relu) v = fmaxf(v, 0.f);
                    ov = v;
                }
                C[(size_t)rr * ldc + cc] = __float2bfloat16(ov);
            }
        }
    }
}

static void launch_gemm_mt(const __hip_bfloat16* A, const __hip_bfloat16* Bt, const float* bias,
                           __hip_bfloat16* C, int M, int N, int Kpad, int lda, int ldc,
                           int Npad_out, int relu, hipStream_t stream)
{
    int cover = N > Npad_out ? N : Npad_out;
    dim3 grid((cover + 63) / 64, (M + 127) / 128);
    gemm_mt_kernel<<<grid, 256, 0, stream>>>(A, Bt, bias, C, M, N, Kpad, lda, ldc, Npad_out, relu);
}

// ---------------------------------------------------------------------------
// Node-layer GEMM: 128x128 tile (wave = 64x64, 16 mfma : 8 ds_read per K-step),
// mod-8 grouping keeps a strip's col tiles on one XCD. bias+relu+bf16 out.
// ---------------------------------------------------------------------------
__global__ __launch_bounds__(256, 4) void gemm_swz2_kernel(
    const __hip_bfloat16* __restrict__ A, const __hip_bfloat16* __restrict__ Bt,
    const float* __restrict__ bias, __hip_bfloat16* __restrict__ C,
    int M, int N, int Kpad, int lda, int ldc, int Npad_out, int nct, int nstrips)
{
    int id = blockIdx.x;
    int rr8 = id & 7, q = id >> 3;
    int c = q % nct, sgrp = q / nct;
    int s = sgrp * 8 + rr8;
    if (s >= nstrips) return;
    int row0 = s * 128, col0 = c * 128;

    __shared__ __align__(16) __hip_bfloat16 As[128][40];
    __shared__ __align__(16) __hip_bfloat16 Bs[128][40];
    int tid = threadIdx.x;
    int wave = tid >> 6, lane = tid & 63;
    int wm = wave >> 1, wn = wave & 1;
    int quad = lane >> 4, l16 = lane & 15;

    f32x4 acc[4][4];
    #pragma unroll
    for (int i = 0; i < 4; ++i)
        #pragma unroll
        for (int j = 0; j < 4; ++j) acc[i][j] = (f32x4){0.f, 0.f, 0.f, 0.f};

    for (int k0 = 0; k0 < Kpad; k0 += 32) {
        #pragma unroll
        for (int u = 0; u < 2; ++u) {
            int item = tid + 256 * u;       // 0..511
            int rr = item >> 2, ch = (item & 3) * 8;
            uint4 av = {0u, 0u, 0u, 0u}, bv = {0u, 0u, 0u, 0u};
            if (row0 + rr < M) av = *(const uint4*)(A + (size_t)(row0 + rr) * lda + k0 + ch);
            if (col0 + rr < N) bv = *(const uint4*)(Bt + (size_t)(col0 + rr) * Kpad + k0 + ch);
            *(uint4*)(&As[rr][ch]) = av;
            *(uint4*)(&Bs[rr][ch]) = bv;
        }
        __syncthreads();

        short8 af[4], bfr[4];
        #pragma unroll
        for (int i = 0; i < 4; ++i)
            af[i] = *(const short8*)(&As[wm * 64 + i * 16 + l16][quad * 8]);
        #pragma unroll
        for (int j = 0; j < 4; ++j)
            bfr[j] = *(const short8*)(&Bs[wn * 64 + j * 16 + l16][quad * 8]);
        #pragma unroll
        for (int i = 0; i < 4; ++i)
            #pragma unroll
            for (int j = 0; j < 4; ++j)
                acc[i][j] = __builtin_amdgcn_mfma_f32_16x16x32_bf16(af[i], bfr[j], acc[i][j], 0, 0, 0);
        __syncthreads();
    }

    #pragma unroll
    for (int ti = 0; ti < 4; ++ti) {
        int rbase = row0 + wm * 64 + ti * 16 + quad * 4;
        #pragma unroll
        for (int tj = 0; tj < 4; ++tj) {
            int cc = col0 + wn * 64 + tj * 16 + l16;
            if (cc >= Npad_out) continue;
            #pragma unroll
            for (int reg = 0; reg < 4; ++reg) {
                int rrow = rbase + reg;
                if (rrow >= M) continue;
                float ov = 0.f;
                if (cc < N) ov = fmaxf(acc[ti][tj][reg] + bias[cc], 0.f);
                C[(size_t)rrow * ldc + cc] = __float2bfloat16(ov);
            }
        }
    }
}

static void launch_gemm_swz2(const __hip_bfloat16* A, const __hip_bfloat16* Bt, const float* bias,
                             __hip_bfloat16* C, int M, int N, int Kpad, int lda, int ldc,
                             int Npad_out, hipStream_t stream)
{
    int nct = (Npad_out + 127) / 128;
    int nstrips = (M + 127) / 128;
    int G = 8 * nct * ((nstrips + 7) / 8);
    gemm_swz2_kernel<<<G, 256, 0, stream>>>(A, Bt, bias, C, M, N, Kpad, lda, ldc, Npad_out,
                                            nct, nstrips);
}

// ---------------------------------------------------------------------------
// GCN: degree, norms, multi-block scan, CSR build
// ---------------------------------------------------------------------------
__global__ void deg_kernel(const int* __restrict__ dst, int* __restrict__ deg, int E)
{
    int e = blockIdx.x * 256 + threadIdx.x;
    if (e < E) atomicAdd(&deg[dst[e]], 1);
}

__global__ void dis_kernel(const int* __restrict__ deg, float* __restrict__ dis,
                           float* __restrict__ selfc, int n)
{
    int i = blockIdx.x * 256 + threadIdx.x;
    if (i < n) {
        float d = (float)deg[i] + 1.0f;
        float r = 1.0f / sqrtf(d);
        dis[i] = r;
        selfc[i] = r * r;
    }
}

__global__ __launch_bounds__(256) void scan_p1(const int* __restrict__ deg,
                                               int* __restrict__ off, int* __restrict__ bsum)
{
    __shared__ int s[256];
    int tid = threadIdx.x;
    int i = blockIdx.x * 256 + tid;
    int v = (i < NNODES) ? deg[i] : 0;
    s[tid] = v;
    __syncthreads();
    #pragma unroll
    for (int d = 1; d < 256; d <<= 1) {
        int t = (tid >= d) ? s[tid - d] : 0;
        __syncthreads();
        s[tid] += t;
        __syncthreads();
    }
    if (i < NNODES) off[i] = s[tid] - v;
    if (tid == 255) bsum[blockIdx.x] = s[255];
}

__global__ __launch_bounds__(512) void scan_p2(int* __restrict__ bsum)
{
    __shared__ int s[512];
    int tid = threadIdx.x;
    int v = (tid < NBLK1) ? bsum[tid] : 0;
    s[tid] = v;
    __syncthreads();
    #pragma unroll
    for (int d = 1; d < 512; d <<= 1) {
        int t = (tid >= d) ? s[tid - d] : 0;
        __syncthreads();
        s[tid] += t;
        __syncthreads();
    }
    if (tid < NBLK1) bsum[tid] = s[tid] - v;
}

__global__ __launch_bounds__(256) void scan_p3(int* __restrict__ off, const int* __restrict__ bsum,
                                               int* __restrict__ cur)
{
    int i = blockIdx.x * 256 + threadIdx.x;
    if (i < NNODES) {
        int v = off[i] + bsum[blockIdx.x];
        off[i] = v;
        cur[i] = v;
    }
    if (i == NNODES) off[NNODES] = NEDGES;
}

__global__ void fill_csr_kernel(const int* __restrict__ src, const int* __restrict__ dst,
                                const float* __restrict__ dis, int* __restrict__ cur,
                                int* __restrict__ csr_src, float* __restrict__ csr_w, int E)
{
    int e = blockIdx.x * 256 + threadIdx.x;
    if (e >= E) return;
    int s = src[e], d = dst[e];
    int p = atomicAdd(&cur[d], 1);
    csr_src[p] = s;
    csr_w[p] = dis[s] * dis[d];
}

// ---------------------------------------------------------------------------
// Pre-GEMM GCN aggregation: out[i] = selfc[i]*T[i] + sum_e w_e * T[src_e]
// 4-edge unrolled for load ILP.
// ---------------------------------------------------------------------------
__global__ __launch_bounds__(256) void gcn_agg2(
    const __hip_bfloat16* __restrict__ Tin, const int* __restrict__ off,
    const int* __restrict__ csr_src, const float* __restrict__ csr_w,
    const float* __restrict__ selfc, __hip_bfloat16* __restrict__ out,
    int half, int nc)
{
    int wave = threadIdx.x >> 6, lane = threadIdx.x & 63;
    int node = blockIdx.x * 4 + wave;
    if (node >= NNODES) return;
    const unsigned int* Tp = (const unsigned int*)Tin;
    unsigned int* Op = (unsigned int*)out;
    size_t rb = (size_t)node * half;
    bool m0 = lane < half;
    bool m1 = (nc > 1) && (lane + 64 < half);
    float sc = selfc[node];
    float a0x = 0.f, a0y = 0.f, a1x = 0.f, a1y = 0.f;
    float b0x = 0.f, b0y = 0.f, b1x = 0.f, b1y = 0.f;
    float c0x = 0.f, c0y = 0.f, c1x = 0.f, c1y = 0.f;
    float d0x = 0.f, d0y = 0.f, d1x = 0.f, d1y = 0.f;
    if (m0) { unsigned int v = Tp[rb + lane];      a0x = bf_lo(v) * sc; a0y = bf_hi(v) * sc; }
    if (m1) { unsigned int v = Tp[rb + lane + 64]; a1x = bf_lo(v) * sc; a1y = bf_hi(v) * sc; }
    int s0 = off[node], s1 = off[node + 1];
    int e = s0;
    for (; e + 4 <= s1; e += 4) {
        int i0 = csr_src[e], i1 = csr_src[e + 1], i2 = csr_src[e + 2], i3 = csr_src[e + 3];
        float w0 = csr_w[e], w1 = csr_w[e + 1], w2 = csr_w[e + 2], w3 = csr_w[e + 3];
        size_t p0 = (size_t)i0 * half, p1 = (size_t)i1 * half;
        size_t p2 = (size_t)i2 * half, p3 = (size_t)i3 * half;
        if (m0) {
            unsigned int v0 = Tp[p0 + lane], v1 = Tp[p1 + lane];
            unsigned int v2 = Tp[p2 + lane], v3 = Tp[p3 + lane];
            a0x += bf_lo(v0) * w0; a0y += bf_hi(v0) * w0;
            b0x += bf_lo(v1) * w1; b0y += bf_hi(v1) * w1;
            c0x += bf_lo(v2) * w2; c0y += bf_hi(v2) * w2;
            d0x += bf_lo(v3) * w3; d0y += bf_hi(v3) * w3;
        }
        if (m1) {
            unsigned int v0 = Tp[p0 + lane + 64], v1 = Tp[p1 + lane + 64];
            unsigned int v2 = Tp[p2 + lane + 64], v3 = Tp[p3 + lane + 64];
            a1x += bf_lo(v0) * w0; a1y += bf_hi(v0) * w0;
            b1x += bf_lo(v1) * w1; b1y += bf_hi(v1) * w1;
            c1x += bf_lo(v2) * w2; c1y += bf_hi(v2) * w2;
            d1x += bf_lo(v3) * w3; d1y += bf_hi(v3) * w3;
        }
    }
    for (; e + 2 <= s1; e += 2) {
        int i0 = csr_src[e], i1 = csr_src[e + 1];
        float w0 = csr_w[e], w1 = csr_w[e + 1];
        size_t p0 = (size_t)i0 * half, p1 = (size_t)i1 * half;
        if (m0) {
            unsigned int v0 = Tp[p0 + lane], v1 = Tp[p1 + lane];
            a0x += bf_lo(v0) * w0; a0y += bf_hi(v0) * w0;
            b0x += bf_lo(v1) * w1; b0y += bf_hi(v1) * w1;
        }
        if (m1) {
            unsigned int v0 = Tp[p0 + lane + 64], v1 = Tp[p1 + lane + 64];
            a1x += bf_lo(v0) * w0; a1y += bf_hi(v0) * w0;
            b1x += bf_lo(v1) * w1; b1y += bf_hi(v1) * w1;
        }
    }
    if (e < s1) {
        int i0 = csr_src[e];
        float w0 = csr_w[e];
        size_t p0 = (size_t)i0 * half;
        if (m0) { unsigned int v = Tp[p0 + lane];      a0x += bf_lo(v) * w0; a0y += bf_hi(v) * w0; }
        if (m1) { unsigned int v = Tp[p0 + lane + 64]; a1x += bf_lo(v) * w0; a1y += bf_hi(v) * w0; }
    }
    if (m0) Op[rb + lane]      = bf_pack((a0x + b0x) + (c0x + d0x), (a0y + b0y) + (c0y + d0y));
    if (m1) Op[rb + lane + 64] = bf_pack((a1x + b1x) + (c1x + d1x), (a1y + b1y) + (c1y + d1y));
}

// ---------------------------------------------------------------------------
// segment max pool (bf16 [NNODES][320] -> bf16 [NB][320]); batch sorted
// ---------------------------------------------------------------------------
__global__ __launch_bounds__(256) void pool_max_bf16(
    const __hip_bfloat16* __restrict__ H, const int* __restrict__ batch,
    __hip_bfloat16* __restrict__ g)
{
    int b = blockIdx.x;
    int lo = 0, hi = NNODES;
    while (lo < hi) { int mid = (lo + hi) >> 1; if (batch[mid] < b) lo = mid + 1; else hi = mid; }
    int s = lo;
    hi = NNODES;
    while (lo < hi) { int mid = (lo + hi) >> 1; if (batch[mid] < b + 1) lo = mid + 1; else hi = mid; }
    int e = lo;
    int tid = threadIdx.x;
    if (tid < 160) {
        const unsigned int* Hp = (const unsigned int*)H;
        float mx = 0.f, my = 0.f;
        for (int i = s; i < e; ++i) {
            unsigned int v = Hp[(size_t)i * 160 + tid];
            mx = fmaxf(mx, bf_lo(v));
            my = fmaxf(my, bf_hi(v));
        }
        ((unsigned int*)g)[(size_t)b * 160 + tid] = bf_pack(mx, my);
    }
}

// ---------------------------------------------------------------------------
// Conv branch: transpose to bf16, vectorized bucketed aggregation, weight folding
// ---------------------------------------------------------------------------
__global__ void conv_transpose_kernel(const float* __restrict__ w, __hip_bfloat16* __restrict__ wt)
{
    int idx = blockIdx.x * 256 + threadIdx.x;
    if (idx >= 256000) return;
    int o = idx / 8000;
    int rem = idx - o * 8000;
    int i = rem >> 3, k = rem & 7;
    wt[i * 256 + o * 8 + k] = __float2bfloat16(w[idx]);
}

__global__ __launch_bounds__(256) void conv_agg_kernel(
    const __hip_bfloat16* __restrict__ cwt, const int* __restrict__ target,
    __hip_bfloat16* __restrict__ aggw)
{
    __shared__ int tb_s[SEQ];
    __shared__ int cnt[26];
    __shared__ int boff[27];
    __shared__ int curs[26];
    __shared__ int bucket[SEQ];
    __shared__ float comb[3][256];
    int b = blockIdx.x, tid = threadIdx.x;
    int wave = tid >> 6, lane = tid & 63;
    const int* tb = target + b * SEQ;
    if (tid < 26) cnt[tid] = 0;
    __syncthreads();
    for (int i = tid; i < SEQ; i += 256) {
        int a = tb[i];
        tb_s[i] = a;
        atomicAdd(&cnt[a], 1);
    }
    __syncthreads();
    if (tid == 0) {
        int run = 0;
        for (int a = 0; a < 26; ++a) { boff[a] = run; curs[a] = run; run += cnt[a]; }
        boff[26] = run;
    }
    __syncthreads();
    for (int i = tid; i < SEQ; i += 256) {
        int a = tb_s[i];
        int p = atomicAdd(&curs[a], 1);
        bucket[p] = i;
    }
    __syncthreads();

    const uint2* cw = (const uint2*)cwt;
    uint2* aw = (uint2*)aggw;
    for (int a = 0; a < 26; ++a) {
        int s = boff[a], e = boff[a + 1];
        float x0 = 0.f, x1 = 0.f, x2 = 0.f, x3 = 0.f;
        float y0 = 0.f, y1 = 0.f, y2 = 0.f, y3 = 0.f;
        int j = s + wave;
        for (; j + 4 < e; j += 8) {
            uint2 v = cw[(size_t)bucket[j] * 64 + lane];
            uint2 u = cw[(size_t)bucket[j + 4] * 64 + lane];
            x0 += bf_lo(v.x); x1 += bf_hi(v.x); x2 += bf_lo(v.y); x3 += bf_hi(v.y);
            y0 += bf_lo(u.x); y1 += bf_hi(u.x); y2 += bf_lo(u.y); y3 += bf_hi(u.y);
        }
        if (j < e) {
            uint2 v = cw[(size_t)bucket[j] * 64 + lane];
            x0 += bf_lo(v.x); x1 += bf_hi(v.x); x2 += bf_lo(v.y); x3 += bf_hi(v.y);
        }
        x0 += y0; x1 += y1; x2 += y2; x3 += y3;
        if (wave > 0) {
            comb[wave - 1][lane * 4 + 0] = x0;
            comb[wave - 1][lane * 4 + 1] = x1;
            comb[wave - 1][lane * 4 + 2] = x2;
            comb[wave - 1][lane * 4 + 3] = x3;
        }
        __syncthreads();
        if (wave == 0) {
            x0 += comb[0][lane * 4 + 0] + comb[1][lane * 4 + 0] + comb[2][lane * 4 + 0];
            x1 += comb[0][lane * 4 + 1] + comb[1][lane * 4 + 1] + comb[2][lane * 4 + 1];
            x2 += comb[0][lane * 4 + 2] + comb[1][lane * 4 + 2] + comb[2][lane * 4 + 2];
            x3 += comb[0][lane * 4 + 3] + comb[1][lane * 4 + 3] + comb[2][lane * 4 + 3];
            uint2 o;
            o.x = bf_pack(x0, x1);
            o.y = bf_pack(x2, x3);
            aw[(size_t)b * 1664 + a * 64 + lane] = o;
        }
        __syncthreads();
    }
}

__global__ __launch_bounds__(128) void conv_wc_kernel(
    const float* __restrict__ emb, const float* __restrict__ w_fc, float* __restrict__ Wc)
{
    int o = blockIdx.x;
    int ak = blockIdx.y;
    int a = ak >> 3, k = ak & 7;
    int j = threadIdx.x;
    const float* wp = w_fc + (long)(o * 121) * 128 + j;
    const float* ep = emb + a * 128 + k;
    float s = 0.f;
    #pragma unroll 11
    for (int t = 0; t < 121; ++t) s += ep[t] * wp[t * 128];
    Wc[(long)(a * 256 + o * 8 + k) * 128 + j] = s;
}

__global__ void xtb_init_kernel(const float* __restrict__ b_fc, float* __restrict__ xtb)
{
    xtb[threadIdx.x] = b_fc[threadIdx.x];
}

__global__ __launch_bounds__(128) void convb_fold_kernel(
    const float* __restrict__ w_fc, const float* __restrict__ conv_b, float* __restrict__ xtb)
{
    int o = blockIdx.x, j = threadIdx.x;
    const float* wp = w_fc + (long)(o * 121) * 128 + j;
    float s = 0.f;
    for (int t = 0; t < 121; ++t) s += wp[t * 128];
    atomicAdd(&xtb[j], s * conv_b[o]);
}

__global__ void xc_convbias_kernel(const float* __restrict__ xtb, float* __restrict__ xc)
{
    int idx = blockIdx.x * 256 + threadIdx.x;
    if (idx >= NB * 128) return;
    int b = idx >> 7, j = idx & 127;
    xc[(long)b * 384 + 128 + j] = xtb[j];
}

// ---------------------------------------------------------------------------
// FG branch: attention row 0 + LayerNorm (bf16 in, bf16 padded out)
// ---------------------------------------------------------------------------
__global__ __launch_bounds__(256) void attn_ln_kernel(
    const __hip_bfloat16* __restrict__ Fb, const __hip_bfloat16* __restrict__ Kf,
    const __hip_bfloat16* __restrict__ Vf, const __hip_bfloat16* __restrict__ q0,
    const float* __restrict__ ln_g, const float* __restrict__ ln_b,
    __hip_bfloat16* __restrict__ out)
{
    int b = blockIdx.x, tid = threadIdx.x;
    __shared__ float qs[HID];
    __shared__ float sc[13];
    __shared__ float red[256];
    __shared__ float red2[256];
    __shared__ float rowv[HID];
    __shared__ float mean_s, inv_s;

    for (int d = tid; d < HID; d += 256) qs[d] = __bfloat162float(q0[(size_t)b * 320 + d]);
    __syncthreads();
    if (tid < 208) {
        int k = tid >> 4, sub = tid & 15;
        const __hip_bfloat16* kr = Kf + ((size_t)b * 13 + k) * 320;
        float p = 0.f;
        for (int d = sub; d < HID; d += 16) p += qs[d] * __bfloat162float(kr[d]);
        red[tid] = p;
    }
    __syncthreads();
    if (tid < 208 && (tid & 15) == 0) {
        float s = 0.f;
        #pragma unroll
        for (int j = 0; j < 16; ++j) s += red[tid + j];
        sc[tid >> 4] = s * 0.0577350269189626f;  // 1/sqrt(300)
    }
    __syncthreads();
    if (tid == 0) {
        float mx = sc[0];
        for (int k = 1; k < 13; ++k) mx = fmaxf(mx, sc[k]);
        float ssum = 0.f;
        for (int k = 0; k < 13; ++k) { float e = expf(sc[k] - mx); sc[k] = e; ssum += e; }
        float inv = 1.0f / ssum;
        for (int k = 0; k < 13; ++k) sc[k] *= inv;
    }
    __syncthreads();
    for (int d = tid; d < HID; d += 256) {
        float v = __bfloat162float(Fb[((size_t)b * 13) * 320 + d]);
        #pragma unroll
        for (int k = 0; k < 13; ++k)
            v += sc[k] * __bfloat162float(Vf[((size_t)b * 13 + k) * 320 + d]);
        rowv[d] = v;
    }
    __syncthreads();
    float s1 = 0.f, s2 = 0.f;
    for (int d = tid; d < HID; d += 256) { float v = rowv[d]; s1 += v; s2 += v * v; }
    red[tid] = s1; red2[tid] = s2;
    __syncthreads();
    for (int s = 128; s > 0; s >>= 1) {
        if (tid < s) { red[tid] += red[tid + s]; red2[tid] += red2[tid + s]; }
        __syncthreads();
    }
    if (tid == 0) {
        float mean = red[0] / (float)HID;
        float var = red2[0] / (float)HID - mean * mean;
        mean_s = mean;
        inv_s = 1.0f / sqrtf(var + 1e-5f);
    }
    __syncthreads();
    for (int d = tid; d < 320; d += 256) {
        float v = 0.f;
        if (d < HID) v = (rowv[d] - mean_s) * inv_s * ln_g[d] + ln_b[d];
        out[(size_t)b * 320 + d] = __float2bfloat16(v);
    }
}

// ---------------------------------------------------------------------------
// final: out[b] = X[b,:512] . out_w + out_b   (fp32)
// ---------------------------------------------------------------------------
__global__ __launch_bounds__(256) void final_out_kernel(
    const float* __restrict__ X, const float* __restrict__ w,
    const float* __restrict__ bias, float* __restrict__ out)
{
    int b = blockIdx.x, tid = threadIdx.x;
    __shared__ float red[256];
    float p = X[(long)b * 512 + tid] * w[tid] + X[(long)b * 512 + tid + 256] * w[tid + 256];
    red[tid] = p;
    __syncthreads();
    for (int s = 128; s > 0; s >>= 1) {
        if (tid < s) red[tid] += red[tid + s];
        __syncthreads();
    }
    if (tid == 0) out[b] = red[0] + bias[0];
}

// ---------------------------------------------------------------------------
// Host launcher
// ---------------------------------------------------------------------------
extern "C" void kernel_launch(void* const* d_in, const int* in_sizes, int n_in,
                              void* d_out, int out_size, void* d_ws, size_t ws_size,
                              hipStream_t stream)
{
    const float* x        = (const float*)d_in[0];
    const int*   ei       = (const int*)d_in[1];
    const int*   batch    = (const int*)d_in[2];
    const int*   target   = (const int*)d_in[3];
    const float* embs     = (const float*)d_in[4];
    const float* W1       = (const float*)d_in[5];
    const float* b1       = (const float*)d_in[6];
    const float* W2       = (const float*)d_in[7];
    const float* b2       = (const float*)d_in[8];
    const float* W3       = (const float*)d_in[9];
    const float* b3       = (const float*)d_in[10];
    const float* fc_g1_w  = (const float*)d_in[11];
    const float* fc_g1_b  = (const float*)d_in[12];
    const float* fc_g2_w  = (const float*)d_in[13];
    const float* fc_g2_b  = (const float*)d_in[14];
    const float* emb_xt   = (const float*)d_in[15];
    const float* conv_w   = (const float*)d_in[16];
    const float* conv_b   = (const float*)d_in[17];
    const float* fc1xt_w  = (const float*)d_in[18];
    const float* fc1xt_b  = (const float*)d_in[19];
    const float* fg_lin_w = (const float*)d_in[20];
    const float* fg_lin_b = (const float*)d_in[21];
    const float* Wq       = (const float*)d_in[22];
    const float* Wk       = (const float*)d_in[23];
    const float* Wv       = (const float*)d_in[24];
    const float* ln_g     = (const float*)d_in[25];
    const float* ln_b     = (const float*)d_in[26];
    const float* fg_out_w = (const float*)d_in[27];
    const float* fg_out_b = (const float*)d_in[28];
    const float* fc1_w    = (const float*)d_in[29];
    const float* fc1_b    = (const float*)d_in[30];
    const float* fc2_w    = (const float*)d_in[31];
    const float* fc2_b    = (const float*)d_in[32];
    const float* out_w    = (const float*)d_in[33];
    const float* out_b    = (const float*)d_in[34];

    const int* src = ei;
    const int* dst = ei + NEDGES;
    typedef __hip_bfloat16 bf;

    // ---- workspace carve (256-B aligned bump allocator) ----
    char* p = (char*)d_ws;
    auto alloc = [&](size_t bytes) { char* r = p; p += (bytes + 255) & ~(size_t)255; return r; };
    bf*   xb      = (bf*)alloc((size_t)NNODES * 96 * 2);
    bf*   T       = (bf*)alloc((size_t)NNODES * 160 * 2);
    bf*   H       = (bf*)alloc((size_t)NNODES * 320 * 2);
    int*  deg     = (int*)alloc(NNODES * 4);                // reused as CSR cursor
    float* dis    = (float*)alloc(NNODES * 4);
    float* selfc  = (float*)alloc(NNODES * 4);
    int*  off     = (int*)alloc((NNODES + 1) * 4);
    int*  bsum    = (int*)alloc(512 * 4);
    int*  csr_src = (int*)alloc(NEDGES * 4);
    float* csr_w  = (float*)alloc(NEDGES * 4);
    bf*   w1t     = (bf*)alloc(78 * 96 * 2);
    bf*   w2t     = (bf*)alloc(156 * 96 * 2);
    bf*   w3t     = (bf*)alloc(312 * 160 * 2);
    bf*   fcg1t   = (bf*)alloc(1024 * 320 * 2);
    bf*   fcg2t   = (bf*)alloc(128 * 1024 * 2);
    bf*   fglint  = (bf*)alloc(300 * 160 * 2);
    bf*   wkt     = (bf*)alloc(300 * 320 * 2);
    bf*   wvt     = (bf*)alloc(300 * 320 * 2);
    bf*   wqt     = (bf*)alloc(300 * 320 * 2);
    bf*   fgoutt  = (bf*)alloc(128 * 320 * 2);
    bf*   fc1t    = (bf*)alloc(1024 * 384 * 2);
    bf*   fc2t    = (bf*)alloc(512 * 1024 * 2);
    bf*   fglwb   = (bf*)alloc(133 * 320 * 2);
    bf*   wk2t    = (bf*)alloc(300 * 160 * 2);
    bf*   wv2t    = (bf*)alloc(300 * 160 * 2);
    bf*   wq2t    = (bf*)alloc(300 * 160 * 2);
    float* bk2    = (float*)alloc(300 * 4);
    float* bv2    = (float*)alloc(300 * 4);
    float* bq2    = (float*)alloc(300 * 4);
    bf*   g       = (bf*)alloc((size_t)NB * 320 * 2);
    bf*   G1b     = (bf*)alloc((size_t)NB * 1024 * 2);
    bf*   embsb   = (bf*)alloc((size_t)NB * 13 * 160 * 2);
    bf*   Fbuf    = (bf*)alloc((size_t)NB * 13 * 320 * 2);
    bf*   Kbuf    = (bf*)alloc((size_t)NB * 13 * 320 * 2);
    bf*   Vbuf    = (bf*)alloc((size_t)NB * 13 * 320 * 2);
    bf*   Qbuf    = (bf*)alloc((size_t)NB * 320 * 2);
    bf*   f2row   = (bf*)alloc((size_t)NB * 320 * 2);
    float* xc     = (float*)alloc((size_t)NB * 384 * 4);
    bf*   xcb     = (bf*)alloc((size_t)NB * 384 * 2);
    float* F2     = (float*)alloc((size_t)NB * 512 * 4);
    bf*   cwt     = (bf*)alloc(256000 * 2);
    bf*   aggwb   = (bf*)alloc((size_t)NB * 6656 * 2);
    float* Wc     = (float*)alloc((size_t)6656 * 128 * 4);
    bf*   Wct     = (bf*)alloc((size_t)128 * 6656 * 2);
    float* xtb    = (float*)alloc(128 * 4);

    // ---- degree / norms / CSR (multi-block scan) ----
    hipMemsetAsync(deg, 0, NNODES * sizeof(int), stream);
    deg_kernel<<<(NEDGES + 255) / 256, 256, 0, stream>>>(dst, deg, NEDGES);
    dis_kernel<<<(NNODES + 255) / 256, 256, 0, stream>>>(deg, dis, selfc, NNODES);
    scan_p1<<<NBLK1, 256, 0, stream>>>(deg, off, bsum);
    scan_p2<<<1, 512, 0, stream>>>(bsum);
    scan_p3<<<NBLK1, 256, 0, stream>>>(off, bsum, deg);   // deg becomes cursor
    fill_csr_kernel<<<(NEDGES + 255) / 256, 256, 0, stream>>>(src, dst, dis, deg, csr_src, csr_w, NEDGES);

    // ---- weight transposes (one batched launch) + input converts ----
    {
        TBatch tb;
        const float* srcs[12] = {W1, W2, W3, fc_g1_w, fc_g2_w, fg_lin_w, Wk, Wv, Wq, fg_out_w, fc1_w, fc2_w};
        bf* dsts[12]          = {w1t, w2t, w3t, fcg1t, fcg2t, fglint, wkt, wvt, wqt, fgoutt, fc1t, fc2t};
        int Ks[12]    = {78, 78, 156, 312, 1024, 133, 300, 300, 300, 300, 384, 1024};
        int Ns[12]    = {78, 156, 312, 1024, 128, 300, 300, 300, 300, 128, 1024, 512};
        int Kpads[12] = {96, 96, 160, 320, 1024, 160, 320, 320, 320, 320, 384, 1024};
        int bs = 0;
        for (int i = 0; i < 12; ++i) {
            tb.src[i] = srcs[i]; tb.dst[i] = dsts[i];
            tb.K[i] = Ks[i]; tb.N[i] = Ns[i]; tb.Kpad[i] = Kpads[i];
            tb.bstart[i] = bs;
            bs += (int)(((long)Ns[i] * Kpads[i] + 255) / 256);
        }
        tb.bstart[12] = bs;
        transpose_batch_kernel<<<bs, 256, 0, stream>>>(tb);
    }
    cvt_pad_kernel<<<((long)NNODES * 96 + 255) / 256, 256, 0, stream>>>(x, xb, NNODES, 78, 96);
    cvt_pad_kernel<<<((long)NB * 13 * 160 + 255) / 256, 256, 0, stream>>>(embs, embsb, NB * 13, 133, 160);

    // ---- GCN layers: agg(input) -> 128x128-tile XCD-grouped MFMA GEMM ----
    int agrid = (NNODES + 3) / 4;
    gcn_agg2<<<agrid, 256, 0, stream>>>(xb, off, csr_src, csr_w, selfc, T, 48, 1);
    launch_gemm_swz2(T, w1t, b1, H, NNODES, 78, 96, 96, 96, 96, stream);

    gcn_agg2<<<agrid, 256, 0, stream>>>(H, off, csr_src, csr_w, selfc, T, 48, 1);
    launch_gemm_swz2(T, w2t, b2, H, NNODES, 156, 96, 96, 160, 160, stream);

    gcn_agg2<<<agrid, 256, 0, stream>>>(H, off, csr_src, csr_w, selfc, T, 80, 2);
    launch_gemm_swz2(T, w3t, b3, H, NNODES, 312, 160, 160, 320, 320, stream);

    // ---- global max pool + graph MLP ----
    pool_max_bf16<<<NB, 256, 0, stream>>>(H, batch, g);
    launch_gemm_bf16(g, fcg1t, fc_g1_b, G1b, NB, 1024, 320, 320, 1024, 1024, 1, 1, 1, stream);
    launch_gemm_bf16(G1b, fcg2t, fc_g2_b, xc, NB, 128, 1024, 1024, 384, 128, 0, 0, 1, stream);

    // ---- conv branch (folded; split-K MFMA accumulates into xc cols 128..255) ----
    conv_transpose_kernel<<<(256000 + 255) / 256, 256, 0, stream>>>(conv_w, cwt);
    conv_agg_kernel<<<NB, 256, 0, stream>>>(cwt, target, aggwb);
    conv_wc_kernel<<<dim3(32, 208), 128, 0, stream>>>(emb_xt, fc1xt_w, Wc);
    transpose_cvt_kernel<<<((long)128 * 6656 + 255) / 256, 256, 0, stream>>>(Wc, Wct, 6656, 128, 6656);
    xtb_init_kernel<<<1, 128, 0, stream>>>(fc1xt_b, xtb);
    convb_fold_kernel<<<32, 128, 0, stream>>>(fc1xt_w, conv_b, xtb);
    xc_convbias_kernel<<<(NB * 128 + 255) / 256, 256, 0, stream>>>(xtb, xc);
    launch_gemm_bf16(aggwb, Wct, nullptr, xc + 128, NB, 128, 6656, 6656, 384, 128, 0, 0, 8, stream);

    // ---- FG branch (K/V/Q projected directly from embs via folded weights) ----
    cvt_pad_kernel<<<(133 * 320 + 255) / 256, 256, 0, stream>>>(fg_lin_w, fglwb, 133, 300, 320);
    launch_gemm_bf16(wkt, fglwb, nullptr, wk2t, 300, 133, 320, 320, 160, 160, 0, 1, 1, stream);
    launch_gemm_bf16(wvt, fglwb, nullptr, wv2t, 300, 133, 320, 320, 160, 160, 0, 1, 1, stream);
    launch_gemm_bf16(wqt, fglwb, nullptr, wq2t, 300, 133, 320, 320, 160, 160, 0, 1, 1, stream);
    bias_fold_t_kernel<<<300, 256, 0, stream>>>(fg_lin_b, wkt, bk2, 300, 320, 300);
    bias_fold_t_kernel<<<300, 256, 0, stream>>>(fg_lin_b, wvt, bv2, 300, 320, 300);
    bias_fold_t_kernel<<<300, 256, 0, stream>>>(fg_lin_b, wqt, bq2, 300, 320, 300);
    launch_gemm_mt(embsb, fglint, fg_lin_b, Fbuf, NB * 13, 300, 160, 160, 320, 320, 0, stream);
    launch_gemm_mt(embsb, wk2t, bk2, Kbuf, NB * 13, 300, 160, 160, 320, 320, 0, stream);
    launch_gemm_mt(embsb, wv2t, bv2, Vbuf, NB * 13, 300, 160, 160, 320, 320, 0, stream);
    launch_gemm_bf16(embsb, wq2t, bq2, Qbuf, NB, 300, 160, 13 * 160, 320, 320, 0, 1, 1, stream);
    attn_ln_kernel<<<NB, 256, 0, stream>>>(Fbuf, Kbuf, Vbuf, Qbuf, ln_g, ln_b, f2row);
    launch_gemm_bf16(f2row, fgoutt, fg_out_b, xc + 256, NB, 128, 320, 320, 384, 128, 0, 0, 1, stream);

    // ---- head ----
    cvt_pad_kernel<<<((long)NB * 384 + 255) / 256, 256, 0, stream>>>(xc, xcb, NB, 384, 384);
    launch_gemm_bf16(xcb, fc1t, fc1_b, G1b, NB, 1024, 384, 384, 1024, 1024, 1, 1, 1, stream);
    launch_gemm_bf16(G1b, fc2t, fc2_b, F2, NB, 512, 1024, 1024, 512, 512, 1, 0, 1, stream);
    final_out_kernel<<<NB, 256, 0, stream>>>(F2, out_w, out_b, (float*)d_out);
}

// Round 14
// 745.811 us; speedup vs baseline: 1.0489x; 1.0489x over previous
//
#include <hip/hip_runtime.h>
#include <hip/hip_bf16.h>
#include <math.h>

// ---------------------------------------------------------------------------
// Problem constants
// ---------------------------------------------------------------------------
#define NNODES 100000
#define NEDGES 400000
#define NB     1024
#define SEQ    1000
#define HID    300
#define NBLK1  ((NNODES + 255) / 256)   // 391

typedef __attribute__((ext_vector_type(8))) short short8;   // 8 bf16 (4 VGPRs)
typedef __attribute__((ext_vector_type(4))) float f32x4;    // MFMA acc

__device__ __forceinline__ float bf_lo(unsigned int v) { return __uint_as_float(v << 16); }
__device__ __forceinline__ float bf_hi(unsigned int v) { return __uint_as_float(v & 0xffff0000u); }
__device__ __forceinline__ unsigned int bf_pack(float lo, float hi) {
    __hip_bfloat16 a = __float2bfloat16(lo), b = __float2bfloat16(hi);
    unsigned short ua = *(unsigned short*)&a, ub = *(unsigned short*)&b;
    return (unsigned int)ua | ((unsigned int)ub << 16);
}

// ---------------------------------------------------------------------------
// fp32 [M][K] -> bf16 [M][Kpad] (zero-padded)
// ---------------------------------------------------------------------------
__global__ void cvt_pad_kernel(const float* __restrict__ in, __hip_bfloat16* __restrict__ out,
                               int M, int K, int Kpad)
{
    long idx = (long)blockIdx.x * 256 + threadIdx.x;
    if (idx >= (long)M * Kpad) return;
    int m = idx / Kpad, k = idx % Kpad;
    out[idx] = __float2bfloat16(k < K ? in[(long)m * K + k] : 0.f);
}

// fp32 [K][N] row-major -> bf16 Bt [N][Kpad] (zero-padded)
__global__ void transpose_cvt_kernel(const float* __restrict__ in, __hip_bfloat16* __restrict__ out,
                                     int K, int N, int Kpad)
{
    long idx = (long)blockIdx.x * 256 + threadIdx.x;
    if (idx >= (long)N * Kpad) return;
    int n = idx / Kpad, k = idx % Kpad;
    out[idx] = __float2bfloat16(k < K ? in[(long)k * N + n] : 0.f);
}

// Batched weight transpose: 12 descriptors in one launch
struct TBatch {
    const float* src[12];
    __hip_bfloat16* dst[12];
    int K[12]; int N[12]; int Kpad[12];
    int bstart[13];
};

__global__ __launch_bounds__(256) void transpose_batch_kernel(TBatch tb)
{
    int blk = blockIdx.x;
    int d = 0;
    while (d < 11 && blk >= tb.bstart[d + 1]) ++d;
    long idx = (long)(blk - tb.bstart[d]) * 256 + threadIdx.x;
    long tot = (long)tb.N[d] * tb.Kpad[d];
    if (idx >= tot) return;
    int Kpad = tb.Kpad[d];
    int n = idx / Kpad, k = idx % Kpad;
    tb.dst[d][idx] = __float2bfloat16(k < tb.K[d] ? tb.src[d][(long)k * tb.N[d] + n] : 0.f);
}

// bias fold from TRANSPOSED bf16 weights: out[n] = sum_k b[k] * Wt[n][k]
__global__ __launch_bounds__(256) void bias_fold_t_kernel(
    const float* __restrict__ b, const __hip_bfloat16* __restrict__ Wt,
    float* __restrict__ out, int K, int Kpad, int N)
{
    int n = blockIdx.x;
    if (n >= N) return;
    __shared__ float red[256];
    int tid = threadIdx.x;
    float s = 0.f;
    for (int k = tid; k < K; k += 256)
        s += b[k] * __bfloat162float(Wt[(size_t)n * Kpad + k]);
    red[tid] = s;
    __syncthreads();
    #pragma unroll
    for (int st = 128; st > 0; st >>= 1) {
        if (tid < st) red[tid] += red[tid + st];
        __syncthreads();
    }
    if (tid == 0) out[n] = red[0];
}

// ---------------------------------------------------------------------------
// BF16 MFMA GEMM (TN), 64x64 tile: C = act(A @ Bt^T + bias)
// ---------------------------------------------------------------------------
__global__ __launch_bounds__(256) void gemm_bf16_kernel(
    const __hip_bfloat16* __restrict__ A, const __hip_bfloat16* __restrict__ Bt,
    const float* __restrict__ bias, void* __restrict__ C,
    int M, int N, int Kpad, int lda, int ldc, int Npad_out,
    int relu, int outbf, int chunk)
{
    __shared__ __align__(16) __hip_bfloat16 As[64][40];
    __shared__ __align__(16) __hip_bfloat16 Bs[64][40];
    int tid = threadIdx.x;
    int wave = tid >> 6, lane = tid & 63;
    int wm = wave >> 1, wn = wave & 1;
    int quad = lane >> 4, l16 = lane & 15;
    int row0 = blockIdx.y * 64, col0 = blockIdx.x * 64;

    int kbeg = 0, kend = Kpad;
    if (chunk > 0) { kbeg = blockIdx.z * chunk; kend = kbeg + chunk; if (kend > Kpad) kend = Kpad; }

    f32x4 acc[2][2];
    #pragma unroll
    for (int i = 0; i < 2; ++i)
        #pragma unroll
        for (int j = 0; j < 2; ++j) acc[i][j] = (f32x4){0.f, 0.f, 0.f, 0.f};

    int r = tid >> 2, cch = (tid & 3) * 8;

    for (int k0 = kbeg; k0 < kend; k0 += 32) {
        uint4 av = {0u, 0u, 0u, 0u};
        if (row0 + r < M) av = *(const uint4*)(A + (size_t)(row0 + r) * lda + k0 + cch);
        *(uint4*)(&As[r][cch]) = av;
        uint4 bv = {0u, 0u, 0u, 0u};
        if (col0 + r < N) bv = *(const uint4*)(Bt + (size_t)(col0 + r) * Kpad + k0 + cch);
        *(uint4*)(&Bs[r][cch]) = bv;
        __syncthreads();

        short8 a0 = *(const short8*)(&As[wm * 32 + l16][quad * 8]);
        short8 a1 = *(const short8*)(&As[wm * 32 + 16 + l16][quad * 8]);
        short8 b0 = *(const short8*)(&Bs[wn * 32 + l16][quad * 8]);
        short8 b1 = *(const short8*)(&Bs[wn * 32 + 16 + l16][quad * 8]);
        acc[0][0] = __builtin_amdgcn_mfma_f32_16x16x32_bf16(a0, b0, acc[0][0], 0, 0, 0);
        acc[0][1] = __builtin_amdgcn_mfma_f32_16x16x32_bf16(a0, b1, acc[0][1], 0, 0, 0);
        acc[1][0] = __builtin_amdgcn_mfma_f32_16x16x32_bf16(a1, b0, acc[1][0], 0, 0, 0);
        acc[1][1] = __builtin_amdgcn_mfma_f32_16x16x32_bf16(a1, b1, acc[1][1], 0, 0, 0);
        __syncthreads();
    }

    #pragma unroll
    for (int ti = 0; ti < 2; ++ti) {
        int rbase = row0 + wm * 32 + ti * 16 + quad * 4;
        #pragma unroll
        for (int tj = 0; tj < 2; ++tj) {
            int cc = col0 + wn * 32 + tj * 16 + l16;
            if (cc >= Npad_out) continue;
            #pragma unroll
            for (int reg = 0; reg < 4; ++reg) {
                int rr = rbase + reg;
                if (rr >= M) continue;
                float v = acc[ti][tj][reg];
                if (chunk > 0) {
                    if (cc < N) atomicAdd((float*)C + (size_t)rr * ldc + cc, v);
                } else {
                    float ov = 0.f;
                    if (cc < N) {
                        if (bias) v += bias[cc];
                        if (relu) v = fmaxf(v, 0.f);
                        ov = v;
                    }
                    if (outbf) ((__hip_bfloat16*)C)[(size_t)rr * ldc + cc] = __float2bfloat16(ov);
                    else       ((float*)C)[(size_t)rr * ldc + cc] = ov;
                }
            }
        }
    }
}

static void launch_gemm_bf16(const __hip_bfloat16* A, const __hip_bfloat16* Bt, const float* bias,
                             void* C, int M, int N, int Kpad, int lda, int ldc, int Npad_out,
                             int relu, int outbf, int splitz, hipStream_t stream)
{
    int cover = N > Npad_out ? N : Npad_out;
    int chunk = (splitz > 1) ? (Kpad / splitz) : 0;
    dim3 grid((cover + 63) / 64, (M + 63) / 64, splitz > 1 ? splitz : 1);
    gemm_bf16_kernel<<<grid, 256, 0, stream>>>(A, Bt, bias, C, M, N, Kpad, lda, ldc, Npad_out,
                                               relu, outbf, chunk);
}

// ---------------------------------------------------------------------------
// BF16 MFMA GEMM (TN), 128x64 tile, 2D grid (FG branch K/V, M=13312)
// ---------------------------------------------------------------------------
__global__ __launch_bounds__(256) void gemm_mt_kernel(
    const __hip_bfloat16* __restrict__ A, const __hip_bfloat16* __restrict__ Bt,
    const float* __restrict__ bias, __hip_bfloat16* __restrict__ C,
    int M, int N, int Kpad, int lda, int ldc, int Npad_out, int relu)
{
    __shared__ __align__(16) __hip_bfloat16 As[128][40];
    __shared__ __align__(16) __hip_bfloat16 Bs[64][40];
    int tid = threadIdx.x;
    int wave = tid >> 6, lane = tid & 63;
    int wm = wave >> 1, wn = wave & 1;
    int quad = lane >> 4, l16 = lane & 15;
    int row0 = blockIdx.y * 128, col0 = blockIdx.x * 64;

    f32x4 acc[4][2];
    #pragma unroll
    for (int i = 0; i < 4; ++i)
        #pragma unroll
        for (int j = 0; j < 2; ++j) acc[i][j] = (f32x4){0.f, 0.f, 0.f, 0.f};

    int r = tid >> 2, cch = (tid & 3) * 8;

    for (int k0 = 0; k0 < Kpad; k0 += 32) {
        uint4 av0 = {0u, 0u, 0u, 0u}, av1 = {0u, 0u, 0u, 0u}, bv = {0u, 0u, 0u, 0u};
        if (row0 + r < M)      av0 = *(const uint4*)(A + (size_t)(row0 + r) * lda + k0 + cch);
        if (row0 + r + 64 < M) av1 = *(const uint4*)(A + (size_t)(row0 + r + 64) * lda + k0 + cch);
        if (col0 + r < N)      bv  = *(const uint4*)(Bt + (size_t)(col0 + r) * Kpad + k0 + cch);
        *(uint4*)(&As[r][cch]) = av0;
        *(uint4*)(&As[r + 64][cch]) = av1;
        *(uint4*)(&Bs[r][cch]) = bv;
        __syncthreads();

        short8 af[4], bfr[2];
        #pragma unroll
        for (int i = 0; i < 4; ++i)
            af[i] = *(const short8*)(&As[wm * 64 + i * 16 + l16][quad * 8]);
        #pragma unroll
        for (int j = 0; j < 2; ++j)
            bfr[j] = *(const short8*)(&Bs[wn * 32 + j * 16 + l16][quad * 8]);
        #pragma unroll
        for (int i = 0; i < 4; ++i)
            #pragma unroll
            for (int j = 0; j < 2; ++j)
                acc[i][j] = __builtin_amdgcn_mfma_f32_16x16x32_bf16(af[i], bfr[j], acc[i][j], 0, 0, 0);
        __syncthreads();
    }

    #pragma unroll
    for (int ti = 0; ti < 4; ++ti) {
        int rbase = row0 + wm * 64 + ti * 16 + quad * 4;
        #pragma unroll
        for (int tj = 0; tj < 2; ++tj) {
            int cc = col0 + wn * 32 + tj * 16 + l16;
            if (cc >= Npad_out) continue;
            #pragma unroll
            for (int reg = 0; reg < 4; ++reg) {
                int rr = rbase + reg;
                if (rr >= M) continue;
                float v = acc[ti][tj][reg];
                float ov = 0.f;
                if (cc < N) {
                    if (bias) v += bias[cc];
                    if (relu) v = fmaxf(v, 0.f);
                    ov = v;
                }
                C[(size_t)rr * ldc + cc] = __float2bfloat16(ov);
            }
        }
    }
}

static void launch_gemm_mt(const __hip_bfloat16* A, const __hip_bfloat16* Bt, const float* bias,
                           __hip_bfloat16* C, int M, int N, int Kpad, int lda, int ldc,
                           int Npad_out, int relu, hipStream_t stream)
{
    int cover = N > Npad_out ? N : Npad_out;
    dim3 grid((cover + 63) / 64, (M + 127) / 128);
    gemm_mt_kernel<<<grid, 256, 0, stream>>>(A, Bt, bias, C, M, N, Kpad, lda, ldc, Npad_out, relu);
}

// ---------------------------------------------------------------------------
// Node-layer GEMM: 128x64 staged tile + XCD-aware mod-8 swizzle (round-12 best)
// ---------------------------------------------------------------------------
__global__ __launch_bounds__(256) void gemm_swz_kernel(
    const __hip_bfloat16* __restrict__ A, const __hip_bfloat16* __restrict__ Bt,
    const float* __restrict__ bias, __hip_bfloat16* __restrict__ C,
    int M, int N, int Kpad, int lda, int ldc, int Npad_out, int nct, int nstrips)
{
    int id = blockIdx.x;
    int rr8 = id & 7, q = id >> 3;
    int c = q % nct, sgrp = q / nct;
    int s = sgrp * 8 + rr8;
    if (s >= nstrips) return;
    int row0 = s * 128, col0 = c * 64;

    __shared__ __align__(16) __hip_bfloat16 As[128][40];
    __shared__ __align__(16) __hip_bfloat16 Bs[64][40];
    int tid = threadIdx.x;
    int wave = tid >> 6, lane = tid & 63;
    int wm = wave >> 1, wn = wave & 1;
    int quad = lane >> 4, l16 = lane & 15;

    f32x4 acc[4][2];
    #pragma unroll
    for (int i = 0; i < 4; ++i)
        #pragma unroll
        for (int j = 0; j < 2; ++j) acc[i][j] = (f32x4){0.f, 0.f, 0.f, 0.f};

    int r = tid >> 2, cch = (tid & 3) * 8;

    for (int k0 = 0; k0 < Kpad; k0 += 32) {
        uint4 av0 = {0u, 0u, 0u, 0u}, av1 = {0u, 0u, 0u, 0u}, bv = {0u, 0u, 0u, 0u};
        if (row0 + r < M)      av0 = *(const uint4*)(A + (size_t)(row0 + r) * lda + k0 + cch);
        if (row0 + r + 64 < M) av1 = *(const uint4*)(A + (size_t)(row0 + r + 64) * lda + k0 + cch);
        if (col0 + r < N)      bv  = *(const uint4*)(Bt + (size_t)(col0 + r) * Kpad + k0 + cch);
        *(uint4*)(&As[r][cch]) = av0;
        *(uint4*)(&As[r + 64][cch]) = av1;
        *(uint4*)(&Bs[r][cch]) = bv;
        __syncthreads();

        short8 af[4], bfr[2];
        #pragma unroll
        for (int i = 0; i < 4; ++i)
            af[i] = *(const short8*)(&As[wm * 64 + i * 16 + l16][quad * 8]);
        #pragma unroll
        for (int j = 0; j < 2; ++j)
            bfr[j] = *(const short8*)(&Bs[wn * 32 + j * 16 + l16][quad * 8]);
        #pragma unroll
        for (int i = 0; i < 4; ++i)
            #pragma unroll
            for (int j = 0; j < 2; ++j)
                acc[i][j] = __builtin_amdgcn_mfma_f32_16x16x32_bf16(af[i], bfr[j], acc[i][j], 0, 0, 0);
        __syncthreads();
    }

    #pragma unroll
    for (int ti = 0; ti < 4; ++ti) {
        int rbase = row0 + wm * 64 + ti * 16 + quad * 4;
        #pragma unroll
        for (int tj = 0; tj < 2; ++tj) {
            int cc = col0 + wn * 32 + tj * 16 + l16;
            if (cc >= Npad_out) continue;
            #pragma unroll
            for (int reg = 0; reg < 4; ++reg) {
                int rrow = rbase + reg;
                if (rrow >= M) continue;
                float ov = 0.f;
                if (cc < N) ov = fmaxf(acc[ti][tj][reg] + bias[cc], 0.f);
                C[(size_t)rrow * ldc + cc] = __float2bfloat16(ov);
            }
        }
    }
}

static void launch_gemm_swz(const __hip_bfloat16* A, const __hip_bfloat16* Bt, const float* bias,
                            __hip_bfloat16* C, int M, int N, int Kpad, int lda, int ldc,
                            int Npad_out, hipStream_t stream)
{
    int nct = (Npad_out + 63) / 64;
    int nstrips = (M + 127) / 128;
    int G = 8 * nct * ((nstrips + 7) / 8);
    gemm_swz_kernel<<<G, 256, 0, stream>>>(A, Bt, bias, C, M, N, Kpad, lda, ldc, Npad_out,
                                           nct, nstrips);
}

// ---------------------------------------------------------------------------
// GCN: degree, norms, multi-block scan, CSR build
// ---------------------------------------------------------------------------
__global__ void deg_kernel(const int* __restrict__ dst, int* __restrict__ deg, int E)
{
    int e = blockIdx.x * 256 + threadIdx.x;
    if (e < E) atomicAdd(&deg[dst[e]], 1);
}

__global__ void dis_kernel(const int* __restrict__ deg, float* __restrict__ dis,
                           float* __restrict__ selfc, int n)
{
    int i = blockIdx.x * 256 + threadIdx.x;
    if (i < n) {
        float d = (float)deg[i] + 1.0f;
        float r = 1.0f / sqrtf(d);
        dis[i] = r;
        selfc[i] = r * r;
    }
}

__global__ __launch_bounds__(256) void scan_p1(const int* __restrict__ deg,
                                               int* __restrict__ off, int* __restrict__ bsum)
{
    __shared__ int s[256];
    int tid = threadIdx.x;
    int i = blockIdx.x * 256 + tid;
    int v = (i < NNODES) ? deg[i] : 0;
    s[tid] = v;
    __syncthreads();
    #pragma unroll
    for (int d = 1; d < 256; d <<= 1) {
        int t = (tid >= d) ? s[tid - d] : 0;
        __syncthreads();
        s[tid] += t;
        __syncthreads();
    }
    if (i < NNODES) off[i] = s[tid] - v;
    if (tid == 255) bsum[blockIdx.x] = s[255];
}

__global__ __launch_bounds__(512) void scan_p2(int* __restrict__ bsum)
{
    __shared__ int s[512];
    int tid = threadIdx.x;
    int v = (tid < NBLK1) ? bsum[tid] : 0;
    s[tid] = v;
    __syncthreads();
    #pragma unroll
    for (int d = 1; d < 512; d <<= 1) {
        int t = (tid >= d) ? s[tid - d] : 0;
        __syncthreads();
        s[tid] += t;
        __syncthreads();
    }
    if (tid < NBLK1) bsum[tid] = s[tid] - v;
}

__global__ __launch_bounds__(256) void scan_p3(int* __restrict__ off, const int* __restrict__ bsum,
                                               int* __restrict__ cur)
{
    int i = blockIdx.x * 256 + threadIdx.x;
    if (i < NNODES) {
        int v = off[i] + bsum[blockIdx.x];
        off[i] = v;
        cur[i] = v;
    }
    if (i == NNODES) off[NNODES] = NEDGES;
}

__global__ void fill_csr_kernel(const int* __restrict__ src, const int* __restrict__ dst,
                                const float* __restrict__ dis, int* __restrict__ cur,
                                int* __restrict__ csr_src, float* __restrict__ csr_w, int E)
{
    int e = blockIdx.x * 256 + threadIdx.x;
    if (e >= E) return;
    int s = src[e], d = dst[e];
    int p = atomicAdd(&cur[d], 1);
    csr_src[p] = s;
    csr_w[p] = dis[s] * dis[d];
}

// ---------------------------------------------------------------------------
// Pre-GEMM GCN aggregation: out[i] = selfc[i]*T[i] + sum_e w_e * T[src_e]
// 4-edge unrolled for load ILP.
// ---------------------------------------------------------------------------
__global__ __launch_bounds__(256) void gcn_agg2(
    const __hip_bfloat16* __restrict__ Tin, const int* __restrict__ off,
    const int* __restrict__ csr_src, const float* __restrict__ csr_w,
    const float* __restrict__ selfc, __hip_bfloat16* __restrict__ out,
    int half, int nc)
{
    int wave = threadIdx.x >> 6, lane = threadIdx.x & 63;
    int node = blockIdx.x * 4 + wave;
    if (node >= NNODES) return;
    const unsigned int* Tp = (const unsigned int*)Tin;
    unsigned int* Op = (unsigned int*)out;
    size_t rb = (size_t)node * half;
    bool m0 = lane < half;
    bool m1 = (nc > 1) && (lane + 64 < half);
    float sc = selfc[node];
    float a0x = 0.f, a0y = 0.f, a1x = 0.f, a1y = 0.f;
    float b0x = 0.f, b0y = 0.f, b1x = 0.f, b1y = 0.f;
    float c0x = 0.f, c0y = 0.f, c1x = 0.f, c1y = 0.f;
    float d0x = 0.f, d0y = 0.f, d1x = 0.f, d1y = 0.f;
    if (m0) { unsigned int v = Tp[rb + lane];      a0x = bf_lo(v) * sc; a0y = bf_hi(v) * sc; }
    if (m1) { unsigned int v = Tp[rb + lane + 64]; a1x = bf_lo(v) * sc; a1y = bf_hi(v) * sc; }
    int s0 = off[node], s1 = off[node + 1];
    int e = s0;
    for (; e + 4 <= s1; e += 4) {
        int i0 = csr_src[e], i1 = csr_src[e + 1], i2 = csr_src[e + 2], i3 = csr_src[e + 3];
        float w0 = csr_w[e], w1 = csr_w[e + 1], w2 = csr_w[e + 2], w3 = csr_w[e + 3];
        size_t p0 = (size_t)i0 * half, p1 = (size_t)i1 * half;
        size_t p2 = (size_t)i2 * half, p3 = (size_t)i3 * half;
        if (m0) {
            unsigned int v0 = Tp[p0 + lane], v1 = Tp[p1 + lane];
            unsigned int v2 = Tp[p2 + lane], v3 = Tp[p3 + lane];
            a0x += bf_lo(v0) * w0; a0y += bf_hi(v0) * w0;
            b0x += bf_lo(v1) * w1; b0y += bf_hi(v1) * w1;
            c0x += bf_lo(v2) * w2; c0y += bf_hi(v2) * w2;
            d0x += bf_lo(v3) * w3; d0y += bf_hi(v3) * w3;
        }
        if (m1) {
            unsigned int v0 = Tp[p0 + lane + 64], v1 = Tp[p1 + lane + 64];
            unsigned int v2 = Tp[p2 + lane + 64], v3 = Tp[p3 + lane + 64];
            a1x += bf_lo(v0) * w0; a1y += bf_hi(v0) * w0;
            b1x += bf_lo(v1) * w1; b1y += bf_hi(v1) * w1;
            c1x += bf_lo(v2) * w2; c1y += bf_hi(v2) * w2;
            d1x += bf_lo(v3) * w3; d1y += bf_hi(v3) * w3;
        }
    }
    for (; e + 2 <= s1; e += 2) {
        int i0 = csr_src[e], i1 = csr_src[e + 1];
        float w0 = csr_w[e], w1 = csr_w[e + 1];
        size_t p0 = (size_t)i0 * half, p1 = (size_t)i1 * half;
        if (m0) {
            unsigned int v0 = Tp[p0 + lane], v1 = Tp[p1 + lane];
            a0x += bf_lo(v0) * w0; a0y += bf_hi(v0) * w0;
            b0x += bf_lo(v1) * w1; b0y += bf_hi(v1) * w1;
        }
        if (m1) {
            unsigned int v0 = Tp[p0 + lane + 64], v1 = Tp[p1 + lane + 64];
            a1x += bf_lo(v0) * w0; a1y += bf_hi(v0) * w0;
            b1x += bf_lo(v1) * w1; b1y += bf_hi(v1) * w1;
        }
    }
    if (e < s1) {
        int i0 = csr_src[e];
        float w0 = csr_w[e];
        size_t p0 = (size_t)i0 * half;
        if (m0) { unsigned int v = Tp[p0 + lane];      a0x += bf_lo(v) * w0; a0y += bf_hi(v) * w0; }
        if (m1) { unsigned int v = Tp[p0 + lane + 64]; a1x += bf_lo(v) * w0; a1y += bf_hi(v) * w0; }
    }
    if (m0) Op[rb + lane]      = bf_pack((a0x + b0x) + (c0x + d0x), (a0y + b0y) + (c0y + d0y));
    if (m1) Op[rb + lane + 64] = bf_pack((a1x + b1x) + (c1x + d1x), (a1y + b1y) + (c1y + d1y));
}

// ---------------------------------------------------------------------------
// segment max pool (bf16 [NNODES][320] -> bf16 [NB][320]); batch sorted
// ---------------------------------------------------------------------------
__global__ __launch_bounds__(256) void pool_max_bf16(
    const __hip_bfloat16* __restrict__ H, const int* __restrict__ batch,
    __hip_bfloat16* __restrict__ g)
{
    int b = blockIdx.x;
    int lo = 0, hi = NNODES;
    while (lo < hi) { int mid = (lo + hi) >> 1; if (batch[mid] < b) lo = mid + 1; else hi = mid; }
    int s = lo;
    hi = NNODES;
    while (lo < hi) { int mid = (lo + hi) >> 1; if (batch[mid] < b + 1) lo = mid + 1; else hi = mid; }
    int e = lo;
    int tid = threadIdx.x;
    if (tid < 160) {
        const unsigned int* Hp = (const unsigned int*)H;
        float mx = 0.f, my = 0.f;
        for (int i = s; i < e; ++i) {
            unsigned int v = Hp[(size_t)i * 160 + tid];
            mx = fmaxf(mx, bf_lo(v));
            my = fmaxf(my, bf_hi(v));
        }
        ((unsigned int*)g)[(size_t)b * 160 + tid] = bf_pack(mx, my);
    }
}

// ---------------------------------------------------------------------------
// Conv branch: transpose to bf16, vectorized bucketed aggregation, weight folding
// ---------------------------------------------------------------------------
__global__ void conv_transpose_kernel(const float* __restrict__ w, __hip_bfloat16* __restrict__ wt)
{
    int idx = blockIdx.x * 256 + threadIdx.x;
    if (idx >= 256000) return;
    int o = idx / 8000;
    int rem = idx - o * 8000;
    int i = rem >> 3, k = rem & 7;
    wt[i * 256 + o * 8 + k] = __float2bfloat16(w[idx]);
}

__global__ __launch_bounds__(256) void conv_agg_kernel(
    const __hip_bfloat16* __restrict__ cwt, const int* __restrict__ target,
    __hip_bfloat16* __restrict__ aggw)
{
    __shared__ int tb_s[SEQ];
    __shared__ int cnt[26];
    __shared__ int boff[27];
    __shared__ int curs[26];
    __shared__ int bucket[SEQ];
    __shared__ float comb[3][256];
    int b = blockIdx.x, tid = threadIdx.x;
    int wave = tid >> 6, lane = tid & 63;
    const int* tb = target + b * SEQ;
    if (tid < 26) cnt[tid] = 0;
    __syncthreads();
    for (int i = tid; i < SEQ; i += 256) {
        int a = tb[i];
        tb_s[i] = a;
        atomicAdd(&cnt[a], 1);
    }
    __syncthreads();
    if (tid == 0) {
        int run = 0;
        for (int a = 0; a < 26; ++a) { boff[a] = run; curs[a] = run; run += cnt[a]; }
        boff[26] = run;
    }
    __syncthreads();
    for (int i = tid; i < SEQ; i += 256) {
        int a = tb_s[i];
        int p = atomicAdd(&curs[a], 1);
        bucket[p] = i;
    }
    __syncthreads();

    const uint2* cw = (const uint2*)cwt;
    uint2* aw = (uint2*)aggw;
    for (int a = 0; a < 26; ++a) {
        int s = boff[a], e = boff[a + 1];
        float x0 = 0.f, x1 = 0.f, x2 = 0.f, x3 = 0.f;
        float y0 = 0.f, y1 = 0.f, y2 = 0.f, y3 = 0.f;
        int j = s + wave;
        for (; j + 4 < e; j += 8) {
            uint2 v = cw[(size_t)bucket[j] * 64 + lane];
            uint2 u = cw[(size_t)bucket[j + 4] * 64 + lane];
            x0 += bf_lo(v.x); x1 += bf_hi(v.x); x2 += bf_lo(v.y); x3 += bf_hi(v.y);
            y0 += bf_lo(u.x); y1 += bf_hi(u.x); y2 += bf_lo(u.y); y3 += bf_hi(u.y);
        }
        if (j < e) {
            uint2 v = cw[(size_t)bucket[j] * 64 + lane];
            x0 += bf_lo(v.x); x1 += bf_hi(v.x); x2 += bf_lo(v.y); x3 += bf_hi(v.y);
        }
        x0 += y0; x1 += y1; x2 += y2; x3 += y3;
        if (wave > 0) {
            comb[wave - 1][lane * 4 + 0] = x0;
            comb[wave - 1][lane * 4 + 1] = x1;
            comb[wave - 1][lane * 4 + 2] = x2;
            comb[wave - 1][lane * 4 + 3] = x3;
        }
        __syncthreads();
        if (wave == 0) {
            x0 += comb[0][lane * 4 + 0] + comb[1][lane * 4 + 0] + comb[2][lane * 4 + 0];
            x1 += comb[0][lane * 4 + 1] + comb[1][lane * 4 + 1] + comb[2][lane * 4 + 1];
            x2 += comb[0][lane * 4 + 2] + comb[1][lane * 4 + 2] + comb[2][lane * 4 + 2];
            x3 += comb[0][lane * 4 + 3] + comb[1][lane * 4 + 3] + comb[2][lane * 4 + 3];
            uint2 o;
            o.x = bf_pack(x0, x1);
            o.y = bf_pack(x2, x3);
            aw[(size_t)b * 1664 + a * 64 + lane] = o;
        }
        __syncthreads();
    }
}

__global__ __launch_bounds__(128) void conv_wc_kernel(
    const float* __restrict__ emb, const float* __restrict__ w_fc, float* __restrict__ Wc)
{
    int o = blockIdx.x;
    int ak = blockIdx.y;
    int a = ak >> 3, k = ak & 7;
    int j = threadIdx.x;
    const float* wp = w_fc + (long)(o * 121) * 128 + j;
    const float* ep = emb + a * 128 + k;
    float s = 0.f;
    #pragma unroll 11
    for (int t = 0; t < 121; ++t) s += ep[t] * wp[t * 128];
    Wc[(long)(a * 256 + o * 8 + k) * 128 + j] = s;
}

__global__ void xtb_init_kernel(const float* __restrict__ b_fc, float* __restrict__ xtb)
{
    xtb[threadIdx.x] = b_fc[threadIdx.x];
}

__global__ __launch_bounds__(128) void convb_fold_kernel(
    const float* __restrict__ w_fc, const float* __restrict__ conv_b, float* __restrict__ xtb)
{
    int o = blockIdx.x, j = threadIdx.x;
    const float* wp = w_fc + (long)(o * 121) * 128 + j;
    float s = 0.f;
    for (int t = 0; t < 121; ++t) s += wp[t * 128];
    atomicAdd(&xtb[j], s * conv_b[o]);
}

__global__ void xc_convbias_kernel(const float* __restrict__ xtb, float* __restrict__ xc)
{
    int idx = blockIdx.x * 256 + threadIdx.x;
    if (idx >= NB * 128) return;
    int b = idx >> 7, j = idx & 127;
    xc[(long)b * 384 + 128 + j] = xtb[j];
}

// ---------------------------------------------------------------------------
// FG branch: attention row 0 + LayerNorm (bf16 in, bf16 padded out)
// Fb is strided: row b lives at Fb[b*13*320]
// ---------------------------------------------------------------------------
__global__ __launch_bounds__(256) void attn_ln_kernel(
    const __hip_bfloat16* __restrict__ Fb, const __hip_bfloat16* __restrict__ Kf,
    const __hip_bfloat16* __restrict__ Vf, const __hip_bfloat16* __restrict__ q0,
    const float* __restrict__ ln_g, const float* __restrict__ ln_b,
    __hip_bfloat16* __restrict__ out)
{
    int b = blockIdx.x, tid = threadIdx.x;
    __shared__ float qs[HID];
    __shared__ float sc[13];
    __shared__ float red[256];
    __shared__ float red2[256];
    __shared__ float rowv[HID];
    __shared__ float mean_s, inv_s;

    for (int d = tid; d < HID; d += 256) qs[d] = __bfloat162float(q0[(size_t)b * 320 + d]);
    __syncthreads();
    if (tid < 208) {
        int k = tid >> 4, sub = tid & 15;
        const __hip_bfloat16* kr = Kf + ((size_t)b * 13 + k) * 320;
        float p = 0.f;
        for (int d = sub; d < HID; d += 16) p += qs[d] * __bfloat162float(kr[d]);
        red[tid] = p;
    }
    __syncthreads();
    if (tid < 208 && (tid & 15) == 0) {
        float s = 0.f;
        #pragma unroll
        for (int j = 0; j < 16; ++j) s += red[tid + j];
        sc[tid >> 4] = s * 0.0577350269189626f;  // 1/sqrt(300)
    }
    __syncthreads();
    if (tid == 0) {
        float mx = sc[0];
        for (int k = 1; k < 13; ++k) mx = fmaxf(mx, sc[k]);
        float ssum = 0.f;
        for (int k = 0; k < 13; ++k) { float e = expf(sc[k] - mx); sc[k] = e; ssum += e; }
        float inv = 1.0f / ssum;
        for (int k = 0; k < 13; ++k) sc[k] *= inv;
    }
    __syncthreads();
    for (int d = tid; d < HID; d += 256) {
        float v = __bfloat162float(Fb[((size_t)b * 13) * 320 + d]);
        #pragma unroll
        for (int k = 0; k < 13; ++k)
            v += sc[k] * __bfloat162float(Vf[((size_t)b * 13 + k) * 320 + d]);
        rowv[d] = v;
    }
    __syncthreads();
    float s1 = 0.f, s2 = 0.f;
    for (int d = tid; d < HID; d += 256) { float v = rowv[d]; s1 += v; s2 += v * v; }
    red[tid] = s1; red2[tid] = s2;
    __syncthreads();
    for (int s = 128; s > 0; s >>= 1) {
        if (tid < s) { red[tid] += red[tid + s]; red2[tid] += red2[tid + s]; }
        __syncthreads();
    }
    if (tid == 0) {
        float mean = red[0] / (float)HID;
        float var = red2[0] / (float)HID - mean * mean;
        mean_s = mean;
        inv_s = 1.0f / sqrtf(var + 1e-5f);
    }
    __syncthreads();
    for (int d = tid; d < 320; d += 256) {
        float v = 0.f;
        if (d < HID) v = (rowv[d] - mean_s) * inv_s * ln_g[d] + ln_b[d];
        out[(size_t)b * 320 + d] = __float2bfloat16(v);
    }
}

// ---------------------------------------------------------------------------
// final: out[b] = X[b,:512] . out_w + out_b   (fp32)
// ---------------------------------------------------------------------------
__global__ __launch_bounds__(256) void final_out_kernel(
    const float* __restrict__ X, const float* __restrict__ w,
    const float* __restrict__ bias, float* __restrict__ out)
{
    int b = blockIdx.x, tid = threadIdx.x;
    __shared__ float red[256];
    float p = X[(long)b * 512 + tid] * w[tid] + X[(long)b * 512 + tid + 256] * w[tid + 256];
    red[tid] = p;
    __syncthreads();
    for (int s = 128; s > 0; s >>= 1) {
        if (tid < s) red[tid] += red[tid + s];
        __syncthreads();
    }
    if (tid == 0) out[b] = red[0] + bias[0];
}

// ---------------------------------------------------------------------------
// Host launcher
// ---------------------------------------------------------------------------
extern "C" void kernel_launch(void* const* d_in, const int* in_sizes, int n_in,
                              void* d_out, int out_size, void* d_ws, size_t ws_size,
                              hipStream_t stream)
{
    const float* x        = (const float*)d_in[0];
    const int*   ei       = (const int*)d_in[1];
    const int*   batch    = (const int*)d_in[2];
    const int*   target   = (const int*)d_in[3];
    const float* embs     = (const float*)d_in[4];
    const float* W1       = (const float*)d_in[5];
    const float* b1       = (const float*)d_in[6];
    const float* W2       = (const float*)d_in[7];
    const float* b2       = (const float*)d_in[8];
    const float* W3       = (const float*)d_in[9];
    const float* b3       = (const float*)d_in[10];
    const float* fc_g1_w  = (const float*)d_in[11];
    const float* fc_g1_b  = (const float*)d_in[12];
    const float* fc_g2_w  = (const float*)d_in[13];
    const float* fc_g2_b  = (const float*)d_in[14];
    const float* emb_xt   = (const float*)d_in[15];
    const float* conv_w   = (const float*)d_in[16];
    const float* conv_b   = (const float*)d_in[17];
    const float* fc1xt_w  = (const float*)d_in[18];
    const float* fc1xt_b  = (const float*)d_in[19];
    const float* fg_lin_w = (const float*)d_in[20];
    const float* fg_lin_b = (const float*)d_in[21];
    const float* Wq       = (const float*)d_in[22];
    const float* Wk       = (const float*)d_in[23];
    const float* Wv       = (const float*)d_in[24];
    const float* ln_g     = (const float*)d_in[25];
    const float* ln_b     = (const float*)d_in[26];
    const float* fg_out_w = (const float*)d_in[27];
    const float* fg_out_b = (const float*)d_in[28];
    const float* fc1_w    = (const float*)d_in[29];
    const float* fc1_b    = (const float*)d_in[30];
    const float* fc2_w    = (const float*)d_in[31];
    const float* fc2_b    = (const float*)d_in[32];
    const float* out_w    = (const float*)d_in[33];
    const float* out_b    = (const float*)d_in[34];

    const int* src = ei;
    const int* dst = ei + NEDGES;
    typedef __hip_bfloat16 bf;

    // ---- workspace carve (256-B aligned bump allocator) ----
    char* p = (char*)d_ws;
    auto alloc = [&](size_t bytes) { char* r = p; p += (bytes + 255) & ~(size_t)255; return r; };
    bf*   xb      = (bf*)alloc((size_t)NNODES * 96 * 2);
    bf*   T       = (bf*)alloc((size_t)NNODES * 160 * 2);
    bf*   H       = (bf*)alloc((size_t)NNODES * 320 * 2);
    int*  deg     = (int*)alloc(NNODES * 4);                // reused as CSR cursor
    float* dis    = (float*)alloc(NNODES * 4);
    float* selfc  = (float*)alloc(NNODES * 4);
    int*  off     = (int*)alloc((NNODES + 1) * 4);
    int*  bsum    = (int*)alloc(512 * 4);
    int*  csr_src = (int*)alloc(NEDGES * 4);
    float* csr_w  = (float*)alloc(NEDGES * 4);
    bf*   w1t     = (bf*)alloc(78 * 96 * 2);
    bf*   w2t     = (bf*)alloc(156 * 96 * 2);
    bf*   w3t     = (bf*)alloc(312 * 160 * 2);
    bf*   fcg1t   = (bf*)alloc(1024 * 320 * 2);
    bf*   fcg2t   = (bf*)alloc(128 * 1024 * 2);
    bf*   fglint  = (bf*)alloc(300 * 160 * 2);
    bf*   wkt     = (bf*)alloc(300 * 320 * 2);
    bf*   wvt     = (bf*)alloc(300 * 320 * 2);
    bf*   wqt     = (bf*)alloc(300 * 320 * 2);
    bf*   fgoutt  = (bf*)alloc(128 * 320 * 2);
    bf*   fc1t    = (bf*)alloc(1024 * 384 * 2);
    bf*   fc2t    = (bf*)alloc(512 * 1024 * 2);
    bf*   fglwb   = (bf*)alloc(133 * 320 * 2);
    bf*   wk2t    = (bf*)alloc(300 * 160 * 2);
    bf*   wv2t    = (bf*)alloc(300 * 160 * 2);
    bf*   wq2t    = (bf*)alloc(300 * 160 * 2);
    float* bk2    = (float*)alloc(300 * 4);
    float* bv2    = (float*)alloc(300 * 4);
    float* bq2    = (float*)alloc(300 * 4);
    bf*   g       = (bf*)alloc((size_t)NB * 320 * 2);
    bf*   G1b     = (bf*)alloc((size_t)NB * 1024 * 2);
    bf*   embsb   = (bf*)alloc((size_t)NB * 13 * 160 * 2);
    bf*   Fbuf    = (bf*)alloc((size_t)NB * 13 * 320 * 2);
    bf*   Kbuf    = (bf*)alloc((size_t)NB * 13 * 320 * 2);
    bf*   Vbuf    = (bf*)alloc((size_t)NB * 13 * 320 * 2);
    bf*   Qbuf    = (bf*)alloc((size_t)NB * 320 * 2);
    bf*   f2row   = (bf*)alloc((size_t)NB * 320 * 2);
    float* xc     = (float*)alloc((size_t)NB * 384 * 4);
    bf*   xcb     = (bf*)alloc((size_t)NB * 384 * 2);
    float* F2     = (float*)alloc((size_t)NB * 512 * 4);
    bf*   cwt     = (bf*)alloc(256000 * 2);
    bf*   aggwb   = (bf*)alloc((size_t)NB * 6656 * 2);
    float* Wc     = (float*)alloc((size_t)6656 * 128 * 4);
    bf*   Wct     = (bf*)alloc((size_t)128 * 6656 * 2);
    float* xtb    = (float*)alloc(128 * 4);

    // ---- degree / norms / CSR (multi-block scan) ----
    hipMemsetAsync(deg, 0, NNODES * sizeof(int), stream);
    deg_kernel<<<(NEDGES + 255) / 256, 256, 0, stream>>>(dst, deg, NEDGES);
    dis_kernel<<<(NNODES + 255) / 256, 256, 0, stream>>>(deg, dis, selfc, NNODES);
    scan_p1<<<NBLK1, 256, 0, stream>>>(deg, off, bsum);
    scan_p2<<<1, 512, 0, stream>>>(bsum);
    scan_p3<<<NBLK1, 256, 0, stream>>>(off, bsum, deg);   // deg becomes cursor
    fill_csr_kernel<<<(NEDGES + 255) / 256, 256, 0, stream>>>(src, dst, dis, deg, csr_src, csr_w, NEDGES);

    // ---- weight transposes (one batched launch) + input converts ----
    {
        TBatch tb;
        const float* srcs[12] = {W1, W2, W3, fc_g1_w, fc_g2_w, fg_lin_w, Wk, Wv, Wq, fg_out_w, fc1_w, fc2_w};
        bf* dsts[12]          = {w1t, w2t, w3t, fcg1t, fcg2t, fglint, wkt, wvt, wqt, fgoutt, fc1t, fc2t};
        int Ks[12]    = {78, 78, 156, 312, 1024, 133, 300, 300, 300, 300, 384, 1024};
        int Ns[12]    = {78, 156, 312, 1024, 128, 300, 300, 300, 300, 128, 1024, 512};
        int Kpads[12] = {96, 96, 160, 320, 1024, 160, 320, 320, 320, 320, 384, 1024};
        int bs = 0;
        for (int i = 0; i < 12; ++i) {
            tb.src[i] = srcs[i]; tb.dst[i] = dsts[i];
            tb.K[i] = Ks[i]; tb.N[i] = Ns[i]; tb.Kpad[i] = Kpads[i];
            tb.bstart[i] = bs;
            bs += (int)(((long)Ns[i] * Kpads[i] + 255) / 256);
        }
        tb.bstart[12] = bs;
        transpose_batch_kernel<<<bs, 256, 0, stream>>>(tb);
    }
    cvt_pad_kernel<<<((long)NNODES * 96 + 255) / 256, 256, 0, stream>>>(x, xb, NNODES, 78, 96);
    cvt_pad_kernel<<<((long)NB * 13 * 160 + 255) / 256, 256, 0, stream>>>(embs, embsb, NB * 13, 133, 160);

    // ---- GCN layers: agg(input) -> XCD-swizzled 128x64 MFMA GEMM ----
    int agrid = (NNODES + 3) / 4;
    gcn_agg2<<<agrid, 256, 0, stream>>>(xb, off, csr_src, csr_w, selfc, T, 48, 1);
    launch_gemm_swz(T, w1t, b1, H, NNODES, 78, 96, 96, 96, 96, stream);

    gcn_agg2<<<agrid, 256, 0, stream>>>(H, off, csr_src, csr_w, selfc, T, 48, 1);
    launch_gemm_swz(T, w2t, b2, H, NNODES, 156, 96, 96, 160, 160, stream);

    gcn_agg2<<<agrid, 256, 0, stream>>>(H, off, csr_src, csr_w, selfc, T, 80, 2);
    launch_gemm_swz(T, w3t, b3, H, NNODES, 312, 160, 160, 320, 320, stream);

    // ---- global max pool + graph MLP ----
    pool_max_bf16<<<NB, 256, 0, stream>>>(H, batch, g);
    launch_gemm_bf16(g, fcg1t, fc_g1_b, G1b, NB, 1024, 320, 320, 1024, 1024, 1, 1, 1, stream);
    launch_gemm_bf16(G1b, fcg2t, fc_g2_b, xc, NB, 128, 1024, 1024, 384, 128, 0, 0, 1, stream);

    // ---- conv branch (folded; split-K MFMA accumulates into xc cols 128..255) ----
    conv_transpose_kernel<<<(256000 + 255) / 256, 256, 0, stream>>>(conv_w, cwt);
    conv_agg_kernel<<<NB, 256, 0, stream>>>(cwt, target, aggwb);
    conv_wc_kernel<<<dim3(32, 208), 128, 0, stream>>>(emb_xt, fc1xt_w, Wc);
    transpose_cvt_kernel<<<((long)128 * 6656 + 255) / 256, 256, 0, stream>>>(Wc, Wct, 6656, 128, 6656);
    xtb_init_kernel<<<1, 128, 0, stream>>>(fc1xt_b, xtb);
    convb_fold_kernel<<<32, 128, 0, stream>>>(fc1xt_w, conv_b, xtb);
    xc_convbias_kernel<<<(NB * 128 + 255) / 256, 256, 0, stream>>>(xtb, xc);
    launch_gemm_bf16(aggwb, Wct, nullptr, xc + 128, NB, 128, 6656, 6656, 384, 128, 0, 0, 8, stream);

    // ---- FG branch (K/V/Q from embs via folded weights; F only at rows b*13) ----
    cvt_pad_kernel<<<(133 * 320 + 255) / 256, 256, 0, stream>>>(fg_lin_w, fglwb, 133, 300, 320);
    launch_gemm_bf16(wkt, fglwb, nullptr, wk2t, 300, 133, 320, 320, 160, 160, 0, 1, 1, stream);
    launch_gemm_bf16(wvt, fglwb, nullptr, wv2t, 300, 133, 320, 320, 160, 160, 0, 1, 1, stream);
    launch_gemm_bf16(wqt, fglwb, nullptr, wq2t, 300, 133, 320, 320, 160, 160, 0, 1, 1, stream);
    bias_fold_t_kernel<<<300, 256, 0, stream>>>(fg_lin_b, wkt, bk2, 300, 320, 300);
    bias_fold_t_kernel<<<300, 256, 0, stream>>>(fg_lin_b, wvt, bv2, 300, 320, 300);
    bias_fold_t_kernel<<<300, 256, 0, stream>>>(fg_lin_b, wqt, bq2, 300, 320, 300);
    // F needed only at rows b*13 (attention residual row 0): strided M=NB GEMM
    launch_gemm_bf16(embsb, fglint, fg_lin_b, Fbuf, NB, 300, 160, 13 * 160, 13 * 320, 320, 0, 1, 1, stream);
    launch_gemm_mt(embsb, wk2t, bk2, Kbuf, NB * 13, 300, 160, 160, 320, 320, 0, stream);
    launch_gemm_mt(embsb, wv2t, bv2, Vbuf, NB * 13, 300, 160, 160, 320, 320, 0, stream);
    launch_gemm_bf16(embsb, wq2t, bq2, Qbuf, NB, 300, 160, 13 * 160, 320, 320, 0, 1, 1, stream);
    attn_ln_kernel<<<NB, 256, 0, stream>>>(Fbuf, Kbuf, Vbuf, Qbuf, ln_g, ln_b, f2row);
    launch_gemm_bf16(f2row, fgoutt, fg_out_b, xc + 256, NB, 128, 320, 320, 384, 128, 0, 0, 1, stream);

    // ---- head ----
    cvt_pad_kernel<<<((long)NB * 384 + 255) / 256, 256, 0, stream>>>(xc, xcb, NB, 384, 384);
    launch_gemm_bf16(xcb, fc1t, fc1_b, G1b, NB, 1024, 384, 384, 1024, 1024, 1, 1, 1, stream);
    launch_gemm_bf16(G1b, fc2t, fc2_b, F2, NB, 512, 1024, 1024, 512, 512, 1, 0, 1, stream);
    final_out_kernel<<<NB, 256, 0, stream>>>(F2, out_w, out_b, (float*)d_out);
}

// Round 15
// 714.555 us; speedup vs baseline: 1.0948x; 1.0437x over previous
//
#include <hip/hip_runtime.h>
#include <hip/hip_bf16.h>
#include <math.h>

// ---------------------------------------------------------------------------
// Problem constants
// ---------------------------------------------------------------------------
#define NNODES 100000
#define NEDGES 400000
#define NB     1024
#define SEQ    1000
#define HID    300
#define NBLK1  ((NNODES + 255) / 256)   // 391

typedef __attribute__((ext_vector_type(8))) short short8;   // 8 bf16 (4 VGPRs)
typedef __attribute__((ext_vector_type(4))) float f32x4;    // MFMA acc

__device__ __forceinline__ float bf_lo(unsigned int v) { return __uint_as_float(v << 16); }
__device__ __forceinline__ float bf_hi(unsigned int v) { return __uint_as_float(v & 0xffff0000u); }
__device__ __forceinline__ unsigned int bf_pack(float lo, float hi) {
    __hip_bfloat16 a = __float2bfloat16(lo), b = __float2bfloat16(hi);
    unsigned short ua = *(unsigned short*)&a, ub = *(unsigned short*)&b;
    return (unsigned int)ua | ((unsigned int)ub << 16);
}

// ---------------------------------------------------------------------------
// fp32 [M][K] -> bf16 [M][Kpad] (zero-padded)
// ---------------------------------------------------------------------------
__global__ void cvt_pad_kernel(const float* __restrict__ in, __hip_bfloat16* __restrict__ out,
                               int M, int K, int Kpad)
{
    long idx = (long)blockIdx.x * 256 + threadIdx.x;
    if (idx >= (long)M * Kpad) return;
    int m = idx / Kpad, k = idx % Kpad;
    out[idx] = __float2bfloat16(k < K ? in[(long)m * K + k] : 0.f);
}

// batched cvt_pad: 3 descriptors, one launch
struct CBatch {
    const float* src[3];
    __hip_bfloat16* dst[3];
    int M[3]; int K[3]; int Kpad[3];
    int bstart[4];
};

__global__ __launch_bounds__(256) void cvt_batch_kernel(CBatch cb)
{
    int blk = blockIdx.x;
    int d = 0;
    while (d < 2 && blk >= cb.bstart[d + 1]) ++d;
    long idx = (long)(blk - cb.bstart[d]) * 256 + threadIdx.x;
    long tot = (long)cb.M[d] * cb.Kpad[d];
    if (idx >= tot) return;
    int Kpad = cb.Kpad[d];
    int m = idx / Kpad, k = idx % Kpad;
    cb.dst[d][idx] = __float2bfloat16(k < cb.K[d] ? cb.src[d][(long)m * cb.K[d] + k] : 0.f);
}

// fp32 [K][N] row-major -> bf16 Bt [N][Kpad] (zero-padded)
__global__ void transpose_cvt_kernel(const float* __restrict__ in, __hip_bfloat16* __restrict__ out,
                                     int K, int N, int Kpad)
{
    long idx = (long)blockIdx.x * 256 + threadIdx.x;
    if (idx >= (long)N * Kpad) return;
    int n = idx / Kpad, k = idx % Kpad;
    out[idx] = __float2bfloat16(k < K ? in[(long)k * N + n] : 0.f);
}

// Batched weight transpose: 12 descriptors in one launch
struct TBatch {
    const float* src[12];
    __hip_bfloat16* dst[12];
    int K[12]; int N[12]; int Kpad[12];
    int bstart[13];
};

__global__ __launch_bounds__(256) void transpose_batch_kernel(TBatch tb)
{
    int blk = blockIdx.x;
    int d = 0;
    while (d < 11 && blk >= tb.bstart[d + 1]) ++d;
    long idx = (long)(blk - tb.bstart[d]) * 256 + threadIdx.x;
    long tot = (long)tb.N[d] * tb.Kpad[d];
    if (idx >= tot) return;
    int Kpad = tb.Kpad[d];
    int n = idx / Kpad, k = idx % Kpad;
    tb.dst[d][idx] = __float2bfloat16(k < tb.K[d] ? tb.src[d][(long)k * tb.N[d] + n] : 0.f);
}

// batched bias fold from TRANSPOSED bf16 weights: out_d[n] = sum_k b[k] * Wt_d[n][k]
struct BF3 { const __hip_bfloat16* Wt[3]; float* out[3]; };

__global__ __launch_bounds__(256) void bias_fold3_kernel(const float* __restrict__ b, BF3 p)
{
    int d = blockIdx.x / 300;
    int n = blockIdx.x % 300;
    __shared__ float red[256];
    int tid = threadIdx.x;
    const __hip_bfloat16* Wt = p.Wt[d];
    float s = 0.f;
    for (int k = tid; k < 300; k += 256)
        s += b[k] * __bfloat162float(Wt[(size_t)n * 320 + k]);
    red[tid] = s;
    __syncthreads();
    #pragma unroll
    for (int st = 128; st > 0; st >>= 1) {
        if (tid < st) red[tid] += red[tid + st];
        __syncthreads();
    }
    if (tid == 0) p.out[d][n] = red[0];
}

// ---------------------------------------------------------------------------
// BF16 MFMA GEMM (TN), 64x64 tile: C = act(A @ Bt^T + bias)
// ---------------------------------------------------------------------------
__global__ __launch_bounds__(256) void gemm_bf16_kernel(
    const __hip_bfloat16* __restrict__ A, const __hip_bfloat16* __restrict__ Bt,
    const float* __restrict__ bias, void* __restrict__ C,
    int M, int N, int Kpad, int lda, int ldc, int Npad_out,
    int relu, int outbf, int chunk)
{
    __shared__ __align__(16) __hip_bfloat16 As[64][40];
    __shared__ __align__(16) __hip_bfloat16 Bs[64][40];
    int tid = threadIdx.x;
    int wave = tid >> 6, lane = tid & 63;
    int wm = wave >> 1, wn = wave & 1;
    int quad = lane >> 4, l16 = lane & 15;
    int row0 = blockIdx.y * 64, col0 = blockIdx.x * 64;

    int kbeg = 0, kend = Kpad;
    if (chunk > 0) { kbeg = blockIdx.z * chunk; kend = kbeg + chunk; if (kend > Kpad) kend = Kpad; }

    f32x4 acc[2][2];
    #pragma unroll
    for (int i = 0; i < 2; ++i)
        #pragma unroll
        for (int j = 0; j < 2; ++j) acc[i][j] = (f32x4){0.f, 0.f, 0.f, 0.f};

    int r = tid >> 2, cch = (tid & 3) * 8;

    for (int k0 = kbeg; k0 < kend; k0 += 32) {
        uint4 av = {0u, 0u, 0u, 0u};
        if (row0 + r < M) av = *(const uint4*)(A + (size_t)(row0 + r) * lda + k0 + cch);
        *(uint4*)(&As[r][cch]) = av;
        uint4 bv = {0u, 0u, 0u, 0u};
        if (col0 + r < N) bv = *(const uint4*)(Bt + (size_t)(col0 + r) * Kpad + k0 + cch);
        *(uint4*)(&Bs[r][cch]) = bv;
        __syncthreads();

        short8 a0 = *(const short8*)(&As[wm * 32 + l16][quad * 8]);
        short8 a1 = *(const short8*)(&As[wm * 32 + 16 + l16][quad * 8]);
        short8 b0 = *(const short8*)(&Bs[wn * 32 + l16][quad * 8]);
        short8 b1 = *(const short8*)(&Bs[wn * 32 + 16 + l16][quad * 8]);
        acc[0][0] = __builtin_amdgcn_mfma_f32_16x16x32_bf16(a0, b0, acc[0][0], 0, 0, 0);
        acc[0][1] = __builtin_amdgcn_mfma_f32_16x16x32_bf16(a0, b1, acc[0][1], 0, 0, 0);
        acc[1][0] = __builtin_amdgcn_mfma_f32_16x16x32_bf16(a1, b0, acc[1][0], 0, 0, 0);
        acc[1][1] = __builtin_amdgcn_mfma_f32_16x16x32_bf16(a1, b1, acc[1][1], 0, 0, 0);
        __syncthreads();
    }

    #pragma unroll
    for (int ti = 0; ti < 2; ++ti) {
        int rbase = row0 + wm * 32 + ti * 16 + quad * 4;
        #pragma unroll
        for (int tj = 0; tj < 2; ++tj) {
            int cc = col0 + wn * 32 + tj * 16 + l16;
            if (cc >= Npad_out) continue;
            #pragma unroll
            for (int reg = 0; reg < 4; ++reg) {
                int rr = rbase + reg;
                if (rr >= M) continue;
                float v = acc[ti][tj][reg];
                if (chunk > 0) {
                    if (cc < N) atomicAdd((float*)C + (size_t)rr * ldc + cc, v);
                } else {
                    float ov = 0.f;
                    if (cc < N) {
                        if (bias) v += bias[cc];
                        if (relu) v = fmaxf(v, 0.f);
                        ov = v;
                    }
                    if (outbf) ((__hip_bfloat16*)C)[(size_t)rr * ldc + cc] = __float2bfloat16(ov);
                    else       ((float*)C)[(size_t)rr * ldc + cc] = ov;
                }
            }
        }
    }
}

static void launch_gemm_bf16(const __hip_bfloat16* A, const __hip_bfloat16* Bt, const float* bias,
                             void* C, int M, int N, int Kpad, int lda, int ldc, int Npad_out,
                             int relu, int outbf, int splitz, hipStream_t stream)
{
    int cover = N > Npad_out ? N : Npad_out;
    int chunk = (splitz > 1) ? (Kpad / splitz) : 0;
    dim3 grid((cover + 63) / 64, (M + 63) / 64, splitz > 1 ? splitz : 1);
    gemm_bf16_kernel<<<grid, 256, 0, stream>>>(A, Bt, bias, C, M, N, Kpad, lda, ldc, Npad_out,
                                               relu, outbf, chunk);
}

// ---------------------------------------------------------------------------
// Batched 64x64 GEMM (z selects descriptor). bf16 out, no relu.
// ---------------------------------------------------------------------------
struct GB { const __hip_bfloat16* A; const __hip_bfloat16* Bt; const float* bias;
            __hip_bfloat16* C; int M, N, Kpad, lda, ldc, Npad; };
struct GB3 { GB g[3]; };

__global__ __launch_bounds__(256) void gemm_batch64_kernel(GB3 p)
{
    GB gb = p.g[blockIdx.z];
    __shared__ __align__(16) __hip_bfloat16 As[64][40];
    __shared__ __align__(16) __hip_bfloat16 Bs[64][40];
    int tid = threadIdx.x;
    int wave = tid >> 6, lane = tid & 63;
    int wm = wave >> 1, wn = wave & 1;
    int quad = lane >> 4, l16 = lane & 15;
    int row0 = blockIdx.y * 64, col0 = blockIdx.x * 64;

    f32x4 acc[2][2];
    #pragma unroll
    for (int i = 0; i < 2; ++i)
        #pragma unroll
        for (int j = 0; j < 2; ++j) acc[i][j] = (f32x4){0.f, 0.f, 0.f, 0.f};

    int r = tid >> 2, cch = (tid & 3) * 8;

    for (int k0 = 0; k0 < gb.Kpad; k0 += 32) {
        uint4 av = {0u, 0u, 0u, 0u};
        if (row0 + r < gb.M) av = *(const uint4*)(gb.A + (size_t)(row0 + r) * gb.lda + k0 + cch);
        *(uint4*)(&As[r][cch]) = av;
        uint4 bv = {0u, 0u, 0u, 0u};
        if (col0 + r < gb.N) bv = *(const uint4*)(gb.Bt + (size_t)(col0 + r) * gb.Kpad + k0 + cch);
        *(uint4*)(&Bs[r][cch]) = bv;
        __syncthreads();

        short8 a0 = *(const short8*)(&As[wm * 32 + l16][quad * 8]);
        short8 a1 = *(const short8*)(&As[wm * 32 + 16 + l16][quad * 8]);
        short8 b0 = *(const short8*)(&Bs[wn * 32 + l16][quad * 8]);
        short8 b1 = *(const short8*)(&Bs[wn * 32 + 16 + l16][quad * 8]);
        acc[0][0] = __builtin_amdgcn_mfma_f32_16x16x32_bf16(a0, b0, acc[0][0], 0, 0, 0);
        acc[0][1] = __builtin_amdgcn_mfma_f32_16x16x32_bf16(a0, b1, acc[0][1], 0, 0, 0);
        acc[1][0] = __builtin_amdgcn_mfma_f32_16x16x32_bf16(a1, b0, acc[1][0], 0, 0, 0);
        acc[1][1] = __builtin_amdgcn_mfma_f32_16x16x32_bf16(a1, b1, acc[1][1], 0, 0, 0);
        __syncthreads();
    }

    #pragma unroll
    for (int ti = 0; ti < 2; ++ti) {
        int rbase = row0 + wm * 32 + ti * 16 + quad * 4;
        #pragma unroll
        for (int tj = 0; tj < 2; ++tj) {
            int cc = col0 + wn * 32 + tj * 16 + l16;
            if (cc >= gb.Npad) continue;
            #pragma unroll
            for (int reg = 0; reg < 4; ++reg) {
                int rr = rbase + reg;
                if (rr >= gb.M) continue;
                float ov = 0.f;
                if (cc < gb.N) {
                    float v = acc[ti][tj][reg];
                    if (gb.bias) v += gb.bias[cc];
                    ov = v;
                }
                gb.C[(size_t)rr * gb.ldc + cc] = __float2bfloat16(ov);
            }
        }
    }
}

// ---------------------------------------------------------------------------
// Batched 128x64 GEMM (z selects descriptor). bf16 out, no relu. (K/V)
// ---------------------------------------------------------------------------
__global__ __launch_bounds__(256) void gemm_mtb_kernel(GB3 p)
{
    GB gb = p.g[blockIdx.z];
    __shared__ __align__(16) __hip_bfloat16 As[128][40];
    __shared__ __align__(16) __hip_bfloat16 Bs[64][40];
    int tid = threadIdx.x;
    int wave = tid >> 6, lane = tid & 63;
    int wm = wave >> 1, wn = wave & 1;
    int quad = lane >> 4, l16 = lane & 15;
    int row0 = blockIdx.y * 128, col0 = blockIdx.x * 64;

    f32x4 acc[4][2];
    #pragma unroll
    for (int i = 0; i < 4; ++i)
        #pragma unroll
        for (int j = 0; j < 2; ++j) acc[i][j] = (f32x4){0.f, 0.f, 0.f, 0.f};

    int r = tid >> 2, cch = (tid & 3) * 8;

    for (int k0 = 0; k0 < gb.Kpad; k0 += 32) {
        uint4 av0 = {0u, 0u, 0u, 0u}, av1 = {0u, 0u, 0u, 0u}, bv = {0u, 0u, 0u, 0u};
        if (row0 + r < gb.M)      av0 = *(const uint4*)(gb.A + (size_t)(row0 + r) * gb.lda + k0 + cch);
        if (row0 + r + 64 < gb.M) av1 = *(const uint4*)(gb.A + (size_t)(row0 + r + 64) * gb.lda + k0 + cch);
        if (col0 + r < gb.N)      bv  = *(const uint4*)(gb.Bt + (size_t)(col0 + r) * gb.Kpad + k0 + cch);
        *(uint4*)(&As[r][cch]) = av0;
        *(uint4*)(&As[r + 64][cch]) = av1;
        *(uint4*)(&Bs[r][cch]) = bv;
        __syncthreads();

        short8 af[4], bfr[2];
        #pragma unroll
        for (int i = 0; i < 4; ++i)
            af[i] = *(const short8*)(&As[wm * 64 + i * 16 + l16][quad * 8]);
        #pragma unroll
        for (int j = 0; j < 2; ++j)
            bfr[j] = *(const short8*)(&Bs[wn * 32 + j * 16 + l16][quad * 8]);
        #pragma unroll
        for (int i = 0; i < 4; ++i)
            #pragma unroll
            for (int j = 0; j < 2; ++j)
                acc[i][j] = __builtin_amdgcn_mfma_f32_16x16x32_bf16(af[i], bfr[j], acc[i][j], 0, 0, 0);
        __syncthreads();
    }

    #pragma unroll
    for (int ti = 0; ti < 4; ++ti) {
        int rbase = row0 + wm * 64 + ti * 16 + quad * 4;
        #pragma unroll
        for (int tj = 0; tj < 2; ++tj) {
            int cc = col0 + wn * 32 + tj * 16 + l16;
            if (cc >= gb.Npad) continue;
            #pragma unroll
            for (int reg = 0; reg < 4; ++reg) {
                int rr = rbase + reg;
                if (rr >= gb.M) continue;
                float ov = 0.f;
                if (cc < gb.N) {
                    float v = acc[ti][tj][reg];
                    if (gb.bias) v += gb.bias[cc];
                    ov = v;
                }
                gb.C[(size_t)rr * gb.ldc + cc] = __float2bfloat16(ov);
            }
        }
    }
}

// ---------------------------------------------------------------------------
// Node-layer GEMM: 128x64 staged tile + XCD-aware mod-8 swizzle
// ---------------------------------------------------------------------------
__global__ __launch_bounds__(256) void gemm_swz_kernel(
    const __hip_bfloat16* __restrict__ A, const __hip_bfloat16* __restrict__ Bt,
    const float* __restrict__ bias, __hip_bfloat16* __restrict__ C,
    int M, int N, int Kpad, int lda, int ldc, int Npad_out, int nct, int nstrips)
{
    int id = blockIdx.x;
    int rr8 = id & 7, q = id >> 3;
    int c = q % nct, sgrp = q / nct;
    int s = sgrp * 8 + rr8;
    if (s >= nstrips) return;
    int row0 = s * 128, col0 = c * 64;

    __shared__ __align__(16) __hip_bfloat16 As[128][40];
    __shared__ __align__(16) __hip_bfloat16 Bs[64][40];
    int tid = threadIdx.x;
    int wave = tid >> 6, lane = tid & 63;
    int wm = wave >> 1, wn = wave & 1;
    int quad = lane >> 4, l16 = lane & 15;

    f32x4 acc[4][2];
    #pragma unroll
    for (int i = 0; i < 4; ++i)
        #pragma unroll
        for (int j = 0; j < 2; ++j) acc[i][j] = (f32x4){0.f, 0.f, 0.f, 0.f};

    int r = tid >> 2, cch = (tid & 3) * 8;

    for (int k0 = 0; k0 < Kpad; k0 += 32) {
        uint4 av0 = {0u, 0u, 0u, 0u}, av1 = {0u, 0u, 0u, 0u}, bv = {0u, 0u, 0u, 0u};
        if (row0 + r < M)      av0 = *(const uint4*)(A + (size_t)(row0 + r) * lda + k0 + cch);
        if (row0 + r + 64 < M) av1 = *(const uint4*)(A + (size_t)(row0 + r + 64) * lda + k0 + cch);
        if (col0 + r < N)      bv  = *(const uint4*)(Bt + (size_t)(col0 + r) * Kpad + k0 + cch);
        *(uint4*)(&As[r][cch]) = av0;
        *(uint4*)(&As[r + 64][cch]) = av1;
        *(uint4*)(&Bs[r][cch]) = bv;
        __syncthreads();

        short8 af[4], bfr[2];
        #pragma unroll
        for (int i = 0; i < 4; ++i)
            af[i] = *(const short8*)(&As[wm * 64 + i * 16 + l16][quad * 8]);
        #pragma unroll
        for (int j = 0; j < 2; ++j)
            bfr[j] = *(const short8*)(&Bs[wn * 32 + j * 16 + l16][quad * 8]);
        #pragma unroll
        for (int i = 0; i < 4; ++i)
            #pragma unroll
            for (int j = 0; j < 2; ++j)
                acc[i][j] = __builtin_amdgcn_mfma_f32_16x16x32_bf16(af[i], bfr[j], acc[i][j], 0, 0, 0);
        __syncthreads();
    }

    #pragma unroll
    for (int ti = 0; ti < 4; ++ti) {
        int rbase = row0 + wm * 64 + ti * 16 + quad * 4;
        #pragma unroll
        for (int tj = 0; tj < 2; ++tj) {
            int cc = col0 + wn * 32 + tj * 16 + l16;
            if (cc >= Npad_out) continue;
            #pragma unroll
            for (int reg = 0; reg < 4; ++reg) {
                int rrow = rbase + reg;
                if (rrow >= M) continue;
                float ov = 0.f;
                if (cc < N) ov = fmaxf(acc[ti][tj][reg] + bias[cc], 0.f);
                C[(size_t)rrow * ldc + cc] = __float2bfloat16(ov);
            }
        }
    }
}

static void launch_gemm_swz(const __hip_bfloat16* A, const __hip_bfloat16* Bt, const float* bias,
                            __hip_bfloat16* C, int M, int N, int Kpad, int lda, int ldc,
                            int Npad_out, hipStream_t stream)
{
    int nct = (Npad_out + 63) / 64;
    int nstrips = (M + 127) / 128;
    int G = 8 * nct * ((nstrips + 7) / 8);
    gemm_swz_kernel<<<G, 256, 0, stream>>>(A, Bt, bias, C, M, N, Kpad, lda, ldc, Npad_out,
                                           nct, nstrips);
}

// ---------------------------------------------------------------------------
// GCN: degree, norms(+scan p1 fused), multi-block scan, CSR build
// ---------------------------------------------------------------------------
__global__ void deg_kernel(const int* __restrict__ dst, int* __restrict__ deg, int E)
{
    int e = blockIdx.x * 256 + threadIdx.x;
    if (e < E) atomicAdd(&deg[dst[e]], 1);
}

// phase 1 + dis/selfc fused
__global__ __launch_bounds__(256) void scan_p1(const int* __restrict__ deg,
                                               int* __restrict__ off, int* __restrict__ bsum,
                                               float* __restrict__ dis, float* __restrict__ selfc)
{
    __shared__ int s[256];
    int tid = threadIdx.x;
    int i = blockIdx.x * 256 + tid;
    int v = (i < NNODES) ? deg[i] : 0;
    if (i < NNODES) {
        float d = (float)v + 1.0f;
        float r = 1.0f / sqrtf(d);
        dis[i] = r;
        selfc[i] = r * r;
    }
    s[tid] = v;
    __syncthreads();
    #pragma unroll
    for (int d = 1; d < 256; d <<= 1) {
        int t = (tid >= d) ? s[tid - d] : 0;
        __syncthreads();
        s[tid] += t;
        __syncthreads();
    }
    if (i < NNODES) off[i] = s[tid] - v;
    if (tid == 255) bsum[blockIdx.x] = s[255];
}

__global__ __launch_bounds__(512) void scan_p2(int* __restrict__ bsum)
{
    __shared__ int s[512];
    int tid = threadIdx.x;
    int v = (tid < NBLK1) ? bsum[tid] : 0;
    s[tid] = v;
    __syncthreads();
    #pragma unroll
    for (int d = 1; d < 512; d <<= 1) {
        int t = (tid >= d) ? s[tid - d] : 0;
        __syncthreads();
        s[tid] += t;
        __syncthreads();
    }
    if (tid < NBLK1) bsum[tid] = s[tid] - v;
}

__global__ __launch_bounds__(256) void scan_p3(int* __restrict__ off, const int* __restrict__ bsum,
                                               int* __restrict__ cur)
{
    int i = blockIdx.x * 256 + threadIdx.x;
    if (i < NNODES) {
        int v = off[i] + bsum[blockIdx.x];
        off[i] = v;
        cur[i] = v;
    }
    if (i == NNODES) off[NNODES] = NEDGES;
}

__global__ void fill_csr_kernel(const int* __restrict__ src, const int* __restrict__ dst,
                                const float* __restrict__ dis, int* __restrict__ cur,
                                int* __restrict__ csr_src, float* __restrict__ csr_w, int E)
{
    int e = blockIdx.x * 256 + threadIdx.x;
    if (e >= E) return;
    int s = src[e], d = dst[e];
    int p = atomicAdd(&cur[d], 1);
    csr_src[p] = s;
    csr_w[p] = dis[s] * dis[d];
}

// ---------------------------------------------------------------------------
// Pre-GEMM GCN aggregation: out[i] = selfc[i]*T[i] + sum_e w_e * T[src_e]
// 4-edge unrolled for load ILP.
// ---------------------------------------------------------------------------
__global__ __launch_bounds__(256) void gcn_agg2(
    const __hip_bfloat16* __restrict__ Tin, const int* __restrict__ off,
    const int* __restrict__ csr_src, const float* __restrict__ csr_w,
    const float* __restrict__ selfc, __hip_bfloat16* __restrict__ out,
    int half, int nc)
{
    int wave = threadIdx.x >> 6, lane = threadIdx.x & 63;
    int node = blockIdx.x * 4 + wave;
    if (node >= NNODES) return;
    const unsigned int* Tp = (const unsigned int*)Tin;
    unsigned int* Op = (unsigned int*)out;
    size_t rb = (size_t)node * half;
    bool m0 = lane < half;
    bool m1 = (nc > 1) && (lane + 64 < half);
    float sc = selfc[node];
    float a0x = 0.f, a0y = 0.f, a1x = 0.f, a1y = 0.f;
    float b0x = 0.f, b0y = 0.f, b1x = 0.f, b1y = 0.f;
    float c0x = 0.f, c0y = 0.f, c1x = 0.f, c1y = 0.f;
    float d0x = 0.f, d0y = 0.f, d1x = 0.f, d1y = 0.f;
    if (m0) { unsigned int v = Tp[rb + lane];      a0x = bf_lo(v) * sc; a0y = bf_hi(v) * sc; }
    if (m1) { unsigned int v = Tp[rb + lane + 64]; a1x = bf_lo(v) * sc; a1y = bf_hi(v) * sc; }
    int s0 = off[node], s1 = off[node + 1];
    int e = s0;
    for (; e + 4 <= s1; e += 4) {
        int i0 = csr_src[e], i1 = csr_src[e + 1], i2 = csr_src[e + 2], i3 = csr_src[e + 3];
        float w0 = csr_w[e], w1 = csr_w[e + 1], w2 = csr_w[e + 2], w3 = csr_w[e + 3];
        size_t p0 = (size_t)i0 * half, p1 = (size_t)i1 * half;
        size_t p2 = (size_t)i2 * half, p3 = (size_t)i3 * half;
        if (m0) {
            unsigned int v0 = Tp[p0 + lane], v1 = Tp[p1 + lane];
            unsigned int v2 = Tp[p2 + lane], v3 = Tp[p3 + lane];
            a0x += bf_lo(v0) * w0; a0y += bf_hi(v0) * w0;
            b0x += bf_lo(v1) * w1; b0y += bf_hi(v1) * w1;
            c0x += bf_lo(v2) * w2; c0y += bf_hi(v2) * w2;
            d0x += bf_lo(v3) * w3; d0y += bf_hi(v3) * w3;
        }
        if (m1) {
            unsigned int v0 = Tp[p0 + lane + 64], v1 = Tp[p1 + lane + 64];
            unsigned int v2 = Tp[p2 + lane + 64], v3 = Tp[p3 + lane + 64];
            a1x += bf_lo(v0) * w0; a1y += bf_hi(v0) * w0;
            b1x += bf_lo(v1) * w1; b1y += bf_hi(v1) * w1;
            c1x += bf_lo(v2) * w2; c1y += bf_hi(v2) * w2;
            d1x += bf_lo(v3) * w3; d1y += bf_hi(v3) * w3;
        }
    }
    for (; e + 2 <= s1; e += 2) {
        int i0 = csr_src[e], i1 = csr_src[e + 1];
        float w0 = csr_w[e], w1 = csr_w[e + 1];
        size_t p0 = (size_t)i0 * half, p1 = (size_t)i1 * half;
        if (m0) {
            unsigned int v0 = Tp[p0 + lane], v1 = Tp[p1 + lane];
            a0x += bf_lo(v0) * w0; a0y += bf_hi(v0) * w0;
            b0x += bf_lo(v1) * w1; b0y += bf_hi(v1) * w1;
        }
        if (m1) {
            unsigned int v0 = Tp[p0 + lane + 64], v1 = Tp[p1 + lane + 64];
            a1x += bf_lo(v0) * w0; a1y += bf_hi(v0) * w0;
            b1x += bf_lo(v1) * w1; b1y += bf_hi(v1) * w1;
        }
    }
    if (e < s1) {
        int i0 = csr_src[e];
        float w0 = csr_w[e];
        size_t p0 = (size_t)i0 * half;
        if (m0) { unsigned int v = Tp[p0 + lane];      a0x += bf_lo(v) * w0; a0y += bf_hi(v) * w0; }
        if (m1) { unsigned int v = Tp[p0 + lane + 64]; a1x += bf_lo(v) * w0; a1y += bf_hi(v) * w0; }
    }
    if (m0) Op[rb + lane]      = bf_pack((a0x + b0x) + (c0x + d0x), (a0y + b0y) + (c0y + d0y));
    if (m1) Op[rb + lane + 64] = bf_pack((a1x + b1x) + (c1x + d1x), (a1y + b1y) + (c1y + d1y));
}

// ---------------------------------------------------------------------------
// segment max pool (bf16 [NNODES][320] -> bf16 [NB][320]); batch sorted
// ---------------------------------------------------------------------------
__global__ __launch_bounds__(256) void pool_max_bf16(
    const __hip_bfloat16* __restrict__ H, const int* __restrict__ batch,
    __hip_bfloat16* __restrict__ g)
{
    int b = blockIdx.x;
    int lo = 0, hi = NNODES;
    while (lo < hi) { int mid = (lo + hi) >> 1; if (batch[mid] < b) lo = mid + 1; else hi = mid; }
    int s = lo;
    hi = NNODES;
    while (lo < hi) { int mid = (lo + hi) >> 1; if (batch[mid] < b + 1) lo = mid + 1; else hi = mid; }
    int e = lo;
    int tid = threadIdx.x;
    if (tid < 160) {
        const unsigned int* Hp = (const unsigned int*)H;
        float mx = 0.f, my = 0.f;
        for (int i = s; i < e; ++i) {
            unsigned int v = Hp[(size_t)i * 160 + tid];
            mx = fmaxf(mx, bf_lo(v));
            my = fmaxf(my, bf_hi(v));
        }
        ((unsigned int*)g)[(size_t)b * 160 + tid] = bf_pack(mx, my);
    }
}

// ---------------------------------------------------------------------------
// Conv branch: transpose to bf16, vectorized bucketed aggregation, weight folding
// ---------------------------------------------------------------------------
__global__ void conv_transpose_kernel(const float* __restrict__ w, __hip_bfloat16* __restrict__ wt)
{
    int idx = blockIdx.x * 256 + threadIdx.x;
    if (idx >= 256000) return;
    int o = idx / 8000;
    int rem = idx - o * 8000;
    int i = rem >> 3, k = rem & 7;
    wt[i * 256 + o * 8 + k] = __float2bfloat16(w[idx]);
}

__global__ __launch_bounds__(256) void conv_agg_kernel(
    const __hip_bfloat16* __restrict__ cwt, const int* __restrict__ target,
    __hip_bfloat16* __restrict__ aggw)
{
    __shared__ int tb_s[SEQ];
    __shared__ int cnt[26];
    __shared__ int boff[27];
    __shared__ int curs[26];
    __shared__ int bucket[SEQ];
    __shared__ float comb[3][256];
    int b = blockIdx.x, tid = threadIdx.x;
    int wave = tid >> 6, lane = tid & 63;
    const int* tb = target + b * SEQ;
    if (tid < 26) cnt[tid] = 0;
    __syncthreads();
    for (int i = tid; i < SEQ; i += 256) {
        int a = tb[i];
        tb_s[i] = a;
        atomicAdd(&cnt[a], 1);
    }
    __syncthreads();
    if (tid == 0) {
        int run = 0;
        for (int a = 0; a < 26; ++a) { boff[a] = run; curs[a] = run; run += cnt[a]; }
        boff[26] = run;
    }
    __syncthreads();
    for (int i = tid; i < SEQ; i += 256) {
        int a = tb_s[i];
        int p = atomicAdd(&curs[a], 1);
        bucket[p] = i;
    }
    __syncthreads();

    const uint2* cw = (const uint2*)cwt;
    uint2* aw = (uint2*)aggw;
    for (int a = 0; a < 26; ++a) {
        int s = boff[a], e = boff[a + 1];
        float x0 = 0.f, x1 = 0.f, x2 = 0.f, x3 = 0.f;
        float y0 = 0.f, y1 = 0.f, y2 = 0.f, y3 = 0.f;
        int j = s + wave;
        for (; j + 4 < e; j += 8) {
            uint2 v = cw[(size_t)bucket[j] * 64 + lane];
            uint2 u = cw[(size_t)bucket[j + 4] * 64 + lane];
            x0 += bf_lo(v.x); x1 += bf_hi(v.x); x2 += bf_lo(v.y); x3 += bf_hi(v.y);
            y0 += bf_lo(u.x); y1 += bf_hi(u.x); y2 += bf_lo(u.y); y3 += bf_hi(u.y);
        }
        if (j < e) {
            uint2 v = cw[(size_t)bucket[j] * 64 + lane];
            x0 += bf_lo(v.x); x1 += bf_hi(v.x); x2 += bf_lo(v.y); x3 += bf_hi(v.y);
        }
        x0 += y0; x1 += y1; x2 += y2; x3 += y3;
        if (wave > 0) {
            comb[wave - 1][lane * 4 + 0] = x0;
            comb[wave - 1][lane * 4 + 1] = x1;
            comb[wave - 1][lane * 4 + 2] = x2;
            comb[wave - 1][lane * 4 + 3] = x3;
        }
        __syncthreads();
        if (wave == 0) {
            x0 += comb[0][lane * 4 + 0] + comb[1][lane * 4 + 0] + comb[2][lane * 4 + 0];
            x1 += comb[0][lane * 4 + 1] + comb[1][lane * 4 + 1] + comb[2][lane * 4 + 1];
            x2 += comb[0][lane * 4 + 2] + comb[1][lane * 4 + 2] + comb[2][lane * 4 + 2];
            x3 += comb[0][lane * 4 + 3] + comb[1][lane * 4 + 3] + comb[2][lane * 4 + 3];
            uint2 o;
            o.x = bf_pack(x0, x1);
            o.y = bf_pack(x2, x3);
            aw[(size_t)b * 1664 + a * 64 + lane] = o;
        }
        __syncthreads();
    }
}

__global__ __launch_bounds__(128) void conv_wc_kernel(
    const float* __restrict__ emb, const float* __restrict__ w_fc, float* __restrict__ Wc)
{
    int o = blockIdx.x;
    int ak = blockIdx.y;
    int a = ak >> 3, k = ak & 7;
    int j = threadIdx.x;
    const float* wp = w_fc + (long)(o * 121) * 128 + j;
    const float* ep = emb + a * 128 + k;
    float s = 0.f;
    #pragma unroll 11
    for (int t = 0; t < 121; ++t) s += ep[t] * wp[t * 128];
    Wc[(long)(a * 256 + o * 8 + k) * 128 + j] = s;
}

// xtb[j] = fc1xt_b[j] + sum_{o,t} conv_b[o] * w_fc[(o*121+t)*128+j]; one block per j
__global__ __launch_bounds__(256) void convb_fold2_kernel(
    const float* __restrict__ w_fc, const float* __restrict__ conv_b,
    const float* __restrict__ b_fc, float* __restrict__ xtb)
{
    int j = blockIdx.x;
    __shared__ float red[256];
    __shared__ float cb[32];
    int tid = threadIdx.x;
    if (tid < 32) cb[tid] = conv_b[tid];
    __syncthreads();
    float s = 0.f;
    for (int p = tid; p < 3872; p += 256)
        s += cb[p / 121] * w_fc[(size_t)p * 128 + j];
    red[tid] = s;
    __syncthreads();
    #pragma unroll
    for (int st = 128; st > 0; st >>= 1) {
        if (tid < st) red[tid] += red[tid + st];
        __syncthreads();
    }
    if (tid == 0) xtb[j] = b_fc[j] + red[0];
}

__global__ void xc_convbias_kernel(const float* __restrict__ xtb, float* __restrict__ xc)
{
    int idx = blockIdx.x * 256 + threadIdx.x;
    if (idx >= NB * 128) return;
    int b = idx >> 7, j = idx & 127;
    xc[(long)b * 384 + 128 + j] = xtb[j];
}

// ---------------------------------------------------------------------------
// FG branch: attention row 0 + LayerNorm (bf16 in, bf16 padded out)
// ---------------------------------------------------------------------------
__global__ __launch_bounds__(256) void attn_ln_kernel(
    const __hip_bfloat16* __restrict__ Fb, const __hip_bfloat16* __restrict__ Kf,
    const __hip_bfloat16* __restrict__ Vf, const __hip_bfloat16* __restrict__ q0,
    const float* __restrict__ ln_g, const float* __restrict__ ln_b,
    __hip_bfloat16* __restrict__ out)
{
    int b = blockIdx.x, tid = threadIdx.x;
    __shared__ float qs[HID];
    __shared__ float sc[13];
    __shared__ float red[256];
    __shared__ float red2[256];
    __shared__ float rowv[HID];
    __shared__ float mean_s, inv_s;

    for (int d = tid; d < HID; d += 256) qs[d] = __bfloat162float(q0[(size_t)b * 320 + d]);
    __syncthreads();
    if (tid < 208) {
        int k = tid >> 4, sub = tid & 15;
        const __hip_bfloat16* kr = Kf + ((size_t)b * 13 + k) * 320;
        float p = 0.f;
        for (int d = sub; d < HID; d += 16) p += qs[d] * __bfloat162float(kr[d]);
        red[tid] = p;
    }
    __syncthreads();
    if (tid < 208 && (tid & 15) == 0) {
        float s = 0.f;
        #pragma unroll
        for (int j = 0; j < 16; ++j) s += red[tid + j];
        sc[tid >> 4] = s * 0.0577350269189626f;  // 1/sqrt(300)
    }
    __syncthreads();
    if (tid == 0) {
        float mx = sc[0];
        for (int k = 1; k < 13; ++k) mx = fmaxf(mx, sc[k]);
        float ssum = 0.f;
        for (int k = 0; k < 13; ++k) { float e = expf(sc[k] - mx); sc[k] = e; ssum += e; }
        float inv = 1.0f / ssum;
        for (int k = 0; k < 13; ++k) sc[k] *= inv;
    }
    __syncthreads();
    for (int d = tid; d < HID; d += 256) {
        float v = __bfloat162float(Fb[((size_t)b * 13) * 320 + d]);
        #pragma unroll
        for (int k = 0; k < 13; ++k)
            v += sc[k] * __bfloat162float(Vf[((size_t)b * 13 + k) * 320 + d]);
        rowv[d] = v;
    }
    __syncthreads();
    float s1 = 0.f, s2 = 0.f;
    for (int d = tid; d < HID; d += 256) { float v = rowv[d]; s1 += v; s2 += v * v; }
    red[tid] = s1; red2[tid] = s2;
    __syncthreads();
    for (int s = 128; s > 0; s >>= 1) {
        if (tid < s) { red[tid] += red[tid + s]; red2[tid] += red2[tid + s]; }
        __syncthreads();
    }
    if (tid == 0) {
        float mean = red[0] / (float)HID;
        float var = red2[0] / (float)HID - mean * mean;
        mean_s = mean;
        inv_s = 1.0f / sqrtf(var + 1e-5f);
    }
    __syncthreads();
    for (int d = tid; d < 320; d += 256) {
        float v = 0.f;
        if (d < HID) v = (rowv[d] - mean_s) * inv_s * ln_g[d] + ln_b[d];
        out[(size_t)b * 320 + d] = __float2bfloat16(v);
    }
}

// ---------------------------------------------------------------------------
// final: out[b] = X[b,:512] . out_w + out_b   (fp32)
// ---------------------------------------------------------------------------
__global__ __launch_bounds__(256) void final_out_kernel(
    const float* __restrict__ X, const float* __restrict__ w,
    const float* __restrict__ bias, float* __restrict__ out)
{
    int b = blockIdx.x, tid = threadIdx.x;
    __shared__ float red[256];
    float p = X[(long)b * 512 + tid] * w[tid] + X[(long)b * 512 + tid + 256] * w[tid + 256];
    red[tid] = p;
    __syncthreads();
    for (int s = 128; s > 0; s >>= 1) {
        if (tid < s) red[tid] += red[tid + s];
        __syncthreads();
    }
    if (tid == 0) out[b] = red[0] + bias[0];
}

// ---------------------------------------------------------------------------
// Host launcher
// ---------------------------------------------------------------------------
extern "C" void kernel_launch(void* const* d_in, const int* in_sizes, int n_in,
                              void* d_out, int out_size, void* d_ws, size_t ws_size,
                              hipStream_t stream)
{
    const float* x        = (const float*)d_in[0];
    const int*   ei       = (const int*)d_in[1];
    const int*   batch    = (const int*)d_in[2];
    const int*   target   = (const int*)d_in[3];
    const float* embs     = (const float*)d_in[4];
    const float* W1       = (const float*)d_in[5];
    const float* b1       = (const float*)d_in[6];
    const float* W2       = (const float*)d_in[7];
    const float* b2       = (const float*)d_in[8];
    const float* W3       = (const float*)d_in[9];
    const float* b3       = (const float*)d_in[10];
    const float* fc_g1_w  = (const float*)d_in[11];
    const float* fc_g1_b  = (const float*)d_in[12];
    const float* fc_g2_w  = (const float*)d_in[13];
    const float* fc_g2_b  = (const float*)d_in[14];
    const float* emb_xt   = (const float*)d_in[15];
    const float* conv_w   = (const float*)d_in[16];
    const float* conv_b   = (const float*)d_in[17];
    const float* fc1xt_w  = (const float*)d_in[18];
    const float* fc1xt_b  = (const float*)d_in[19];
    const float* fg_lin_w = (const float*)d_in[20];
    const float* fg_lin_b = (const float*)d_in[21];
    const float* Wq       = (const float*)d_in[22];
    const float* Wk       = (const float*)d_in[23];
    const float* Wv       = (const float*)d_in[24];
    const float* ln_g     = (const float*)d_in[25];
    const float* ln_b     = (const float*)d_in[26];
    const float* fg_out_w = (const float*)d_in[27];
    const float* fg_out_b = (const float*)d_in[28];
    const float* fc1_w    = (const float*)d_in[29];
    const float* fc1_b    = (const float*)d_in[30];
    const float* fc2_w    = (const float*)d_in[31];
    const float* fc2_b    = (const float*)d_in[32];
    const float* out_w    = (const float*)d_in[33];
    const float* out_b    = (const float*)d_in[34];

    const int* src = ei;
    const int* dst = ei + NEDGES;
    typedef __hip_bfloat16 bf;

    // ---- workspace carve (256-B aligned bump allocator) ----
    char* p = (char*)d_ws;
    auto alloc = [&](size_t bytes) { char* r = p; p += (bytes + 255) & ~(size_t)255; return r; };
    bf*   xb      = (bf*)alloc((size_t)NNODES * 96 * 2);
    bf*   T       = (bf*)alloc((size_t)NNODES * 160 * 2);
    bf*   H       = (bf*)alloc((size_t)NNODES * 320 * 2);
    int*  deg     = (int*)alloc(NNODES * 4);                // reused as CSR cursor
    float* dis    = (float*)alloc(NNODES * 4);
    float* selfc  = (float*)alloc(NNODES * 4);
    int*  off     = (int*)alloc((NNODES + 1) * 4);
    int*  bsum    = (int*)alloc(512 * 4);
    int*  csr_src = (int*)alloc(NEDGES * 4);
    float* csr_w  = (float*)alloc(NEDGES * 4);
    bf*   w1t     = (bf*)alloc(78 * 96 * 2);
    bf*   w2t     = (bf*)alloc(156 * 96 * 2);
    bf*   w3t     = (bf*)alloc(312 * 160 * 2);
    bf*   fcg1t   = (bf*)alloc(1024 * 320 * 2);
    bf*   fcg2t   = (bf*)alloc(128 * 1024 * 2);
    bf*   fglint  = (bf*)alloc(300 * 160 * 2);
    bf*   wkt     = (bf*)alloc(300 * 320 * 2);
    bf*   wvt     = (bf*)alloc(300 * 320 * 2);
    bf*   wqt     = (bf*)alloc(300 * 320 * 2);
    bf*   fgoutt  = (bf*)alloc(128 * 320 * 2);
    bf*   fc1t    = (bf*)alloc(1024 * 384 * 2);
    bf*   fc2t    = (bf*)alloc(512 * 1024 * 2);
    bf*   fglwb   = (bf*)alloc(133 * 320 * 2);
    bf*   wk2t    = (bf*)alloc(300 * 160 * 2);
    bf*   wv2t    = (bf*)alloc(300 * 160 * 2);
    bf*   wq2t    = (bf*)alloc(300 * 160 * 2);
    float* bk2    = (float*)alloc(300 * 4);
    float* bv2    = (float*)alloc(300 * 4);
    float* bq2    = (float*)alloc(300 * 4);
    bf*   g       = (bf*)alloc((size_t)NB * 320 * 2);
    bf*   G1b     = (bf*)alloc((size_t)NB * 1024 * 2);
    bf*   embsb   = (bf*)alloc((size_t)NB * 13 * 160 * 2);
    bf*   Fbuf    = (bf*)alloc((size_t)NB * 13 * 320 * 2);
    bf*   Kbuf    = (bf*)alloc((size_t)NB * 13 * 320 * 2);
    bf*   Vbuf    = (bf*)alloc((size_t)NB * 13 * 320 * 2);
    bf*   Qbuf    = (bf*)alloc((size_t)NB * 320 * 2);
    bf*   f2row   = (bf*)alloc((size_t)NB * 320 * 2);
    float* xc     = (float*)alloc((size_t)NB * 384 * 4);
    bf*   xcb     = (bf*)alloc((size_t)NB * 384 * 2);
    float* F2     = (float*)alloc((size_t)NB * 512 * 4);
    bf*   cwt     = (bf*)alloc(256000 * 2);
    bf*   aggwb   = (bf*)alloc((size_t)NB * 6656 * 2);
    float* Wc     = (float*)alloc((size_t)6656 * 128 * 4);
    bf*   Wct     = (bf*)alloc((size_t)128 * 6656 * 2);
    float* xtb    = (float*)alloc(128 * 4);

    // ---- degree / norms / CSR ----
    hipMemsetAsync(deg, 0, NNODES * sizeof(int), stream);
    deg_kernel<<<(NEDGES + 255) / 256, 256, 0, stream>>>(dst, deg, NEDGES);
    scan_p1<<<NBLK1, 256, 0, stream>>>(deg, off, bsum, dis, selfc);
    scan_p2<<<1, 512, 0, stream>>>(bsum);
    scan_p3<<<NBLK1, 256, 0, stream>>>(off, bsum, deg);   // deg becomes cursor
    fill_csr_kernel<<<(NEDGES + 255) / 256, 256, 0, stream>>>(src, dst, dis, deg, csr_src, csr_w, NEDGES);

    // ---- weight transposes (one batched launch) + batched input converts ----
    {
        TBatch tb;
        const float* srcs[12] = {W1, W2, W3, fc_g1_w, fc_g2_w, fg_lin_w, Wk, Wv, Wq, fg_out_w, fc1_w, fc2_w};
        bf* dsts[12]          = {w1t, w2t, w3t, fcg1t, fcg2t, fglint, wkt, wvt, wqt, fgoutt, fc1t, fc2t};
        int Ks[12]    = {78, 78, 156, 312, 1024, 133, 300, 300, 300, 300, 384, 1024};
        int Ns[12]    = {78, 156, 312, 1024, 128, 300, 300, 300, 300, 128, 1024, 512};
        int Kpads[12] = {96, 96, 160, 320, 1024, 160, 320, 320, 320, 320, 384, 1024};
        int bs = 0;
        for (int i = 0; i < 12; ++i) {
            tb.src[i] = srcs[i]; tb.dst[i] = dsts[i];
            tb.K[i] = Ks[i]; tb.N[i] = Ns[i]; tb.Kpad[i] = Kpads[i];
            tb.bstart[i] = bs;
            bs += (int)(((long)Ns[i] * Kpads[i] + 255) / 256);
        }
        tb.bstart[12] = bs;
        transpose_batch_kernel<<<bs, 256, 0, stream>>>(tb);
    }
    {
        CBatch cb;
        cb.src[0] = x;       cb.dst[0] = xb;    cb.M[0] = NNODES;  cb.K[0] = 78;  cb.Kpad[0] = 96;
        cb.src[1] = embs;    cb.dst[1] = embsb; cb.M[1] = NB * 13; cb.K[1] = 133; cb.Kpad[1] = 160;
        cb.src[2] = fg_lin_w;cb.dst[2] = fglwb; cb.M[2] = 133;     cb.K[2] = 300; cb.Kpad[2] = 320;
        int bs = 0;
        for (int i = 0; i < 3; ++i) {
            cb.bstart[i] = bs;
            bs += (int)(((long)cb.M[i] * cb.Kpad[i] + 255) / 256);
        }
        cb.bstart[3] = bs;
        cvt_batch_kernel<<<bs, 256, 0, stream>>>(cb);
    }

    // ---- GCN layers: agg(input) -> XCD-swizzled 128x64 MFMA GEMM ----
    int agrid = (NNODES + 3) / 4;
    gcn_agg2<<<agrid, 256, 0, stream>>>(xb, off, csr_src, csr_w, selfc, T, 48, 1);
    launch_gemm_swz(T, w1t, b1, H, NNODES, 78, 96, 96, 96, 96, stream);

    gcn_agg2<<<agrid, 256, 0, stream>>>(H, off, csr_src, csr_w, selfc, T, 48, 1);
    launch_gemm_swz(T, w2t, b2, H, NNODES, 156, 96, 96, 160, 160, stream);

    gcn_agg2<<<agrid, 256, 0, stream>>>(H, off, csr_src, csr_w, selfc, T, 80, 2);
    launch_gemm_swz(T, w3t, b3, H, NNODES, 312, 160, 160, 320, 320, stream);

    // ---- global max pool + graph MLP ----
    pool_max_bf16<<<NB, 256, 0, stream>>>(H, batch, g);
    launch_gemm_bf16(g, fcg1t, fc_g1_b, G1b, NB, 1024, 320, 320, 1024, 1024, 1, 1, 1, stream);
    launch_gemm_bf16(G1b, fcg2t, fc_g2_b, xc, NB, 128, 1024, 1024, 384, 128, 0, 0, 1, stream);

    // ---- conv branch (folded; split-K MFMA accumulates into xc cols 128..255) ----
    conv_transpose_kernel<<<(256000 + 255) / 256, 256, 0, stream>>>(conv_w, cwt);
    conv_agg_kernel<<<NB, 256, 0, stream>>>(cwt, target, aggwb);
    conv_wc_kernel<<<dim3(32, 208), 128, 0, stream>>>(emb_xt, fc1xt_w, Wc);
    transpose_cvt_kernel<<<((long)128 * 6656 + 255) / 256, 256, 0, stream>>>(Wc, Wct, 6656, 128, 6656);
    convb_fold2_kernel<<<128, 256, 0, stream>>>(fc1xt_w, conv_b, fc1xt_b, xtb);
    xc_convbias_kernel<<<(NB * 128 + 255) / 256, 256, 0, stream>>>(xtb, xc);
    launch_gemm_bf16(aggwb, Wct, nullptr, xc + 128, NB, 128, 6656, 6656, 384, 128, 0, 0, 8, stream);

    // ---- FG branch (batched folded-weight GEMMs) ----
    {
        GB3 p;
        for (int z = 0; z < 3; ++z) {
            p.g[z].Bt = fglwb; p.g[z].bias = nullptr;
            p.g[z].M = 300; p.g[z].N = 133; p.g[z].Kpad = 320;
            p.g[z].lda = 320; p.g[z].ldc = 160; p.g[z].Npad = 160;
        }
        p.g[0].A = wkt; p.g[0].C = wk2t;
        p.g[1].A = wvt; p.g[1].C = wv2t;
        p.g[2].A = wqt; p.g[2].C = wq2t;
        gemm_batch64_kernel<<<dim3(3, 5, 3), 256, 0, stream>>>(p);
    }
    {
        BF3 p;
        p.Wt[0] = wkt; p.out[0] = bk2;
        p.Wt[1] = wvt; p.out[1] = bv2;
        p.Wt[2] = wqt; p.out[2] = bq2;
        bias_fold3_kernel<<<900, 256, 0, stream>>>(fg_lin_b, p);
    }
    {
        GB3 p;
        // F at rows b*13 only; Q dense
        p.g[0].A = embsb; p.g[0].Bt = fglint; p.g[0].bias = fg_lin_b; p.g[0].C = Fbuf;
        p.g[0].M = NB; p.g[0].N = 300; p.g[0].Kpad = 160; p.g[0].lda = 13 * 160;
        p.g[0].ldc = 13 * 320; p.g[0].Npad = 320;
        p.g[1] = p.g[0];
        p.g[1].Bt = wq2t; p.g[1].bias = bq2; p.g[1].C = Qbuf; p.g[1].ldc = 320;
        p.g[2] = p.g[1];
        gemm_batch64_kernel<<<dim3(5, 16, 2), 256, 0, stream>>>(p);
    }
    {
        GB3 p;
        p.g[0].A = embsb; p.g[0].Bt = wk2t; p.g[0].bias = bk2; p.g[0].C = Kbuf;
        p.g[0].M = NB * 13; p.g[0].N = 300; p.g[0].Kpad = 160; p.g[0].lda = 160;
        p.g[0].ldc = 320; p.g[0].Npad = 320;
        p.g[1] = p.g[0];
        p.g[1].Bt = wv2t; p.g[1].bias = bv2; p.g[1].C = Vbuf;
        p.g[2] = p.g[1];
        gemm_mtb_kernel<<<dim3(5, (NB * 13 + 127) / 128, 2), 256, 0, stream>>>(p);
    }
    attn_ln_kernel<<<NB, 256, 0, stream>>>(Fbuf, Kbuf, Vbuf, Qbuf, ln_g, ln_b, f2row);
    launch_gemm_bf16(f2row, fgoutt, fg_out_b, xc + 256, NB, 128, 320, 320, 384, 128, 0, 0, 1, stream);

    // ---- head ----
    cvt_pad_kernel<<<((long)NB * 384 + 255) / 256, 256, 0, stream>>>(xc, xcb, NB, 384, 384);
    launch_gemm_bf16(xcb, fc1t, fc1_b, G1b, NB, 1024, 384, 384, 1024, 1024, 1, 1, 1, stream);
    launch_gemm_bf16(G1b, fc2t, fc2_b, F2, NB, 512, 1024, 1024, 512, 512, 1, 0, 1, stream);
    final_out_kernel<<<NB, 256, 0, stream>>>(F2, out_w, out_b, (float*)d_out);
}

// Round 16
// 705.350 us; speedup vs baseline: 1.1091x; 1.0130x over previous
//
#include <hip/hip_runtime.h>
#include <hip/hip_bf16.h>
#include <math.h>

// ---------------------------------------------------------------------------
// Problem constants
// ---------------------------------------------------------------------------
#define NNODES 100000
#define NEDGES 400000
#define NB     1024
#define SEQ    1000
#define HID    300
#define NBLK1  ((NNODES + 255) / 256)   // 391

typedef __attribute__((ext_vector_type(8))) short short8;   // 8 bf16 (4 VGPRs)
typedef __attribute__((ext_vector_type(4))) float f32x4;    // MFMA acc

__device__ __forceinline__ float bf_lo(unsigned int v) { return __uint_as_float(v << 16); }
__device__ __forceinline__ float bf_hi(unsigned int v) { return __uint_as_float(v & 0xffff0000u); }
__device__ __forceinline__ unsigned int bf_pack(float lo, float hi) {
    __hip_bfloat16 a = __float2bfloat16(lo), b = __float2bfloat16(hi);
    unsigned short ua = *(unsigned short*)&a, ub = *(unsigned short*)&b;
    return (unsigned int)ua | ((unsigned int)ub << 16);
}

// ---------------------------------------------------------------------------
// fp32 [M][K] -> bf16 [M][Kpad] (zero-padded)
// ---------------------------------------------------------------------------
__global__ void cvt_pad_kernel(const float* __restrict__ in, __hip_bfloat16* __restrict__ out,
                               int M, int K, int Kpad)
{
    long idx = (long)blockIdx.x * 256 + threadIdx.x;
    if (idx >= (long)M * Kpad) return;
    int m = idx / Kpad, k = idx % Kpad;
    out[idx] = __float2bfloat16(k < K ? in[(long)m * K + k] : 0.f);
}

// batched cvt_pad: 3 descriptors, one launch
struct CBatch {
    const float* src[3];
    __hip_bfloat16* dst[3];
    int M[3]; int K[3]; int Kpad[3];
    int bstart[4];
};

__global__ __launch_bounds__(256) void cvt_batch_kernel(CBatch cb)
{
    int blk = blockIdx.x;
    int d = 0;
    while (d < 2 && blk >= cb.bstart[d + 1]) ++d;
    long idx = (long)(blk - cb.bstart[d]) * 256 + threadIdx.x;
    long tot = (long)cb.M[d] * cb.Kpad[d];
    if (idx >= tot) return;
    int Kpad = cb.Kpad[d];
    int m = idx / Kpad, k = idx % Kpad;
    cb.dst[d][idx] = __float2bfloat16(k < cb.K[d] ? cb.src[d][(long)m * cb.K[d] + k] : 0.f);
}

// fp32 [K][N] row-major -> bf16 Bt [N][Kpad] (zero-padded)
__global__ void transpose_cvt_kernel(const float* __restrict__ in, __hip_bfloat16* __restrict__ out,
                                     int K, int N, int Kpad)
{
    long idx = (long)blockIdx.x * 256 + threadIdx.x;
    if (idx >= (long)N * Kpad) return;
    int n = idx / Kpad, k = idx % Kpad;
    out[idx] = __float2bfloat16(k < K ? in[(long)k * N + n] : 0.f);
}

// Batched weight transpose: 12 descriptors in one launch
struct TBatch {
    const float* src[12];
    __hip_bfloat16* dst[12];
    int K[12]; int N[12]; int Kpad[12];
    int bstart[13];
};

__global__ __launch_bounds__(256) void transpose_batch_kernel(TBatch tb)
{
    int blk = blockIdx.x;
    int d = 0;
    while (d < 11 && blk >= tb.bstart[d + 1]) ++d;
    long idx = (long)(blk - tb.bstart[d]) * 256 + threadIdx.x;
    long tot = (long)tb.N[d] * tb.Kpad[d];
    if (idx >= tot) return;
    int Kpad = tb.Kpad[d];
    int n = idx / Kpad, k = idx % Kpad;
    tb.dst[d][idx] = __float2bfloat16(k < tb.K[d] ? tb.src[d][(long)k * tb.N[d] + n] : 0.f);
}

// batched bias fold from TRANSPOSED bf16 weights: out_d[n] = sum_k b[k] * Wt_d[n][k]
struct BF3 { const __hip_bfloat16* Wt[3]; float* out[3]; };

__global__ __launch_bounds__(256) void bias_fold3_kernel(const float* __restrict__ b, BF3 p)
{
    int d = blockIdx.x / 300;
    int n = blockIdx.x % 300;
    __shared__ float red[256];
    int tid = threadIdx.x;
    const __hip_bfloat16* Wt = p.Wt[d];
    float s = 0.f;
    for (int k = tid; k < 300; k += 256)
        s += b[k] * __bfloat162float(Wt[(size_t)n * 320 + k]);
    red[tid] = s;
    __syncthreads();
    #pragma unroll
    for (int st = 128; st > 0; st >>= 1) {
        if (tid < st) red[tid] += red[tid + st];
        __syncthreads();
    }
    if (tid == 0) p.out[d][n] = red[0];
}

// ---------------------------------------------------------------------------
// BF16 MFMA GEMM (TN), 64x64 tile: C = act(A @ Bt^T + bias)
// ---------------------------------------------------------------------------
__global__ __launch_bounds__(256) void gemm_bf16_kernel(
    const __hip_bfloat16* __restrict__ A, const __hip_bfloat16* __restrict__ Bt,
    const float* __restrict__ bias, void* __restrict__ C,
    int M, int N, int Kpad, int lda, int ldc, int Npad_out,
    int relu, int outbf, int chunk)
{
    __shared__ __align__(16) __hip_bfloat16 As[64][40];
    __shared__ __align__(16) __hip_bfloat16 Bs[64][40];
    int tid = threadIdx.x;
    int wave = tid >> 6, lane = tid & 63;
    int wm = wave >> 1, wn = wave & 1;
    int quad = lane >> 4, l16 = lane & 15;
    int row0 = blockIdx.y * 64, col0 = blockIdx.x * 64;

    int kbeg = 0, kend = Kpad;
    if (chunk > 0) { kbeg = blockIdx.z * chunk; kend = kbeg + chunk; if (kend > Kpad) kend = Kpad; }

    f32x4 acc[2][2];
    #pragma unroll
    for (int i = 0; i < 2; ++i)
        #pragma unroll
        for (int j = 0; j < 2; ++j) acc[i][j] = (f32x4){0.f, 0.f, 0.f, 0.f};

    int r = tid >> 2, cch = (tid & 3) * 8;

    for (int k0 = kbeg; k0 < kend; k0 += 32) {
        uint4 av = {0u, 0u, 0u, 0u};
        if (row0 + r < M) av = *(const uint4*)(A + (size_t)(row0 + r) * lda + k0 + cch);
        *(uint4*)(&As[r][cch]) = av;
        uint4 bv = {0u, 0u, 0u, 0u};
        if (col0 + r < N) bv = *(const uint4*)(Bt + (size_t)(col0 + r) * Kpad + k0 + cch);
        *(uint4*)(&Bs[r][cch]) = bv;
        __syncthreads();

        short8 a0 = *(const short8*)(&As[wm * 32 + l16][quad * 8]);
        short8 a1 = *(const short8*)(&As[wm * 32 + 16 + l16][quad * 8]);
        short8 b0 = *(const short8*)(&Bs[wn * 32 + l16][quad * 8]);
        short8 b1 = *(const short8*)(&Bs[wn * 32 + 16 + l16][quad * 8]);
        acc[0][0] = __builtin_amdgcn_mfma_f32_16x16x32_bf16(a0, b0, acc[0][0], 0, 0, 0);
        acc[0][1] = __builtin_amdgcn_mfma_f32_16x16x32_bf16(a0, b1, acc[0][1], 0, 0, 0);
        acc[1][0] = __builtin_amdgcn_mfma_f32_16x16x32_bf16(a1, b0, acc[1][0], 0, 0, 0);
        acc[1][1] = __builtin_amdgcn_mfma_f32_16x16x32_bf16(a1, b1, acc[1][1], 0, 0, 0);
        __syncthreads();
    }

    #pragma unroll
    for (int ti = 0; ti < 2; ++ti) {
        int rbase = row0 + wm * 32 + ti * 16 + quad * 4;
        #pragma unroll
        for (int tj = 0; tj < 2; ++tj) {
            int cc = col0 + wn * 32 + tj * 16 + l16;
            if (cc >= Npad_out) continue;
            #pragma unroll
            for (int reg = 0; reg < 4; ++reg) {
                int rr = rbase + reg;
                if (rr >= M) continue;
                float v = acc[ti][tj][reg];
                if (chunk > 0) {
                    if (cc < N) atomicAdd((float*)C + (size_t)rr * ldc + cc, v);
                } else {
                    float ov = 0.f;
                    if (cc < N) {
                        if (bias) v += bias[cc];
                        if (relu) v = fmaxf(v, 0.f);
                        ov = v;
                    }
                    if (outbf) ((__hip_bfloat16*)C)[(size_t)rr * ldc + cc] = __float2bfloat16(ov);
                    else       ((float*)C)[(size_t)rr * ldc + cc] = ov;
                }
            }
        }
    }
}

static void launch_gemm_bf16(const __hip_bfloat16* A, const __hip_bfloat16* Bt, const float* bias,
                             void* C, int M, int N, int Kpad, int lda, int ldc, int Npad_out,
                             int relu, int outbf, int splitz, hipStream_t stream)
{
    int cover = N > Npad_out ? N : Npad_out;
    int chunk = (splitz > 1) ? (Kpad / splitz) : 0;
    dim3 grid((cover + 63) / 64, (M + 63) / 64, splitz > 1 ? splitz : 1);
    gemm_bf16_kernel<<<grid, 256, 0, stream>>>(A, Bt, bias, C, M, N, Kpad, lda, ldc, Npad_out,
                                               relu, outbf, chunk);
}

// ---------------------------------------------------------------------------
// Batched 64x64 GEMM (z selects descriptor). bf16 out, no relu.
// ---------------------------------------------------------------------------
struct GB { const __hip_bfloat16* A; const __hip_bfloat16* Bt; const float* bias;
            __hip_bfloat16* C; int M, N, Kpad, lda, ldc, Npad; };
struct GB3 { GB g[3]; };

__global__ __launch_bounds__(256) void gemm_batch64_kernel(GB3 p)
{
    GB gb = p.g[blockIdx.z];
    __shared__ __align__(16) __hip_bfloat16 As[64][40];
    __shared__ __align__(16) __hip_bfloat16 Bs[64][40];
    int tid = threadIdx.x;
    int wave = tid >> 6, lane = tid & 63;
    int wm = wave >> 1, wn = wave & 1;
    int quad = lane >> 4, l16 = lane & 15;
    int row0 = blockIdx.y * 64, col0 = blockIdx.x * 64;

    f32x4 acc[2][2];
    #pragma unroll
    for (int i = 0; i < 2; ++i)
        #pragma unroll
        for (int j = 0; j < 2; ++j) acc[i][j] = (f32x4){0.f, 0.f, 0.f, 0.f};

    int r = tid >> 2, cch = (tid & 3) * 8;

    for (int k0 = 0; k0 < gb.Kpad; k0 += 32) {
        uint4 av = {0u, 0u, 0u, 0u};
        if (row0 + r < gb.M) av = *(const uint4*)(gb.A + (size_t)(row0 + r) * gb.lda + k0 + cch);
        *(uint4*)(&As[r][cch]) = av;
        uint4 bv = {0u, 0u, 0u, 0u};
        if (col0 + r < gb.N) bv = *(const uint4*)(gb.Bt + (size_t)(col0 + r) * gb.Kpad + k0 + cch);
        *(uint4*)(&Bs[r][cch]) = bv;
        __syncthreads();

        short8 a0 = *(const short8*)(&As[wm * 32 + l16][quad * 8]);
        short8 a1 = *(const short8*)(&As[wm * 32 + 16 + l16][quad * 8]);
        short8 b0 = *(const short8*)(&Bs[wn * 32 + l16][quad * 8]);
        short8 b1 = *(const short8*)(&Bs[wn * 32 + 16 + l16][quad * 8]);
        acc[0][0] = __builtin_amdgcn_mfma_f32_16x16x32_bf16(a0, b0, acc[0][0], 0, 0, 0);
        acc[0][1] = __builtin_amdgcn_mfma_f32_16x16x32_bf16(a0, b1, acc[0][1], 0, 0, 0);
        acc[1][0] = __builtin_amdgcn_mfma_f32_16x16x32_bf16(a1, b0, acc[1][0], 0, 0, 0);
        acc[1][1] = __builtin_amdgcn_mfma_f32_16x16x32_bf16(a1, b1, acc[1][1], 0, 0, 0);
        __syncthreads();
    }

    #pragma unroll
    for (int ti = 0; ti < 2; ++ti) {
        int rbase = row0 + wm * 32 + ti * 16 + quad * 4;
        #pragma unroll
        for (int tj = 0; tj < 2; ++tj) {
            int cc = col0 + wn * 32 + tj * 16 + l16;
            if (cc >= gb.Npad) continue;
            #pragma unroll
            for (int reg = 0; reg < 4; ++reg) {
                int rr = rbase + reg;
                if (rr >= gb.M) continue;
                float ov = 0.f;
                if (cc < gb.N) {
                    float v = acc[ti][tj][reg];
                    if (gb.bias) v += gb.bias[cc];
                    ov = v;
                }
                gb.C[(size_t)rr * gb.ldc + cc] = __float2bfloat16(ov);
            }
        }
    }
}

// ---------------------------------------------------------------------------
// Batched 128x64 GEMM (z selects descriptor). bf16 out, no relu. (K/V)
// ---------------------------------------------------------------------------
__global__ __launch_bounds__(256) void gemm_mtb_kernel(GB3 p)
{
    GB gb = p.g[blockIdx.z];
    __shared__ __align__(16) __hip_bfloat16 As[128][40];
    __shared__ __align__(16) __hip_bfloat16 Bs[64][40];
    int tid = threadIdx.x;
    int wave = tid >> 6, lane = tid & 63;
    int wm = wave >> 1, wn = wave & 1;
    int quad = lane >> 4, l16 = lane & 15;
    int row0 = blockIdx.y * 128, col0 = blockIdx.x * 64;

    f32x4 acc[4][2];
    #pragma unroll
    for (int i = 0; i < 4; ++i)
        #pragma unroll
        for (int j = 0; j < 2; ++j) acc[i][j] = (f32x4){0.f, 0.f, 0.f, 0.f};

    int r = tid >> 2, cch = (tid & 3) * 8;

    for (int k0 = 0; k0 < gb.Kpad; k0 += 32) {
        uint4 av0 = {0u, 0u, 0u, 0u}, av1 = {0u, 0u, 0u, 0u}, bv = {0u, 0u, 0u, 0u};
        if (row0 + r < gb.M)      av0 = *(const uint4*)(gb.A + (size_t)(row0 + r) * gb.lda + k0 + cch);
        if (row0 + r + 64 < gb.M) av1 = *(const uint4*)(gb.A + (size_t)(row0 + r + 64) * gb.lda + k0 + cch);
        if (col0 + r < gb.N)      bv  = *(const uint4*)(gb.Bt + (size_t)(col0 + r) * gb.Kpad + k0 + cch);
        *(uint4*)(&As[r][cch]) = av0;
        *(uint4*)(&As[r + 64][cch]) = av1;
        *(uint4*)(&Bs[r][cch]) = bv;
        __syncthreads();

        short8 af[4], bfr[2];
        #pragma unroll
        for (int i = 0; i < 4; ++i)
            af[i] = *(const short8*)(&As[wm * 64 + i * 16 + l16][quad * 8]);
        #pragma unroll
        for (int j = 0; j < 2; ++j)
            bfr[j] = *(const short8*)(&Bs[wn * 32 + j * 16 + l16][quad * 8]);
        #pragma unroll
        for (int i = 0; i < 4; ++i)
            #pragma unroll
            for (int j = 0; j < 2; ++j)
                acc[i][j] = __builtin_amdgcn_mfma_f32_16x16x32_bf16(af[i], bfr[j], acc[i][j], 0, 0, 0);
        __syncthreads();
    }

    #pragma unroll
    for (int ti = 0; ti < 4; ++ti) {
        int rbase = row0 + wm * 64 + ti * 16 + quad * 4;
        #pragma unroll
        for (int tj = 0; tj < 2; ++tj) {
            int cc = col0 + wn * 32 + tj * 16 + l16;
            if (cc >= gb.Npad) continue;
            #pragma unroll
            for (int reg = 0; reg < 4; ++reg) {
                int rr = rbase + reg;
                if (rr >= gb.M) continue;
                float ov = 0.f;
                if (cc < gb.N) {
                    float v = acc[ti][tj][reg];
                    if (gb.bias) v += gb.bias[cc];
                    ov = v;
                }
                gb.C[(size_t)rr * gb.ldc + cc] = __float2bfloat16(ov);
            }
        }
    }
}

// ---------------------------------------------------------------------------
// Node-layer GEMM: 128x64 staged tile + XCD-aware mod-8 swizzle
// ---------------------------------------------------------------------------
__global__ __launch_bounds__(256) void gemm_swz_kernel(
    const __hip_bfloat16* __restrict__ A, const __hip_bfloat16* __restrict__ Bt,
    const float* __restrict__ bias, __hip_bfloat16* __restrict__ C,
    int M, int N, int Kpad, int lda, int ldc, int Npad_out, int nct, int nstrips)
{
    int id = blockIdx.x;
    int rr8 = id & 7, q = id >> 3;
    int c = q % nct, sgrp = q / nct;
    int s = sgrp * 8 + rr8;
    if (s >= nstrips) return;
    int row0 = s * 128, col0 = c * 64;

    __shared__ __align__(16) __hip_bfloat16 As[128][40];
    __shared__ __align__(16) __hip_bfloat16 Bs[64][40];
    int tid = threadIdx.x;
    int wave = tid >> 6, lane = tid & 63;
    int wm = wave >> 1, wn = wave & 1;
    int quad = lane >> 4, l16 = lane & 15;

    f32x4 acc[4][2];
    #pragma unroll
    for (int i = 0; i < 4; ++i)
        #pragma unroll
        for (int j = 0; j < 2; ++j) acc[i][j] = (f32x4){0.f, 0.f, 0.f, 0.f};

    int r = tid >> 2, cch = (tid & 3) * 8;

    for (int k0 = 0; k0 < Kpad; k0 += 32) {
        uint4 av0 = {0u, 0u, 0u, 0u}, av1 = {0u, 0u, 0u, 0u}, bv = {0u, 0u, 0u, 0u};
        if (row0 + r < M)      av0 = *(const uint4*)(A + (size_t)(row0 + r) * lda + k0 + cch);
        if (row0 + r + 64 < M) av1 = *(const uint4*)(A + (size_t)(row0 + r + 64) * lda + k0 + cch);
        if (col0 + r < N)      bv  = *(const uint4*)(Bt + (size_t)(col0 + r) * Kpad + k0 + cch);
        *(uint4*)(&As[r][cch]) = av0;
        *(uint4*)(&As[r + 64][cch]) = av1;
        *(uint4*)(&Bs[r][cch]) = bv;
        __syncthreads();

        short8 af[4], bfr[2];
        #pragma unroll
        for (int i = 0; i < 4; ++i)
            af[i] = *(const short8*)(&As[wm * 64 + i * 16 + l16][quad * 8]);
        #pragma unroll
        for (int j = 0; j < 2; ++j)
            bfr[j] = *(const short8*)(&Bs[wn * 32 + j * 16 + l16][quad * 8]);
        #pragma unroll
        for (int i = 0; i < 4; ++i)
            #pragma unroll
            for (int j = 0; j < 2; ++j)
                acc[i][j] = __builtin_amdgcn_mfma_f32_16x16x32_bf16(af[i], bfr[j], acc[i][j], 0, 0, 0);
        __syncthreads();
    }

    #pragma unroll
    for (int ti = 0; ti < 4; ++ti) {
        int rbase = row0 + wm * 64 + ti * 16 + quad * 4;
        #pragma unroll
        for (int tj = 0; tj < 2; ++tj) {
            int cc = col0 + wn * 32 + tj * 16 + l16;
            if (cc >= Npad_out) continue;
            #pragma unroll
            for (int reg = 0; reg < 4; ++reg) {
                int rrow = rbase + reg;
                if (rrow >= M) continue;
                float ov = 0.f;
                if (cc < N) ov = fmaxf(acc[ti][tj][reg] + bias[cc], 0.f);
                C[(size_t)rrow * ldc + cc] = __float2bfloat16(ov);
            }
        }
    }
}

static void launch_gemm_swz(const __hip_bfloat16* A, const __hip_bfloat16* Bt, const float* bias,
                            __hip_bfloat16* C, int M, int N, int Kpad, int lda, int ldc,
                            int Npad_out, hipStream_t stream)
{
    int nct = (Npad_out + 63) / 64;
    int nstrips = (M + 127) / 128;
    int G = 8 * nct * ((nstrips + 7) / 8);
    gemm_swz_kernel<<<G, 256, 0, stream>>>(A, Bt, bias, C, M, N, Kpad, lda, ldc, Npad_out,
                                           nct, nstrips);
}

// ---------------------------------------------------------------------------
// GCN: degree, norms(+scan p1 fused), multi-block scan, CSR build
// ---------------------------------------------------------------------------
__global__ void deg_kernel(const int* __restrict__ dst, int* __restrict__ deg, int E)
{
    int e = blockIdx.x * 256 + threadIdx.x;
    if (e < E) atomicAdd(&deg[dst[e]], 1);
}

__global__ __launch_bounds__(256) void scan_p1(const int* __restrict__ deg,
                                               int* __restrict__ off, int* __restrict__ bsum,
                                               float* __restrict__ dis, float* __restrict__ selfc)
{
    __shared__ int s[256];
    int tid = threadIdx.x;
    int i = blockIdx.x * 256 + tid;
    int v = (i < NNODES) ? deg[i] : 0;
    if (i < NNODES) {
        float d = (float)v + 1.0f;
        float r = 1.0f / sqrtf(d);
        dis[i] = r;
        selfc[i] = r * r;
    }
    s[tid] = v;
    __syncthreads();
    #pragma unroll
    for (int d = 1; d < 256; d <<= 1) {
        int t = (tid >= d) ? s[tid - d] : 0;
        __syncthreads();
        s[tid] += t;
        __syncthreads();
    }
    if (i < NNODES) off[i] = s[tid] - v;
    if (tid == 255) bsum[blockIdx.x] = s[255];
}

__global__ __launch_bounds__(512) void scan_p2(int* __restrict__ bsum)
{
    __shared__ int s[512];
    int tid = threadIdx.x;
    int v = (tid < NBLK1) ? bsum[tid] : 0;
    s[tid] = v;
    __syncthreads();
    #pragma unroll
    for (int d = 1; d < 512; d <<= 1) {
        int t = (tid >= d) ? s[tid - d] : 0;
        __syncthreads();
        s[tid] += t;
        __syncthreads();
    }
    if (tid < NBLK1) bsum[tid] = s[tid] - v;
}

__global__ __launch_bounds__(256) void scan_p3(int* __restrict__ off, const int* __restrict__ bsum,
                                               int* __restrict__ cur)
{
    int i = blockIdx.x * 256 + threadIdx.x;
    if (i < NNODES) {
        int v = off[i] + bsum[blockIdx.x];
        off[i] = v;
        cur[i] = v;
    }
    if (i == NNODES) off[NNODES] = NEDGES;
}

__global__ void fill_csr_kernel(const int* __restrict__ src, const int* __restrict__ dst,
                                const float* __restrict__ dis, int* __restrict__ cur,
                                int* __restrict__ csr_src, float* __restrict__ csr_w, int E)
{
    int e = blockIdx.x * 256 + threadIdx.x;
    if (e >= E) return;
    int s = src[e], d = dst[e];
    int p = atomicAdd(&cur[d], 1);
    csr_src[p] = s;
    csr_w[p] = dis[s] * dis[d];
}

// ---------------------------------------------------------------------------
// Pre-GEMM GCN aggregation: out[i] = selfc[i]*T[i] + sum_e w_e * T[src_e]
// uint2 (4 bf16) per lane: full row in ONE load per edge; 4-edge unroll.
// halfq = row length in uint2 (<= 64).
// ---------------------------------------------------------------------------
__global__ __launch_bounds__(256) void gcn_agg2(
    const __hip_bfloat16* __restrict__ Tin, const int* __restrict__ off,
    const int* __restrict__ csr_src, const float* __restrict__ csr_w,
    const float* __restrict__ selfc, __hip_bfloat16* __restrict__ out,
    int halfq)
{
    int wave = threadIdx.x >> 6, lane = threadIdx.x & 63;
    int node = blockIdx.x * 4 + wave;
    if (node >= NNODES) return;
    const uint2* Tp = (const uint2*)Tin;
    uint2* Op = (uint2*)out;
    size_t rb = (size_t)node * halfq;
    bool m = lane < halfq;
    float sc = selfc[node];
    float a0 = 0.f, a1 = 0.f, a2 = 0.f, a3 = 0.f;
    float b0 = 0.f, b1 = 0.f, b2 = 0.f, b3 = 0.f;
    float c0 = 0.f, c1 = 0.f, c2 = 0.f, c3 = 0.f;
    float d0 = 0.f, d1 = 0.f, d2 = 0.f, d3 = 0.f;
    if (m) {
        uint2 v = Tp[rb + lane];
        a0 = bf_lo(v.x) * sc; a1 = bf_hi(v.x) * sc;
        a2 = bf_lo(v.y) * sc; a3 = bf_hi(v.y) * sc;
    }
    int s0 = off[node], s1 = off[node + 1];
    int e = s0;
    for (; e + 4 <= s1; e += 4) {
        int i0 = csr_src[e], i1 = csr_src[e + 1], i2 = csr_src[e + 2], i3 = csr_src[e + 3];
        float w0 = csr_w[e], w1 = csr_w[e + 1], w2 = csr_w[e + 2], w3 = csr_w[e + 3];
        if (m) {
            uint2 v0 = Tp[(size_t)i0 * halfq + lane];
            uint2 v1 = Tp[(size_t)i1 * halfq + lane];
            uint2 v2 = Tp[(size_t)i2 * halfq + lane];
            uint2 v3 = Tp[(size_t)i3 * halfq + lane];
            a0 += bf_lo(v0.x) * w0; a1 += bf_hi(v0.x) * w0;
            a2 += bf_lo(v0.y) * w0; a3 += bf_hi(v0.y) * w0;
            b0 += bf_lo(v1.x) * w1; b1 += bf_hi(v1.x) * w1;
            b2 += bf_lo(v1.y) * w1; b3 += bf_hi(v1.y) * w1;
            c0 += bf_lo(v2.x) * w2; c1 += bf_hi(v2.x) * w2;
            c2 += bf_lo(v2.y) * w2; c3 += bf_hi(v2.y) * w2;
            d0 += bf_lo(v3.x) * w3; d1 += bf_hi(v3.x) * w3;
            d2 += bf_lo(v3.y) * w3; d3 += bf_hi(v3.y) * w3;
        }
    }
    for (; e + 2 <= s1; e += 2) {
        int i0 = csr_src[e], i1 = csr_src[e + 1];
        float w0 = csr_w[e], w1 = csr_w[e + 1];
        if (m) {
            uint2 v0 = Tp[(size_t)i0 * halfq + lane];
            uint2 v1 = Tp[(size_t)i1 * halfq + lane];
            a0 += bf_lo(v0.x) * w0; a1 += bf_hi(v0.x) * w0;
            a2 += bf_lo(v0.y) * w0; a3 += bf_hi(v0.y) * w0;
            b0 += bf_lo(v1.x) * w1; b1 += bf_hi(v1.x) * w1;
            b2 += bf_lo(v1.y) * w1; b3 += bf_hi(v1.y) * w1;
        }
    }
    if (e < s1) {
        int i0 = csr_src[e];
        float w0 = csr_w[e];
        if (m) {
            uint2 v0 = Tp[(size_t)i0 * halfq + lane];
            a0 += bf_lo(v0.x) * w0; a1 += bf_hi(v0.x) * w0;
            a2 += bf_lo(v0.y) * w0; a3 += bf_hi(v0.y) * w0;
        }
    }
    if (m) {
        uint2 o;
        o.x = bf_pack((a0 + b0) + (c0 + d0), (a1 + b1) + (c1 + d1));
        o.y = bf_pack((a2 + b2) + (c2 + d2), (a3 + b3) + (c3 + d3));
        Op[rb + lane] = o;
    }
}

// ---------------------------------------------------------------------------
// segment max pool (bf16 [NNODES][320] -> bf16 [NB][320]); batch sorted
// ---------------------------------------------------------------------------
__global__ __launch_bounds__(256) void pool_max_bf16(
    const __hip_bfloat16* __restrict__ H, const int* __restrict__ batch,
    __hip_bfloat16* __restrict__ g)
{
    int b = blockIdx.x;
    int lo = 0, hi = NNODES;
    while (lo < hi) { int mid = (lo + hi) >> 1; if (batch[mid] < b) lo = mid + 1; else hi = mid; }
    int s = lo;
    hi = NNODES;
    while (lo < hi) { int mid = (lo + hi) >> 1; if (batch[mid] < b + 1) lo = mid + 1; else hi = mid; }
    int e = lo;
    int tid = threadIdx.x;
    if (tid < 160) {
        const unsigned int* Hp = (const unsigned int*)H;
        float mx = 0.f, my = 0.f;
        for (int i = s; i < e; ++i) {
            unsigned int v = Hp[(size_t)i * 160 + tid];
            mx = fmaxf(mx, bf_lo(v));
            my = fmaxf(my, bf_hi(v));
        }
        ((unsigned int*)g)[(size_t)b * 160 + tid] = bf_pack(mx, my);
    }
}

// ---------------------------------------------------------------------------
// Conv branch: transpose to bf16, vectorized bucketed aggregation, weight folding
// ---------------------------------------------------------------------------
__global__ void conv_transpose_kernel(const float* __restrict__ w, __hip_bfloat16* __restrict__ wt)
{
    int idx = blockIdx.x * 256 + threadIdx.x;
    if (idx >= 256000) return;
    int o = idx / 8000;
    int rem = idx - o * 8000;
    int i = rem >> 3, k = rem & 7;
    wt[i * 256 + o * 8 + k] = __float2bfloat16(w[idx]);
}

__global__ __launch_bounds__(256) void conv_agg_kernel(
    const __hip_bfloat16* __restrict__ cwt, const int* __restrict__ target,
    __hip_bfloat16* __restrict__ aggw)
{
    __shared__ int tb_s[SEQ];
    __shared__ int cnt[26];
    __shared__ int boff[27];
    __shared__ int curs[26];
    __shared__ int bucket[SEQ];
    __shared__ float comb[3][256];
    int b = blockIdx.x, tid = threadIdx.x;
    int wave = tid >> 6, lane = tid & 63;
    const int* tb = target + b * SEQ;
    if (tid < 26) cnt[tid] = 0;
    __syncthreads();
    for (int i = tid; i < SEQ; i += 256) {
        int a = tb[i];
        tb_s[i] = a;
        atomicAdd(&cnt[a], 1);
    }
    __syncthreads();
    if (tid == 0) {
        int run = 0;
        for (int a = 0; a < 26; ++a) { boff[a] = run; curs[a] = run; run += cnt[a]; }
        boff[26] = run;
    }
    __syncthreads();
    for (int i = tid; i < SEQ; i += 256) {
        int a = tb_s[i];
        int p = atomicAdd(&curs[a], 1);
        bucket[p] = i;
    }
    __syncthreads();

    const uint2* cw = (const uint2*)cwt;
    uint2* aw = (uint2*)aggw;
    for (int a = 0; a < 26; ++a) {
        int s = boff[a], e = boff[a + 1];
        float x0 = 0.f, x1 = 0.f, x2 = 0.f, x3 = 0.f;
        float y0 = 0.f, y1 = 0.f, y2 = 0.f, y3 = 0.f;
        int j = s + wave;
        for (; j + 4 < e; j += 8) {
            uint2 v = cw[(size_t)bucket[j] * 64 + lane];
            uint2 u = cw[(size_t)bucket[j + 4] * 64 + lane];
            x0 += bf_lo(v.x); x1 += bf_hi(v.x); x2 += bf_lo(v.y); x3 += bf_hi(v.y);
            y0 += bf_lo(u.x); y1 += bf_hi(u.x); y2 += bf_lo(u.y); y3 += bf_hi(u.y);
        }
        if (j < e) {
            uint2 v = cw[(size_t)bucket[j] * 64 + lane];
            x0 += bf_lo(v.x); x1 += bf_hi(v.x); x2 += bf_lo(v.y); x3 += bf_hi(v.y);
        }
        x0 += y0; x1 += y1; x2 += y2; x3 += y3;
        if (wave > 0) {
            comb[wave - 1][lane * 4 + 0] = x0;
            comb[wave - 1][lane * 4 + 1] = x1;
            comb[wave - 1][lane * 4 + 2] = x2;
            comb[wave - 1][lane * 4 + 3] = x3;
        }
        __syncthreads();
        if (wave == 0) {
            x0 += comb[0][lane * 4 + 0] + comb[1][lane * 4 + 0] + comb[2][lane * 4 + 0];
            x1 += comb[0][lane * 4 + 1] + comb[1][lane * 4 + 1] + comb[2][lane * 4 + 1];
            x2 += comb[0][lane * 4 + 2] + comb[1][lane * 4 + 2] + comb[2][lane * 4 + 2];
            x3 += comb[0][lane * 4 + 3] + comb[1][lane * 4 + 3] + comb[2][lane * 4 + 3];
            uint2 o;
            o.x = bf_pack(x0, x1);
            o.y = bf_pack(x2, x3);
            aw[(size_t)b * 1664 + a * 64 + lane] = o;
        }
        __syncthreads();
    }
}

__global__ __launch_bounds__(128) void conv_wc_kernel(
    const float* __restrict__ emb, const float* __restrict__ w_fc, float* __restrict__ Wc)
{
    int o = blockIdx.x;
    int ak = blockIdx.y;
    int a = ak >> 3, k = ak & 7;
    int j = threadIdx.x;
    const float* wp = w_fc + (long)(o * 121) * 128 + j;
    const float* ep = emb + a * 128 + k;
    float s = 0.f;
    #pragma unroll 11
    for (int t = 0; t < 121; ++t) s += ep[t] * wp[t * 128];
    Wc[(long)(a * 256 + o * 8 + k) * 128 + j] = s;
}

__global__ __launch_bounds__(256) void convb_fold2_kernel(
    const float* __restrict__ w_fc, const float* __restrict__ conv_b,
    const float* __restrict__ b_fc, float* __restrict__ xtb)
{
    int j = blockIdx.x;
    __shared__ float red[256];
    __shared__ float cb[32];
    int tid = threadIdx.x;
    if (tid < 32) cb[tid] = conv_b[tid];
    __syncthreads();
    float s = 0.f;
    for (int p = tid; p < 3872; p += 256)
        s += cb[p / 121] * w_fc[(size_t)p * 128 + j];
    red[tid] = s;
    __syncthreads();
    #pragma unroll
    for (int st = 128; st > 0; st >>= 1) {
        if (tid < st) red[tid] += red[tid + st];
        __syncthreads();
    }
    if (tid == 0) xtb[j] = b_fc[j] + red[0];
}

__global__ void xc_convbias_kernel(const float* __restrict__ xtb, float* __restrict__ xc)
{
    int idx = blockIdx.x * 256 + threadIdx.x;
    if (idx >= NB * 128) return;
    int b = idx >> 7, j = idx & 127;
    xc[(long)b * 384 + 128 + j] = xtb[j];
}

// ---------------------------------------------------------------------------
// FG branch: attention row 0 + LayerNorm (bf16 in, bf16 padded out)
// ---------------------------------------------------------------------------
__global__ __launch_bounds__(256) void attn_ln_kernel(
    const __hip_bfloat16* __restrict__ Fb, const __hip_bfloat16* __restrict__ Kf,
    const __hip_bfloat16* __restrict__ Vf, const __hip_bfloat16* __restrict__ q0,
    const float* __restrict__ ln_g, const float* __restrict__ ln_b,
    __hip_bfloat16* __restrict__ out)
{
    int b = blockIdx.x, tid = threadIdx.x;
    __shared__ float qs[HID];
    __shared__ float sc[13];
    __shared__ float red[256];
    __shared__ float red2[256];
    __shared__ float rowv[HID];
    __shared__ float mean_s, inv_s;

    for (int d = tid; d < HID; d += 256) qs[d] = __bfloat162float(q0[(size_t)b * 320 + d]);
    __syncthreads();
    if (tid < 208) {
        int k = tid >> 4, sub = tid & 15;
        const __hip_bfloat16* kr = Kf + ((size_t)b * 13 + k) * 320;
        float p = 0.f;
        for (int d = sub; d < HID; d += 16) p += qs[d] * __bfloat162float(kr[d]);
        red[tid] = p;
    }
    __syncthreads();
    if (tid < 208 && (tid & 15) == 0) {
        float s = 0.f;
        #pragma unroll
        for (int j = 0; j < 16; ++j) s += red[tid + j];
        sc[tid >> 4] = s * 0.0577350269189626f;  // 1/sqrt(300)
    }
    __syncthreads();
    if (tid == 0) {
        float mx = sc[0];
        for (int k = 1; k < 13; ++k) mx = fmaxf(mx, sc[k]);
        float ssum = 0.f;
        for (int k = 0; k < 13; ++k) { float e = expf(sc[k] - mx); sc[k] = e; ssum += e; }
        float inv = 1.0f / ssum;
        for (int k = 0; k < 13; ++k) sc[k] *= inv;
    }
    __syncthreads();
    for (int d = tid; d < HID; d += 256) {
        float v = __bfloat162float(Fb[((size_t)b * 13) * 320 + d]);
        #pragma unroll
        for (int k = 0; k < 13; ++k)
            v += sc[k] * __bfloat162float(Vf[((size_t)b * 13 + k) * 320 + d]);
        rowv[d] = v;
    }
    __syncthreads();
    float s1 = 0.f, s2 = 0.f;
    for (int d = tid; d < HID; d += 256) { float v = rowv[d]; s1 += v; s2 += v * v; }
    red[tid] = s1; red2[tid] = s2;
    __syncthreads();
    for (int s = 128; s > 0; s >>= 1) {
        if (tid < s) { red[tid] += red[tid + s]; red2[tid] += red2[tid + s]; }
        __syncthreads();
    }
    if (tid == 0) {
        float mean = red[0] / (float)HID;
        float var = red2[0] / (float)HID - mean * mean;
        mean_s = mean;
        inv_s = 1.0f / sqrtf(var + 1e-5f);
    }
    __syncthreads();
    for (int d = tid; d < 320; d += 256) {
        float v = 0.f;
        if (d < HID) v = (rowv[d] - mean_s) * inv_s * ln_g[d] + ln_b[d];
        out[(size_t)b * 320 + d] = __float2bfloat16(v);
    }
}

// ---------------------------------------------------------------------------
// final: out[b] = X[b,:512] . out_w + out_b   (fp32)
// ---------------------------------------------------------------------------
__global__ __launch_bounds__(256) void final_out_kernel(
    const float* __restrict__ X, const float* __restrict__ w,
    const float* __restrict__ bias, float* __restrict__ out)
{
    int b = blockIdx.x, tid = threadIdx.x;
    __shared__ float red[256];
    float p = X[(long)b * 512 + tid] * w[tid] + X[(long)b * 512 + tid + 256] * w[tid + 256];
    red[tid] = p;
    __syncthreads();
    for (int s = 128; s > 0; s >>= 1) {
        if (tid < s) red[tid] += red[tid + s];
        __syncthreads();
    }
    if (tid == 0) out[b] = red[0] + bias[0];
}

// ---------------------------------------------------------------------------
// Host launcher
// ---------------------------------------------------------------------------
extern "C" void kernel_launch(void* const* d_in, const int* in_sizes, int n_in,
                              void* d_out, int out_size, void* d_ws, size_t ws_size,
                              hipStream_t stream)
{
    const float* x        = (const float*)d_in[0];
    const int*   ei       = (const int*)d_in[1];
    const int*   batch    = (const int*)d_in[2];
    const int*   target   = (const int*)d_in[3];
    const float* embs     = (const float*)d_in[4];
    const float* W1       = (const float*)d_in[5];
    const float* b1       = (const float*)d_in[6];
    const float* W2       = (const float*)d_in[7];
    const float* b2       = (const float*)d_in[8];
    const float* W3       = (const float*)d_in[9];
    const float* b3       = (const float*)d_in[10];
    const float* fc_g1_w  = (const float*)d_in[11];
    const float* fc_g1_b  = (const float*)d_in[12];
    const float* fc_g2_w  = (const float*)d_in[13];
    const float* fc_g2_b  = (const float*)d_in[14];
    const float* emb_xt   = (const float*)d_in[15];
    const float* conv_w   = (const float*)d_in[16];
    const float* conv_b   = (const float*)d_in[17];
    const float* fc1xt_w  = (const float*)d_in[18];
    const float* fc1xt_b  = (const float*)d_in[19];
    const float* fg_lin_w = (const float*)d_in[20];
    const float* fg_lin_b = (const float*)d_in[21];
    const float* Wq       = (const float*)d_in[22];
    const float* Wk       = (const float*)d_in[23];
    const float* Wv       = (const float*)d_in[24];
    const float* ln_g     = (const float*)d_in[25];
    const float* ln_b     = (const float*)d_in[26];
    const float* fg_out_w = (const float*)d_in[27];
    const float* fg_out_b = (const float*)d_in[28];
    const float* fc1_w    = (const float*)d_in[29];
    const float* fc1_b    = (const float*)d_in[30];
    const float* fc2_w    = (const float*)d_in[31];
    const float* fc2_b    = (const float*)d_in[32];
    const float* out_w    = (const float*)d_in[33];
    const float* out_b    = (const float*)d_in[34];

    const int* src = ei;
    const int* dst = ei + NEDGES;
    typedef __hip_bfloat16 bf;

    // ---- workspace carve (256-B aligned bump allocator) ----
    char* p = (char*)d_ws;
    auto alloc = [&](size_t bytes) { char* r = p; p += (bytes + 255) & ~(size_t)255; return r; };
    bf*   xb      = (bf*)alloc((size_t)NNODES * 96 * 2);
    bf*   T       = (bf*)alloc((size_t)NNODES * 160 * 2);
    bf*   H       = (bf*)alloc((size_t)NNODES * 320 * 2);
    int*  deg     = (int*)alloc(NNODES * 4);                // reused as CSR cursor
    float* dis    = (float*)alloc(NNODES * 4);
    float* selfc  = (float*)alloc(NNODES * 4);
    int*  off     = (int*)alloc((NNODES + 1) * 4);
    int*  bsum    = (int*)alloc(512 * 4);
    int*  csr_src = (int*)alloc(NEDGES * 4);
    float* csr_w  = (float*)alloc(NEDGES * 4);
    bf*   w1t     = (bf*)alloc(78 * 96 * 2);
    bf*   w2t     = (bf*)alloc(156 * 96 * 2);
    bf*   w3t     = (bf*)alloc(312 * 160 * 2);
    bf*   fcg1t   = (bf*)alloc(1024 * 320 * 2);
    bf*   fcg2t   = (bf*)alloc(128 * 1024 * 2);
    bf*   fglint  = (bf*)alloc(300 * 160 * 2);
    bf*   wkt     = (bf*)alloc(300 * 320 * 2);
    bf*   wvt     = (bf*)alloc(300 * 320 * 2);
    bf*   wqt     = (bf*)alloc(300 * 320 * 2);
    bf*   fgoutt  = (bf*)alloc(128 * 320 * 2);
    bf*   fc1t    = (bf*)alloc(1024 * 384 * 2);
    bf*   fc2t    = (bf*)alloc(512 * 1024 * 2);
    bf*   fglwb   = (bf*)alloc(133 * 320 * 2);
    bf*   wk2t    = (bf*)alloc(300 * 160 * 2);
    bf*   wv2t    = (bf*)alloc(300 * 160 * 2);
    bf*   wq2t    = (bf*)alloc(300 * 160 * 2);
    float* bk2    = (float*)alloc(300 * 4);
    float* bv2    = (float*)alloc(300 * 4);
    float* bq2    = (float*)alloc(300 * 4);
    bf*   g       = (bf*)alloc((size_t)NB * 320 * 2);
    bf*   G1b     = (bf*)alloc((size_t)NB * 1024 * 2);
    bf*   embsb   = (bf*)alloc((size_t)NB * 13 * 160 * 2);
    bf*   Fbuf    = (bf*)alloc((size_t)NB * 13 * 320 * 2);
    bf*   Kbuf    = (bf*)alloc((size_t)NB * 13 * 320 * 2);
    bf*   Vbuf    = (bf*)alloc((size_t)NB * 13 * 320 * 2);
    bf*   Qbuf    = (bf*)alloc((size_t)NB * 320 * 2);
    bf*   f2row   = (bf*)alloc((size_t)NB * 320 * 2);
    float* xc     = (float*)alloc((size_t)NB * 384 * 4);
    bf*   xcb     = (bf*)alloc((size_t)NB * 384 * 2);
    float* F2     = (float*)alloc((size_t)NB * 512 * 4);
    bf*   cwt     = (bf*)alloc(256000 * 2);
    bf*   aggwb   = (bf*)alloc((size_t)NB * 6656 * 2);
    float* Wc     = (float*)alloc((size_t)6656 * 128 * 4);
    bf*   Wct     = (bf*)alloc((size_t)128 * 6656 * 2);
    float* xtb    = (float*)alloc(128 * 4);

    // ---- degree / norms / CSR ----
    hipMemsetAsync(deg, 0, NNODES * sizeof(int), stream);
    deg_kernel<<<(NEDGES + 255) / 256, 256, 0, stream>>>(dst, deg, NEDGES);
    scan_p1<<<NBLK1, 256, 0, stream>>>(deg, off, bsum, dis, selfc);
    scan_p2<<<1, 512, 0, stream>>>(bsum);
    scan_p3<<<NBLK1, 256, 0, stream>>>(off, bsum, deg);   // deg becomes cursor
    fill_csr_kernel<<<(NEDGES + 255) / 256, 256, 0, stream>>>(src, dst, dis, deg, csr_src, csr_w, NEDGES);

    // ---- weight transposes (one batched launch) + batched input converts ----
    {
        TBatch tb;
        const float* srcs[12] = {W1, W2, W3, fc_g1_w, fc_g2_w, fg_lin_w, Wk, Wv, Wq, fg_out_w, fc1_w, fc2_w};
        bf* dsts[12]          = {w1t, w2t, w3t, fcg1t, fcg2t, fglint, wkt, wvt, wqt, fgoutt, fc1t, fc2t};
        int Ks[12]    = {78, 78, 156, 312, 1024, 133, 300, 300, 300, 300, 384, 1024};
        int Ns[12]    = {78, 156, 312, 1024, 128, 300, 300, 300, 300, 128, 1024, 512};
        int Kpads[12] = {96, 96, 160, 320, 1024, 160, 320, 320, 320, 320, 384, 1024};
        int bs = 0;
        for (int i = 0; i < 12; ++i) {
            tb.src[i] = srcs[i]; tb.dst[i] = dsts[i];
            tb.K[i] = Ks[i]; tb.N[i] = Ns[i]; tb.Kpad[i] = Kpads[i];
            tb.bstart[i] = bs;
            bs += (int)(((long)Ns[i] * Kpads[i] + 255) / 256);
        }
        tb.bstart[12] = bs;
        transpose_batch_kernel<<<bs, 256, 0, stream>>>(tb);
    }
    {
        CBatch cb;
        cb.src[0] = x;       cb.dst[0] = xb;    cb.M[0] = NNODES;  cb.K[0] = 78;  cb.Kpad[0] = 96;
        cb.src[1] = embs;    cb.dst[1] = embsb; cb.M[1] = NB * 13; cb.K[1] = 133; cb.Kpad[1] = 160;
        cb.src[2] = fg_lin_w;cb.dst[2] = fglwb; cb.M[2] = 133;     cb.K[2] = 300; cb.Kpad[2] = 320;
        int bs = 0;
        for (int i = 0; i < 3; ++i) {
            cb.bstart[i] = bs;
            bs += (int)(((long)cb.M[i] * cb.Kpad[i] + 255) / 256);
        }
        cb.bstart[3] = bs;
        cvt_batch_kernel<<<bs, 256, 0, stream>>>(cb);
    }

    // ---- GCN layers: agg(input) -> XCD-swizzled 128x64 MFMA GEMM ----
    int agrid = (NNODES + 3) / 4;
    gcn_agg2<<<agrid, 256, 0, stream>>>(xb, off, csr_src, csr_w, selfc, T, 24);
    launch_gemm_swz(T, w1t, b1, H, NNODES, 78, 96, 96, 96, 96, stream);

    gcn_agg2<<<agrid, 256, 0, stream>>>(H, off, csr_src, csr_w, selfc, T, 24);
    launch_gemm_swz(T, w2t, b2, H, NNODES, 156, 96, 96, 160, 160, stream);

    gcn_agg2<<<agrid, 256, 0, stream>>>(H, off, csr_src, csr_w, selfc, T, 40);
    launch_gemm_swz(T, w3t, b3, H, NNODES, 312, 160, 160, 320, 320, stream);

    // ---- global max pool + graph MLP ----
    pool_max_bf16<<<NB, 256, 0, stream>>>(H, batch, g);
    launch_gemm_bf16(g, fcg1t, fc_g1_b, G1b, NB, 1024, 320, 320, 1024, 1024, 1, 1, 1, stream);
    launch_gemm_bf16(G1b, fcg2t, fc_g2_b, xc, NB, 128, 1024, 1024, 384, 128, 0, 0, 1, stream);

    // ---- conv branch (folded; split-K MFMA accumulates into xc cols 128..255) ----
    conv_transpose_kernel<<<(256000 + 255) / 256, 256, 0, stream>>>(conv_w, cwt);
    conv_agg_kernel<<<NB, 256, 0, stream>>>(cwt, target, aggwb);
    conv_wc_kernel<<<dim3(32, 208), 128, 0, stream>>>(emb_xt, fc1xt_w, Wc);
    transpose_cvt_kernel<<<((long)128 * 6656 + 255) / 256, 256, 0, stream>>>(Wc, Wct, 6656, 128, 6656);
    convb_fold2_kernel<<<128, 256, 0, stream>>>(fc1xt_w, conv_b, fc1xt_b, xtb);
    xc_convbias_kernel<<<(NB * 128 + 255) / 256, 256, 0, stream>>>(xtb, xc);
    launch_gemm_bf16(aggwb, Wct, nullptr, xc + 128, NB, 128, 6656, 6656, 384, 128, 0, 0, 8, stream);

    // ---- FG branch (batched folded-weight GEMMs) ----
    {
        GB3 p;
        for (int z = 0; z < 3; ++z) {
            p.g[z].Bt = fglwb; p.g[z].bias = nullptr;
            p.g[z].M = 300; p.g[z].N = 133; p.g[z].Kpad = 320;
            p.g[z].lda = 320; p.g[z].ldc = 160; p.g[z].Npad = 160;
        }
        p.g[0].A = wkt; p.g[0].C = wk2t;
        p.g[1].A = wvt; p.g[1].C = wv2t;
        p.g[2].A = wqt; p.g[2].C = wq2t;
        gemm_batch64_kernel<<<dim3(3, 5, 3), 256, 0, stream>>>(p);
    }
    {
        BF3 p;
        p.Wt[0] = wkt; p.out[0] = bk2;
        p.Wt[1] = wvt; p.out[1] = bv2;
        p.Wt[2] = wqt; p.out[2] = bq2;
        bias_fold3_kernel<<<900, 256, 0, stream>>>(fg_lin_b, p);
    }
    {
        GB3 p;
        p.g[0].A = embsb; p.g[0].Bt = fglint; p.g[0].bias = fg_lin_b; p.g[0].C = Fbuf;
        p.g[0].M = NB; p.g[0].N = 300; p.g[0].Kpad = 160; p.g[0].lda = 13 * 160;
        p.g[0].ldc = 13 * 320; p.g[0].Npad = 320;
        p.g[1] = p.g[0];
        p.g[1].Bt = wq2t; p.g[1].bias = bq2; p.g[1].C = Qbuf; p.g[1].ldc = 320;
        p.g[2] = p.g[1];
        gemm_batch64_kernel<<<dim3(5, 16, 2), 256, 0, stream>>>(p);
    }
    {
        GB3 p;
        p.g[0].A = embsb; p.g[0].Bt = wk2t; p.g[0].bias = bk2; p.g[0].C = Kbuf;
        p.g[0].M = NB * 13; p.g[0].N = 300; p.g[0].Kpad = 160; p.g[0].lda = 160;
        p.g[0].ldc = 320; p.g[0].Npad = 320;
        p.g[1] = p.g[0];
        p.g[1].Bt = wv2t; p.g[1].bias = bv2; p.g[1].C = Vbuf;
        p.g[2] = p.g[1];
        gemm_mtb_kernel<<<dim3(5, (NB * 13 + 127) / 128, 2), 256, 0, stream>>>(p);
    }
    attn_ln_kernel<<<NB, 256, 0, stream>>>(Fbuf, Kbuf, Vbuf, Qbuf, ln_g, ln_b, f2row);
    launch_gemm_bf16(f2row, fgoutt, fg_out_b, xc + 256, NB, 128, 320, 320, 384, 128, 0, 0, 1, stream);

    // ---- head ----
    cvt_pad_kernel<<<((long)NB * 384 + 255) / 256, 256, 0, stream>>>(xc, xcb, NB, 384, 384);
    launch_gemm_bf16(xcb, fc1t, fc1_b, G1b, NB, 1024, 384, 384, 1024, 1024, 1, 1, 1, stream);
    launch_gemm_bf16(G1b, fc2t, fc2_b, F2, NB, 512, 1024, 1024, 512, 512, 1, 0, 1, stream);
    final_out_kernel<<<NB, 256, 0, stream>>>(F2, out_w, out_b, (float*)d_out);
}

// Round 17
// 693.478 us; speedup vs baseline: 1.1281x; 1.0171x over previous
//
#include <hip/hip_runtime.h>
#include <hip/hip_bf16.h>
#include <math.h>

// ---------------------------------------------------------------------------
// Problem constants
// ---------------------------------------------------------------------------
#define NNODES 100000
#define NEDGES 400000
#define NB     1024
#define SEQ    1000
#define HID    300
#define NBLK1  ((NNODES + 255) / 256)   // 391

typedef __attribute__((ext_vector_type(8))) short short8;   // 8 bf16 (4 VGPRs)
typedef __attribute__((ext_vector_type(4))) float f32x4;    // MFMA acc

__device__ __forceinline__ float bf_lo(unsigned int v) { return __uint_as_float(v << 16); }
__device__ __forceinline__ float bf_hi(unsigned int v) { return __uint_as_float(v & 0xffff0000u); }
__device__ __forceinline__ unsigned int bf_pack(float lo, float hi) {
    __hip_bfloat16 a = __float2bfloat16(lo), b = __float2bfloat16(hi);
    unsigned short ua = *(unsigned short*)&a, ub = *(unsigned short*)&b;
    return (unsigned int)ua | ((unsigned int)ub << 16);
}

// ---------------------------------------------------------------------------
// fp32 [M][K] -> bf16 [M][Kpad] (zero-padded)
// ---------------------------------------------------------------------------
__global__ void cvt_pad_kernel(const float* __restrict__ in, __hip_bfloat16* __restrict__ out,
                               int M, int K, int Kpad)
{
    long idx = (long)blockIdx.x * 256 + threadIdx.x;
    if (idx >= (long)M * Kpad) return;
    int m = idx / Kpad, k = idx % Kpad;
    out[idx] = __float2bfloat16(k < K ? in[(long)m * K + k] : 0.f);
}

// batched cvt_pad: 3 descriptors, one launch
struct CBatch {
    const float* src[3];
    __hip_bfloat16* dst[3];
    int M[3]; int K[3]; int Kpad[3];
    int bstart[4];
};

__global__ __launch_bounds__(256) void cvt_batch_kernel(CBatch cb)
{
    int blk = blockIdx.x;
    int d = 0;
    while (d < 2 && blk >= cb.bstart[d + 1]) ++d;
    long idx = (long)(blk - cb.bstart[d]) * 256 + threadIdx.x;
    long tot = (long)cb.M[d] * cb.Kpad[d];
    if (idx >= tot) return;
    int Kpad = cb.Kpad[d];
    int m = idx / Kpad, k = idx % Kpad;
    cb.dst[d][idx] = __float2bfloat16(k < cb.K[d] ? cb.src[d][(long)m * cb.K[d] + k] : 0.f);
}

// fp32 [K][N] row-major -> bf16 Bt [N][Kpad] (zero-padded)
__global__ void transpose_cvt_kernel(const float* __restrict__ in, __hip_bfloat16* __restrict__ out,
                                     int K, int N, int Kpad)
{
    long idx = (long)blockIdx.x * 256 + threadIdx.x;
    if (idx >= (long)N * Kpad) return;
    int n = idx / Kpad, k = idx % Kpad;
    out[idx] = __float2bfloat16(k < K ? in[(long)k * N + n] : 0.f);
}

// Batched weight transpose: 12 descriptors in one launch
struct TBatch {
    const float* src[12];
    __hip_bfloat16* dst[12];
    int K[12]; int N[12]; int Kpad[12];
    int bstart[13];
};

__global__ __launch_bounds__(256) void transpose_batch_kernel(TBatch tb)
{
    int blk = blockIdx.x;
    int d = 0;
    while (d < 11 && blk >= tb.bstart[d + 1]) ++d;
    long idx = (long)(blk - tb.bstart[d]) * 256 + threadIdx.x;
    long tot = (long)tb.N[d] * tb.Kpad[d];
    if (idx >= tot) return;
    int Kpad = tb.Kpad[d];
    int n = idx / Kpad, k = idx % Kpad;
    tb.dst[d][idx] = __float2bfloat16(k < tb.K[d] ? tb.src[d][(long)k * tb.N[d] + n] : 0.f);
}

// batched bias fold from TRANSPOSED bf16 weights: out_d[n] = sum_k b[k] * Wt_d[n][k]
struct BF3 { const __hip_bfloat16* Wt[3]; float* out[3]; };

__global__ __launch_bounds__(256) void bias_fold3_kernel(const float* __restrict__ b, BF3 p)
{
    int d = blockIdx.x / 300;
    int n = blockIdx.x % 300;
    __shared__ float red[256];
    int tid = threadIdx.x;
    const __hip_bfloat16* Wt = p.Wt[d];
    float s = 0.f;
    for (int k = tid; k < 300; k += 256)
        s += b[k] * __bfloat162float(Wt[(size_t)n * 320 + k]);
    red[tid] = s;
    __syncthreads();
    #pragma unroll
    for (int st = 128; st > 0; st >>= 1) {
        if (tid < st) red[tid] += red[tid + st];
        __syncthreads();
    }
    if (tid == 0) p.out[d][n] = red[0];
}

// ---------------------------------------------------------------------------
// BF16 MFMA GEMM (TN), 64x64 tile: C = act(A @ Bt^T + bias)
// ---------------------------------------------------------------------------
__global__ __launch_bounds__(256) void gemm_bf16_kernel(
    const __hip_bfloat16* __restrict__ A, const __hip_bfloat16* __restrict__ Bt,
    const float* __restrict__ bias, void* __restrict__ C,
    int M, int N, int Kpad, int lda, int ldc, int Npad_out,
    int relu, int outbf, int chunk)
{
    __shared__ __align__(16) __hip_bfloat16 As[64][40];
    __shared__ __align__(16) __hip_bfloat16 Bs[64][40];
    int tid = threadIdx.x;
    int wave = tid >> 6, lane = tid & 63;
    int wm = wave >> 1, wn = wave & 1;
    int quad = lane >> 4, l16 = lane & 15;
    int row0 = blockIdx.y * 64, col0 = blockIdx.x * 64;

    int kbeg = 0, kend = Kpad;
    if (chunk > 0) { kbeg = blockIdx.z * chunk; kend = kbeg + chunk; if (kend > Kpad) kend = Kpad; }

    f32x4 acc[2][2];
    #pragma unroll
    for (int i = 0; i < 2; ++i)
        #pragma unroll
        for (int j = 0; j < 2; ++j) acc[i][j] = (f32x4){0.f, 0.f, 0.f, 0.f};

    int r = tid >> 2, cch = (tid & 3) * 8;

    for (int k0 = kbeg; k0 < kend; k0 += 32) {
        uint4 av = {0u, 0u, 0u, 0u};
        if (row0 + r < M) av = *(const uint4*)(A + (size_t)(row0 + r) * lda + k0 + cch);
        *(uint4*)(&As[r][cch]) = av;
        uint4 bv = {0u, 0u, 0u, 0u};
        if (col0 + r < N) bv = *(const uint4*)(Bt + (size_t)(col0 + r) * Kpad + k0 + cch);
        *(uint4*)(&Bs[r][cch]) = bv;
        __syncthreads();

        short8 a0 = *(const short8*)(&As[wm * 32 + l16][quad * 8]);
        short8 a1 = *(const short8*)(&As[wm * 32 + 16 + l16][quad * 8]);
        short8 b0 = *(const short8*)(&Bs[wn * 32 + l16][quad * 8]);
        short8 b1 = *(const short8*)(&Bs[wn * 32 + 16 + l16][quad * 8]);
        acc[0][0] = __builtin_amdgcn_mfma_f32_16x16x32_bf16(a0, b0, acc[0][0], 0, 0, 0);
        acc[0][1] = __builtin_amdgcn_mfma_f32_16x16x32_bf16(a0, b1, acc[0][1], 0, 0, 0);
        acc[1][0] = __builtin_amdgcn_mfma_f32_16x16x32_bf16(a1, b0, acc[1][0], 0, 0, 0);
        acc[1][1] = __builtin_amdgcn_mfma_f32_16x16x32_bf16(a1, b1, acc[1][1], 0, 0, 0);
        __syncthreads();
    }

    #pragma unroll
    for (int ti = 0; ti < 2; ++ti) {
        int rbase = row0 + wm * 32 + ti * 16 + quad * 4;
        #pragma unroll
        for (int tj = 0; tj < 2; ++tj) {
            int cc = col0 + wn * 32 + tj * 16 + l16;
            if (cc >= Npad_out) continue;
            #pragma unroll
            for (int reg = 0; reg < 4; ++reg) {
                int rr = rbase + reg;
                if (rr >= M) continue;
                float v = acc[ti][tj][reg];
                if (chunk > 0) {
                    if (cc < N) atomicAdd((float*)C + (size_t)rr * ldc + cc, v);
                } else {
                    float ov = 0.f;
                    if (cc < N) {
                        if (bias) v += bias[cc];
                        if (relu) v = fmaxf(v, 0.f);
                        ov = v;
                    }
                    if (outbf) ((__hip_bfloat16*)C)[(size_t)rr * ldc + cc] = __float2bfloat16(ov);
                    else       ((float*)C)[(size_t)rr * ldc + cc] = ov;
                }
            }
        }
    }
}

static void launch_gemm_bf16(const __hip_bfloat16* A, const __hip_bfloat16* Bt, const float* bias,
                             void* C, int M, int N, int Kpad, int lda, int ldc, int Npad_out,
                             int relu, int outbf, int splitz, hipStream_t stream)
{
    int cover = N > Npad_out ? N : Npad_out;
    int chunk = (splitz > 1) ? (Kpad / splitz) : 0;
    dim3 grid((cover + 63) / 64, (M + 63) / 64, splitz > 1 ? splitz : 1);
    gemm_bf16_kernel<<<grid, 256, 0, stream>>>(A, Bt, bias, C, M, N, Kpad, lda, ldc, Npad_out,
                                               relu, outbf, chunk);
}

// ---------------------------------------------------------------------------
// Batched 64x64 GEMM (z selects descriptor). bf16 out, no relu.
// ---------------------------------------------------------------------------
struct GB { const __hip_bfloat16* A; const __hip_bfloat16* Bt; const float* bias;
            __hip_bfloat16* C; int M, N, Kpad, lda, ldc, Npad; };
struct GB3 { GB g[3]; };

__global__ __launch_bounds__(256) void gemm_batch64_kernel(GB3 p)
{
    GB gb = p.g[blockIdx.z];
    __shared__ __align__(16) __hip_bfloat16 As[64][40];
    __shared__ __align__(16) __hip_bfloat16 Bs[64][40];
    int tid = threadIdx.x;
    int wave = tid >> 6, lane = tid & 63;
    int wm = wave >> 1, wn = wave & 1;
    int quad = lane >> 4, l16 = lane & 15;
    int row0 = blockIdx.y * 64, col0 = blockIdx.x * 64;

    f32x4 acc[2][2];
    #pragma unroll
    for (int i = 0; i < 2; ++i)
        #pragma unroll
        for (int j = 0; j < 2; ++j) acc[i][j] = (f32x4){0.f, 0.f, 0.f, 0.f};

    int r = tid >> 2, cch = (tid & 3) * 8;

    for (int k0 = 0; k0 < gb.Kpad; k0 += 32) {
        uint4 av = {0u, 0u, 0u, 0u};
        if (row0 + r < gb.M) av = *(const uint4*)(gb.A + (size_t)(row0 + r) * gb.lda + k0 + cch);
        *(uint4*)(&As[r][cch]) = av;
        uint4 bv = {0u, 0u, 0u, 0u};
        if (col0 + r < gb.N) bv = *(const uint4*)(gb.Bt + (size_t)(col0 + r) * gb.Kpad + k0 + cch);
        *(uint4*)(&Bs[r][cch]) = bv;
        __syncthreads();

        short8 a0 = *(const short8*)(&As[wm * 32 + l16][quad * 8]);
        short8 a1 = *(const short8*)(&As[wm * 32 + 16 + l16][quad * 8]);
        short8 b0 = *(const short8*)(&Bs[wn * 32 + l16][quad * 8]);
        short8 b1 = *(const short8*)(&Bs[wn * 32 + 16 + l16][quad * 8]);
        acc[0][0] = __builtin_amdgcn_mfma_f32_16x16x32_bf16(a0, b0, acc[0][0], 0, 0, 0);
        acc[0][1] = __builtin_amdgcn_mfma_f32_16x16x32_bf16(a0, b1, acc[0][1], 0, 0, 0);
        acc[1][0] = __builtin_amdgcn_mfma_f32_16x16x32_bf16(a1, b0, acc[1][0], 0, 0, 0);
        acc[1][1] = __builtin_amdgcn_mfma_f32_16x16x32_bf16(a1, b1, acc[1][1], 0, 0, 0);
        __syncthreads();
    }

    #pragma unroll
    for (int ti = 0; ti < 2; ++ti) {
        int rbase = row0 + wm * 32 + ti * 16 + quad * 4;
        #pragma unroll
        for (int tj = 0; tj < 2; ++tj) {
            int cc = col0 + wn * 32 + tj * 16 + l16;
            if (cc >= gb.Npad) continue;
            #pragma unroll
            for (int reg = 0; reg < 4; ++reg) {
                int rr = rbase + reg;
                if (rr >= gb.M) continue;
                float ov = 0.f;
                if (cc < gb.N) {
                    float v = acc[ti][tj][reg];
                    if (gb.bias) v += gb.bias[cc];
                    ov = v;
                }
                gb.C[(size_t)rr * gb.ldc + cc] = __float2bfloat16(ov);
            }
        }
    }
}

// ---------------------------------------------------------------------------
// Batched 128x64 GEMM (z selects descriptor). bf16 out, no relu. (K/V)
// ---------------------------------------------------------------------------
__global__ __launch_bounds__(256) void gemm_mtb_kernel(GB3 p)
{
    GB gb = p.g[blockIdx.z];
    __shared__ __align__(16) __hip_bfloat16 As[128][40];
    __shared__ __align__(16) __hip_bfloat16 Bs[64][40];
    int tid = threadIdx.x;
    int wave = tid >> 6, lane = tid & 63;
    int wm = wave >> 1, wn = wave & 1;
    int quad = lane >> 4, l16 = lane & 15;
    int row0 = blockIdx.y * 128, col0 = blockIdx.x * 64;

    f32x4 acc[4][2];
    #pragma unroll
    for (int i = 0; i < 4; ++i)
        #pragma unroll
        for (int j = 0; j < 2; ++j) acc[i][j] = (f32x4){0.f, 0.f, 0.f, 0.f};

    int r = tid >> 2, cch = (tid & 3) * 8;

    for (int k0 = 0; k0 < gb.Kpad; k0 += 32) {
        uint4 av0 = {0u, 0u, 0u, 0u}, av1 = {0u, 0u, 0u, 0u}, bv = {0u, 0u, 0u, 0u};
        if (row0 + r < gb.M)      av0 = *(const uint4*)(gb.A + (size_t)(row0 + r) * gb.lda + k0 + cch);
        if (row0 + r + 64 < gb.M) av1 = *(const uint4*)(gb.A + (size_t)(row0 + r + 64) * gb.lda + k0 + cch);
        if (col0 + r < gb.N)      bv  = *(const uint4*)(gb.Bt + (size_t)(col0 + r) * gb.Kpad + k0 + cch);
        *(uint4*)(&As[r][cch]) = av0;
        *(uint4*)(&As[r + 64][cch]) = av1;
        *(uint4*)(&Bs[r][cch]) = bv;
        __syncthreads();

        short8 af[4], bfr[2];
        #pragma unroll
        for (int i = 0; i < 4; ++i)
            af[i] = *(const short8*)(&As[wm * 64 + i * 16 + l16][quad * 8]);
        #pragma unroll
        for (int j = 0; j < 2; ++j)
            bfr[j] = *(const short8*)(&Bs[wn * 32 + j * 16 + l16][quad * 8]);
        #pragma unroll
        for (int i = 0; i < 4; ++i)
            #pragma unroll
            for (int j = 0; j < 2; ++j)
                acc[i][j] = __builtin_amdgcn_mfma_f32_16x16x32_bf16(af[i], bfr[j], acc[i][j], 0, 0, 0);
        __syncthreads();
    }

    #pragma unroll
    for (int ti = 0; ti < 4; ++ti) {
        int rbase = row0 + wm * 64 + ti * 16 + quad * 4;
        #pragma unroll
        for (int tj = 0; tj < 2; ++tj) {
            int cc = col0 + wn * 32 + tj * 16 + l16;
            if (cc >= gb.Npad) continue;
            #pragma unroll
            for (int reg = 0; reg < 4; ++reg) {
                int rr = rbase + reg;
                if (rr >= gb.M) continue;
                float ov = 0.f;
                if (cc < gb.N) {
                    float v = acc[ti][tj][reg];
                    if (gb.bias) v += gb.bias[cc];
                    ov = v;
                }
                gb.C[(size_t)rr * gb.ldc + cc] = __float2bfloat16(ov);
            }
        }
    }
}

// ---------------------------------------------------------------------------
// Node-layer GEMM: 128x64 staged tile + XCD-aware mod-8 swizzle
// ---------------------------------------------------------------------------
__global__ __launch_bounds__(256) void gemm_swz_kernel(
    const __hip_bfloat16* __restrict__ A, const __hip_bfloat16* __restrict__ Bt,
    const float* __restrict__ bias, __hip_bfloat16* __restrict__ C,
    int M, int N, int Kpad, int lda, int ldc, int Npad_out, int nct, int nstrips)
{
    int id = blockIdx.x;
    int rr8 = id & 7, q = id >> 3;
    int c = q % nct, sgrp = q / nct;
    int s = sgrp * 8 + rr8;
    if (s >= nstrips) return;
    int row0 = s * 128, col0 = c * 64;

    __shared__ __align__(16) __hip_bfloat16 As[128][40];
    __shared__ __align__(16) __hip_bfloat16 Bs[64][40];
    int tid = threadIdx.x;
    int wave = tid >> 6, lane = tid & 63;
    int wm = wave >> 1, wn = wave & 1;
    int quad = lane >> 4, l16 = lane & 15;

    f32x4 acc[4][2];
    #pragma unroll
    for (int i = 0; i < 4; ++i)
        #pragma unroll
        for (int j = 0; j < 2; ++j) acc[i][j] = (f32x4){0.f, 0.f, 0.f, 0.f};

    int r = tid >> 2, cch = (tid & 3) * 8;

    for (int k0 = 0; k0 < Kpad; k0 += 32) {
        uint4 av0 = {0u, 0u, 0u, 0u}, av1 = {0u, 0u, 0u, 0u}, bv = {0u, 0u, 0u, 0u};
        if (row0 + r < M)      av0 = *(const uint4*)(A + (size_t)(row0 + r) * lda + k0 + cch);
        if (row0 + r + 64 < M) av1 = *(const uint4*)(A + (size_t)(row0 + r + 64) * lda + k0 + cch);
        if (col0 + r < N)      bv  = *(const uint4*)(Bt + (size_t)(col0 + r) * Kpad + k0 + cch);
        *(uint4*)(&As[r][cch]) = av0;
        *(uint4*)(&As[r + 64][cch]) = av1;
        *(uint4*)(&Bs[r][cch]) = bv;
        __syncthreads();

        short8 af[4], bfr[2];
        #pragma unroll
        for (int i = 0; i < 4; ++i)
            af[i] = *(const short8*)(&As[wm * 64 + i * 16 + l16][quad * 8]);
        #pragma unroll
        for (int j = 0; j < 2; ++j)
            bfr[j] = *(const short8*)(&Bs[wn * 32 + j * 16 + l16][quad * 8]);
        #pragma unroll
        for (int i = 0; i < 4; ++i)
            #pragma unroll
            for (int j = 0; j < 2; ++j)
                acc[i][j] = __builtin_amdgcn_mfma_f32_16x16x32_bf16(af[i], bfr[j], acc[i][j], 0, 0, 0);
        __syncthreads();
    }

    #pragma unroll
    for (int ti = 0; ti < 4; ++ti) {
        int rbase = row0 + wm * 64 + ti * 16 + quad * 4;
        #pragma unroll
        for (int tj = 0; tj < 2; ++tj) {
            int cc = col0 + wn * 32 + tj * 16 + l16;
            if (cc >= Npad_out) continue;
            #pragma unroll
            for (int reg = 0; reg < 4; ++reg) {
                int rrow = rbase + reg;
                if (rrow >= M) continue;
                float ov = 0.f;
                if (cc < N) ov = fmaxf(acc[ti][tj][reg] + bias[cc], 0.f);
                C[(size_t)rrow * ldc + cc] = __float2bfloat16(ov);
            }
        }
    }
}

static void launch_gemm_swz(const __hip_bfloat16* A, const __hip_bfloat16* Bt, const float* bias,
                            __hip_bfloat16* C, int M, int N, int Kpad, int lda, int ldc,
                            int Npad_out, hipStream_t stream)
{
    int nct = (Npad_out + 63) / 64;
    int nstrips = (M + 127) / 128;
    int G = 8 * nct * ((nstrips + 7) / 8);
    gemm_swz_kernel<<<G, 256, 0, stream>>>(A, Bt, bias, C, M, N, Kpad, lda, ldc, Npad_out,
                                           nct, nstrips);
}

// ---------------------------------------------------------------------------
// GCN: degree, norms(+scan p1 fused), multi-block scan, CSR build
// ---------------------------------------------------------------------------
__global__ void deg_kernel(const int* __restrict__ dst, int* __restrict__ deg, int E)
{
    int e = blockIdx.x * 256 + threadIdx.x;
    if (e < E) atomicAdd(&deg[dst[e]], 1);
}

__global__ __launch_bounds__(256) void scan_p1(const int* __restrict__ deg,
                                               int* __restrict__ off, int* __restrict__ bsum,
                                               float* __restrict__ dis, float* __restrict__ selfc)
{
    __shared__ int s[256];
    int tid = threadIdx.x;
    int i = blockIdx.x * 256 + tid;
    int v = (i < NNODES) ? deg[i] : 0;
    if (i < NNODES) {
        float d = (float)v + 1.0f;
        float r = 1.0f / sqrtf(d);
        dis[i] = r;
        selfc[i] = r * r;
    }
    s[tid] = v;
    __syncthreads();
    #pragma unroll
    for (int d = 1; d < 256; d <<= 1) {
        int t = (tid >= d) ? s[tid - d] : 0;
        __syncthreads();
        s[tid] += t;
        __syncthreads();
    }
    if (i < NNODES) off[i] = s[tid] - v;
    if (tid == 255) bsum[blockIdx.x] = s[255];
}

__global__ __launch_bounds__(512) void scan_p2(int* __restrict__ bsum)
{
    __shared__ int s[512];
    int tid = threadIdx.x;
    int v = (tid < NBLK1) ? bsum[tid] : 0;
    s[tid] = v;
    __syncthreads();
    #pragma unroll
    for (int d = 1; d < 512; d <<= 1) {
        int t = (tid >= d) ? s[tid - d] : 0;
        __syncthreads();
        s[tid] += t;
        __syncthreads();
    }
    if (tid < NBLK1) bsum[tid] = s[tid] - v;
}

__global__ __launch_bounds__(256) void scan_p3(int* __restrict__ off, const int* __restrict__ bsum,
                                               int* __restrict__ cur)
{
    int i = blockIdx.x * 256 + threadIdx.x;
    if (i < NNODES) {
        int v = off[i] + bsum[blockIdx.x];
        off[i] = v;
        cur[i] = v;
    }
    if (i == NNODES) off[NNODES] = NEDGES;
}

__global__ void fill_csr_kernel(const int* __restrict__ src, const int* __restrict__ dst,
                                const float* __restrict__ dis, int* __restrict__ cur,
                                int* __restrict__ csr_src, float* __restrict__ csr_w, int E)
{
    int e = blockIdx.x * 256 + threadIdx.x;
    if (e >= E) return;
    int s = src[e], d = dst[e];
    int p = atomicAdd(&cur[d], 1);
    csr_src[p] = s;
    csr_w[p] = dis[s] * dis[d];
}

// ---------------------------------------------------------------------------
// Pre-GEMM GCN aggregation: out[i] = selfc[i]*T[i] + sum_e w_e * T[src_e]
// uint2 (4 bf16) per lane: full row in ONE load per edge; 4-edge unroll.
// ---------------------------------------------------------------------------
__global__ __launch_bounds__(256) void gcn_agg2(
    const __hip_bfloat16* __restrict__ Tin, const int* __restrict__ off,
    const int* __restrict__ csr_src, const float* __restrict__ csr_w,
    const float* __restrict__ selfc, __hip_bfloat16* __restrict__ out,
    int halfq)
{
    int wave = threadIdx.x >> 6, lane = threadIdx.x & 63;
    int node = blockIdx.x * 4 + wave;
    if (node >= NNODES) return;
    const uint2* Tp = (const uint2*)Tin;
    uint2* Op = (uint2*)out;
    size_t rb = (size_t)node * halfq;
    bool m = lane < halfq;
    float sc = selfc[node];
    float a0 = 0.f, a1 = 0.f, a2 = 0.f, a3 = 0.f;
    float b0 = 0.f, b1 = 0.f, b2 = 0.f, b3 = 0.f;
    float c0 = 0.f, c1 = 0.f, c2 = 0.f, c3 = 0.f;
    float d0 = 0.f, d1 = 0.f, d2 = 0.f, d3 = 0.f;
    if (m) {
        uint2 v = Tp[rb + lane];
        a0 = bf_lo(v.x) * sc; a1 = bf_hi(v.x) * sc;
        a2 = bf_lo(v.y) * sc; a3 = bf_hi(v.y) * sc;
    }
    int s0 = off[node], s1 = off[node + 1];
    int e = s0;
    for (; e + 4 <= s1; e += 4) {
        int i0 = csr_src[e], i1 = csr_src[e + 1], i2 = csr_src[e + 2], i3 = csr_src[e + 3];
        float w0 = csr_w[e], w1 = csr_w[e + 1], w2 = csr_w[e + 2], w3 = csr_w[e + 3];
        if (m) {
            uint2 v0 = Tp[(size_t)i0 * halfq + lane];
            uint2 v1 = Tp[(size_t)i1 * halfq + lane];
            uint2 v2 = Tp[(size_t)i2 * halfq + lane];
            uint2 v3 = Tp[(size_t)i3 * halfq + lane];
            a0 += bf_lo(v0.x) * w0; a1 += bf_hi(v0.x) * w0;
            a2 += bf_lo(v0.y) * w0; a3 += bf_hi(v0.y) * w0;
            b0 += bf_lo(v1.x) * w1; b1 += bf_hi(v1.x) * w1;
            b2 += bf_lo(v1.y) * w1; b3 += bf_hi(v1.y) * w1;
            c0 += bf_lo(v2.x) * w2; c1 += bf_hi(v2.x) * w2;
            c2 += bf_lo(v2.y) * w2; c3 += bf_hi(v2.y) * w2;
            d0 += bf_lo(v3.x) * w3; d1 += bf_hi(v3.x) * w3;
            d2 += bf_lo(v3.y) * w3; d3 += bf_hi(v3.y) * w3;
        }
    }
    for (; e + 2 <= s1; e += 2) {
        int i0 = csr_src[e], i1 = csr_src[e + 1];
        float w0 = csr_w[e], w1 = csr_w[e + 1];
        if (m) {
            uint2 v0 = Tp[(size_t)i0 * halfq + lane];
            uint2 v1 = Tp[(size_t)i1 * halfq + lane];
            a0 += bf_lo(v0.x) * w0; a1 += bf_hi(v0.x) * w0;
            a2 += bf_lo(v0.y) * w0; a3 += bf_hi(v0.y) * w0;
            b0 += bf_lo(v1.x) * w1; b1 += bf_hi(v1.x) * w1;
            b2 += bf_lo(v1.y) * w1; b3 += bf_hi(v1.y) * w1;
        }
    }
    if (e < s1) {
        int i0 = csr_src[e];
        float w0 = csr_w[e];
        if (m) {
            uint2 v0 = Tp[(size_t)i0 * halfq + lane];
            a0 += bf_lo(v0.x) * w0; a1 += bf_hi(v0.x) * w0;
            a2 += bf_lo(v0.y) * w0; a3 += bf_hi(v0.y) * w0;
        }
    }
    if (m) {
        uint2 o;
        o.x = bf_pack((a0 + b0) + (c0 + d0), (a1 + b1) + (c1 + d1));
        o.y = bf_pack((a2 + b2) + (c2 + d2), (a3 + b3) + (c3 + d3));
        Op[rb + lane] = o;
    }
}

// ---------------------------------------------------------------------------
// segment max pool (bf16 [NNODES][320] -> bf16 [NB][320]); batch sorted
// ---------------------------------------------------------------------------
__global__ __launch_bounds__(256) void pool_max_bf16(
    const __hip_bfloat16* __restrict__ H, const int* __restrict__ batch,
    __hip_bfloat16* __restrict__ g)
{
    int b = blockIdx.x;
    int lo = 0, hi = NNODES;
    while (lo < hi) { int mid = (lo + hi) >> 1; if (batch[mid] < b) lo = mid + 1; else hi = mid; }
    int s = lo;
    hi = NNODES;
    while (lo < hi) { int mid = (lo + hi) >> 1; if (batch[mid] < b + 1) lo = mid + 1; else hi = mid; }
    int e = lo;
    int tid = threadIdx.x;
    if (tid < 160) {
        const unsigned int* Hp = (const unsigned int*)H;
        float mx = 0.f, my = 0.f;
        for (int i = s; i < e; ++i) {
            unsigned int v = Hp[(size_t)i * 160 + tid];
            mx = fmaxf(mx, bf_lo(v));
            my = fmaxf(my, bf_hi(v));
        }
        ((unsigned int*)g)[(size_t)b * 160 + tid] = bf_pack(mx, my);
    }
}

// ---------------------------------------------------------------------------
// Conv branch: transpose to bf16, letter-partitioned bucketed aggregation
// ---------------------------------------------------------------------------
__global__ void conv_transpose_kernel(const float* __restrict__ w, __hip_bfloat16* __restrict__ wt)
{
    int idx = blockIdx.x * 256 + threadIdx.x;
    if (idx >= 256000) return;
    int o = idx / 8000;
    int rem = idx - o * 8000;
    int i = rem >> 3, k = rem & 7;
    wt[i * 256 + o * 8 + k] = __float2bfloat16(w[idx]);
}

// aggw[b][a*256+c] = sum_{i: target[b,i]==a} cwt[i][c]
// parallel bucketing; waves own whole letters (balanced by prefix sums):
// no barriers / cross-wave combine in the accumulate phase.
__global__ __launch_bounds__(256) void conv_agg_kernel(
    const __hip_bfloat16* __restrict__ cwt, const int* __restrict__ target,
    __hip_bfloat16* __restrict__ aggw)
{
    __shared__ int tb_s[SEQ];
    __shared__ int cnt[26];
    __shared__ int boff[27];
    __shared__ int curs[26];
    __shared__ int bucket[SEQ];
    __shared__ int wsplit[5];
    int b = blockIdx.x, tid = threadIdx.x;
    int wave = tid >> 6, lane = tid & 63;
    const int* tb = target + b * SEQ;
    if (tid < 26) cnt[tid] = 0;
    __syncthreads();
    for (int i = tid; i < SEQ; i += 256) {
        int a = tb[i];
        tb_s[i] = a;
        atomicAdd(&cnt[a], 1);
    }
    __syncthreads();
    if (tid == 0) {
        int run = 0;
        for (int a = 0; a < 26; ++a) { boff[a] = run; curs[a] = run; run += cnt[a]; }
        boff[26] = run;
        wsplit[0] = 0; wsplit[4] = 26;
        for (int w = 1; w < 4; ++w) {
            int a = 0;
            while (a < 26 && boff[a] < (w * SEQ) / 4) ++a;
            wsplit[w] = a;
        }
    }
    __syncthreads();
    for (int i = tid; i < SEQ; i += 256) {
        int a = tb_s[i];
        int p = atomicAdd(&curs[a], 1);
        bucket[p] = i;
    }
    __syncthreads();

    const uint2* cw = (const uint2*)cwt;
    uint2* aw = (uint2*)aggw;
    int aBeg = wsplit[wave], aEnd = wsplit[wave + 1];
    for (int a = aBeg; a < aEnd; ++a) {
        int s = boff[a], e = boff[a + 1];
        float x0 = 0.f, x1 = 0.f, x2 = 0.f, x3 = 0.f;
        float y0 = 0.f, y1 = 0.f, y2 = 0.f, y3 = 0.f;
        float z0 = 0.f, z1 = 0.f, z2 = 0.f, z3 = 0.f;
        float u0 = 0.f, u1 = 0.f, u2 = 0.f, u3 = 0.f;
        int j = s;
        for (; j + 4 <= e; j += 4) {
            uint2 v0 = cw[(size_t)bucket[j]     * 64 + lane];
            uint2 v1 = cw[(size_t)bucket[j + 1] * 64 + lane];
            uint2 v2 = cw[(size_t)bucket[j + 2] * 64 + lane];
            uint2 v3 = cw[(size_t)bucket[j + 3] * 64 + lane];
            x0 += bf_lo(v0.x); x1 += bf_hi(v0.x); x2 += bf_lo(v0.y); x3 += bf_hi(v0.y);
            y0 += bf_lo(v1.x); y1 += bf_hi(v1.x); y2 += bf_lo(v1.y); y3 += bf_hi(v1.y);
            z0 += bf_lo(v2.x); z1 += bf_hi(v2.x); z2 += bf_lo(v2.y); z3 += bf_hi(v2.y);
            u0 += bf_lo(v3.x); u1 += bf_hi(v3.x); u2 += bf_lo(v3.y); u3 += bf_hi(v3.y);
        }
        for (; j < e; ++j) {
            uint2 v = cw[(size_t)bucket[j] * 64 + lane];
            x0 += bf_lo(v.x); x1 += bf_hi(v.x); x2 += bf_lo(v.y); x3 += bf_hi(v.y);
        }
        uint2 o;
        o.x = bf_pack((x0 + y0) + (z0 + u0), (x1 + y1) + (z1 + u1));
        o.y = bf_pack((x2 + y2) + (z2 + u2), (x3 + y3) + (z3 + u3));
        aw[(size_t)b * 1664 + a * 64 + lane] = o;
    }
}

__global__ __launch_bounds__(128) void conv_wc_kernel(
    const float* __restrict__ emb, const float* __restrict__ w_fc, float* __restrict__ Wc)
{
    int o = blockIdx.x;
    int ak = blockIdx.y;
    int a = ak >> 3, k = ak & 7;
    int j = threadIdx.x;
    const float* wp = w_fc + (long)(o * 121) * 128 + j;
    const float* ep = emb + a * 128 + k;
    float s = 0.f;
    #pragma unroll 11
    for (int t = 0; t < 121; ++t) s += ep[t] * wp[t * 128];
    Wc[(long)(a * 256 + o * 8 + k) * 128 + j] = s;
}

__global__ __launch_bounds__(256) void convb_fold2_kernel(
    const float* __restrict__ w_fc, const float* __restrict__ conv_b,
    const float* __restrict__ b_fc, float* __restrict__ xtb)
{
    int j = blockIdx.x;
    __shared__ float red[256];
    __shared__ float cb[32];
    int tid = threadIdx.x;
    if (tid < 32) cb[tid] = conv_b[tid];
    __syncthreads();
    float s = 0.f;
    for (int p = tid; p < 3872; p += 256)
        s += cb[p / 121] * w_fc[(size_t)p * 128 + j];
    red[tid] = s;
    __syncthreads();
    #pragma unroll
    for (int st = 128; st > 0; st >>= 1) {
        if (tid < st) red[tid] += red[tid + st];
        __syncthreads();
    }
    if (tid == 0) xtb[j] = b_fc[j] + red[0];
}

__global__ void xc_convbias_kernel(const float* __restrict__ xtb, float* __restrict__ xc)
{
    int idx = blockIdx.x * 256 + threadIdx.x;
    if (idx >= NB * 128) return;
    int b = idx >> 7, j = idx & 127;
    xc[(long)b * 384 + 128 + j] = xtb[j];
}

// ---------------------------------------------------------------------------
// FG branch: attention row 0 + LayerNorm (bf16 in, bf16 padded out)
// ---------------------------------------------------------------------------
__global__ __launch_bounds__(256) void attn_ln_kernel(
    const __hip_bfloat16* __restrict__ Fb, const __hip_bfloat16* __restrict__ Kf,
    const __hip_bfloat16* __restrict__ Vf, const __hip_bfloat16* __restrict__ q0,
    const float* __restrict__ ln_g, const float* __restrict__ ln_b,
    __hip_bfloat16* __restrict__ out)
{
    int b = blockIdx.x, tid = threadIdx.x;
    __shared__ float qs[HID];
    __shared__ float sc[13];
    __shared__ float red[256];
    __shared__ float red2[256];
    __shared__ float rowv[HID];
    __shared__ float mean_s, inv_s;

    for (int d = tid; d < HID; d += 256) qs[d] = __bfloat162float(q0[(size_t)b * 320 + d]);
    __syncthreads();
    if (tid < 208) {
        int k = tid >> 4, sub = tid & 15;
        const __hip_bfloat16* kr = Kf + ((size_t)b * 13 + k) * 320;
        float p = 0.f;
        for (int d = sub; d < HID; d += 16) p += qs[d] * __bfloat162float(kr[d]);
        red[tid] = p;
    }
    __syncthreads();
    if (tid < 208 && (tid & 15) == 0) {
        float s = 0.f;
        #pragma unroll
        for (int j = 0; j < 16; ++j) s += red[tid + j];
        sc[tid >> 4] = s * 0.0577350269189626f;  // 1/sqrt(300)
    }
    __syncthreads();
    if (tid == 0) {
        float mx = sc[0];
        for (int k = 1; k < 13; ++k) mx = fmaxf(mx, sc[k]);
        float ssum = 0.f;
        for (int k = 0; k < 13; ++k) { float e = expf(sc[k] - mx); sc[k] = e; ssum += e; }
        float inv = 1.0f / ssum;
        for (int k = 0; k < 13; ++k) sc[k] *= inv;
    }
    __syncthreads();
    for (int d = tid; d < HID; d += 256) {
        float v = __bfloat162float(Fb[((size_t)b * 13) * 320 + d]);
        #pragma unroll
        for (int k = 0; k < 13; ++k)
            v += sc[k] * __bfloat162float(Vf[((size_t)b * 13 + k) * 320 + d]);
        rowv[d] = v;
    }
    __syncthreads();
    float s1 = 0.f, s2 = 0.f;
    for (int d = tid; d < HID; d += 256) { float v = rowv[d]; s1 += v; s2 += v * v; }
    red[tid] = s1; red2[tid] = s2;
    __syncthreads();
    for (int s = 128; s > 0; s >>= 1) {
        if (tid < s) { red[tid] += red[tid + s]; red2[tid] += red2[tid + s]; }
        __syncthreads();
    }
    if (tid == 0) {
        float mean = red[0] / (float)HID;
        float var = red2[0] / (float)HID - mean * mean;
        mean_s = mean;
        inv_s = 1.0f / sqrtf(var + 1e-5f);
    }
    __syncthreads();
    for (int d = tid; d < 320; d += 256) {
        float v = 0.f;
        if (d < HID) v = (rowv[d] - mean_s) * inv_s * ln_g[d] + ln_b[d];
        out[(size_t)b * 320 + d] = __float2bfloat16(v);
    }
}

// ---------------------------------------------------------------------------
// final: out[b] = X[b,:512] . out_w + out_b   (fp32)
// ---------------------------------------------------------------------------
__global__ __launch_bounds__(256) void final_out_kernel(
    const float* __restrict__ X, const float* __restrict__ w,
    const float* __restrict__ bias, float* __restrict__ out)
{
    int b = blockIdx.x, tid = threadIdx.x;
    __shared__ float red[256];
    float p = X[(long)b * 512 + tid] * w[tid] + X[(long)b * 512 + tid + 256] * w[tid + 256];
    red[tid] = p;
    __syncthreads();
    for (int s = 128; s > 0; s >>= 1) {
        if (tid < s) red[tid] += red[tid + s];
        __syncthreads();
    }
    if (tid == 0) out[b] = red[0] + bias[0];
}

// ---------------------------------------------------------------------------
// Host launcher
// ---------------------------------------------------------------------------
extern "C" void kernel_launch(void* const* d_in, const int* in_sizes, int n_in,
                              void* d_out, int out_size, void* d_ws, size_t ws_size,
                              hipStream_t stream)
{
    const float* x        = (const float*)d_in[0];
    const int*   ei       = (const int*)d_in[1];
    const int*   batch    = (const int*)d_in[2];
    const int*   target   = (const int*)d_in[3];
    const float* embs     = (const float*)d_in[4];
    const float* W1       = (const float*)d_in[5];
    const float* b1       = (const float*)d_in[6];
    const float* W2       = (const float*)d_in[7];
    const float* b2       = (const float*)d_in[8];
    const float* W3       = (const float*)d_in[9];
    const float* b3       = (const float*)d_in[10];
    const float* fc_g1_w  = (const float*)d_in[11];
    const float* fc_g1_b  = (const float*)d_in[12];
    const float* fc_g2_w  = (const float*)d_in[13];
    const float* fc_g2_b  = (const float*)d_in[14];
    const float* emb_xt   = (const float*)d_in[15];
    const float* conv_w   = (const float*)d_in[16];
    const float* conv_b   = (const float*)d_in[17];
    const float* fc1xt_w  = (const float*)d_in[18];
    const float* fc1xt_b  = (const float*)d_in[19];
    const float* fg_lin_w = (const float*)d_in[20];
    const float* fg_lin_b = (const float*)d_in[21];
    const float* Wq       = (const float*)d_in[22];
    const float* Wk       = (const float*)d_in[23];
    const float* Wv       = (const float*)d_in[24];
    const float* ln_g     = (const float*)d_in[25];
    const float* ln_b     = (const float*)d_in[26];
    const float* fg_out_w = (const float*)d_in[27];
    const float* fg_out_b = (const float*)d_in[28];
    const float* fc1_w    = (const float*)d_in[29];
    const float* fc1_b    = (const float*)d_in[30];
    const float* fc2_w    = (const float*)d_in[31];
    const float* fc2_b    = (const float*)d_in[32];
    const float* out_w    = (const float*)d_in[33];
    const float* out_b    = (const float*)d_in[34];

    const int* src = ei;
    const int* dst = ei + NEDGES;
    typedef __hip_bfloat16 bf;

    // ---- workspace carve (256-B aligned bump allocator) ----
    char* p = (char*)d_ws;
    auto alloc = [&](size_t bytes) { char* r = p; p += (bytes + 255) & ~(size_t)255; return r; };
    bf*   xb      = (bf*)alloc((size_t)NNODES * 96 * 2);
    bf*   T       = (bf*)alloc((size_t)NNODES * 160 * 2);
    bf*   H       = (bf*)alloc((size_t)NNODES * 320 * 2);
    int*  deg     = (int*)alloc(NNODES * 4);                // reused as CSR cursor
    float* dis    = (float*)alloc(NNODES * 4);
    float* selfc  = (float*)alloc(NNODES * 4);
    int*  off     = (int*)alloc((NNODES + 1) * 4);
    int*  bsum    = (int*)alloc(512 * 4);
    int*  csr_src = (int*)alloc(NEDGES * 4);
    float* csr_w  = (float*)alloc(NEDGES * 4);
    bf*   w1t     = (bf*)alloc(78 * 96 * 2);
    bf*   w2t     = (bf*)alloc(156 * 96 * 2);
    bf*   w3t     = (bf*)alloc(312 * 160 * 2);
    bf*   fcg1t   = (bf*)alloc(1024 * 320 * 2);
    bf*   fcg2t   = (bf*)alloc(128 * 1024 * 2);
    bf*   fglint  = (bf*)alloc(300 * 160 * 2);
    bf*   wkt     = (bf*)alloc(300 * 320 * 2);
    bf*   wvt     = (bf*)alloc(300 * 320 * 2);
    bf*   wqt     = (bf*)alloc(300 * 320 * 2);
    bf*   fgoutt  = (bf*)alloc(128 * 320 * 2);
    bf*   fc1t    = (bf*)alloc(1024 * 384 * 2);
    bf*   fc2t    = (bf*)alloc(512 * 1024 * 2);
    bf*   fglwb   = (bf*)alloc(133 * 320 * 2);
    bf*   wk2t    = (bf*)alloc(300 * 160 * 2);
    bf*   wv2t    = (bf*)alloc(300 * 160 * 2);
    bf*   wq2t    = (bf*)alloc(300 * 160 * 2);
    float* bk2    = (float*)alloc(300 * 4);
    float* bv2    = (float*)alloc(300 * 4);
    float* bq2    = (float*)alloc(300 * 4);
    bf*   g       = (bf*)alloc((size_t)NB * 320 * 2);
    bf*   G1b     = (bf*)alloc((size_t)NB * 1024 * 2);
    bf*   embsb   = (bf*)alloc((size_t)NB * 13 * 160 * 2);
    bf*   Fbuf    = (bf*)alloc((size_t)NB * 13 * 320 * 2);
    bf*   Kbuf    = (bf*)alloc((size_t)NB * 13 * 320 * 2);
    bf*   Vbuf    = (bf*)alloc((size_t)NB * 13 * 320 * 2);
    bf*   Qbuf    = (bf*)alloc((size_t)NB * 320 * 2);
    bf*   f2row   = (bf*)alloc((size_t)NB * 320 * 2);
    float* xc     = (float*)alloc((size_t)NB * 384 * 4);
    bf*   xcb     = (bf*)alloc((size_t)NB * 384 * 2);
    float* F2     = (float*)alloc((size_t)NB * 512 * 4);
    bf*   cwt     = (bf*)alloc(256000 * 2);
    bf*   aggwb   = (bf*)alloc((size_t)NB * 6656 * 2);
    float* Wc     = (float*)alloc((size_t)6656 * 128 * 4);
    bf*   Wct     = (bf*)alloc((size_t)128 * 6656 * 2);
    float* xtb    = (float*)alloc(128 * 4);

    // ---- degree / norms / CSR ----
    hipMemsetAsync(deg, 0, NNODES * sizeof(int), stream);
    deg_kernel<<<(NEDGES + 255) / 256, 256, 0, stream>>>(dst, deg, NEDGES);
    scan_p1<<<NBLK1, 256, 0, stream>>>(deg, off, bsum, dis, selfc);
    scan_p2<<<1, 512, 0, stream>>>(bsum);
    scan_p3<<<NBLK1, 256, 0, stream>>>(off, bsum, deg);   // deg becomes cursor
    fill_csr_kernel<<<(NEDGES + 255) / 256, 256, 0, stream>>>(src, dst, dis, deg, csr_src, csr_w, NEDGES);

    // ---- weight transposes (one batched launch) + batched input converts ----
    {
        TBatch tb;
        const float* srcs[12] = {W1, W2, W3, fc_g1_w, fc_g2_w, fg_lin_w, Wk, Wv, Wq, fg_out_w, fc1_w, fc2_w};
        bf* dsts[12]          = {w1t, w2t, w3t, fcg1t, fcg2t, fglint, wkt, wvt, wqt, fgoutt, fc1t, fc2t};
        int Ks[12]    = {78, 78, 156, 312, 1024, 133, 300, 300, 300, 300, 384, 1024};
        int Ns[12]    = {78, 156, 312, 1024, 128, 300, 300, 300, 300, 128, 1024, 512};
        int Kpads[12] = {96, 96, 160, 320, 1024, 160, 320, 320, 320, 320, 384, 1024};
        int bs = 0;
        for (int i = 0; i < 12; ++i) {
            tb.src[i] = srcs[i]; tb.dst[i] = dsts[i];
            tb.K[i] = Ks[i]; tb.N[i] = Ns[i]; tb.Kpad[i] = Kpads[i];
            tb.bstart[i] = bs;
            bs += (int)(((long)Ns[i] * Kpads[i] + 255) / 256);
        }
        tb.bstart[12] = bs;
        transpose_batch_kernel<<<bs, 256, 0, stream>>>(tb);
    }
    {
        CBatch cb;
        cb.src[0] = x;       cb.dst[0] = xb;    cb.M[0] = NNODES;  cb.K[0] = 78;  cb.Kpad[0] = 96;
        cb.src[1] = embs;    cb.dst[1] = embsb; cb.M[1] = NB * 13; cb.K[1] = 133; cb.Kpad[1] = 160;
        cb.src[2] = fg_lin_w;cb.dst[2] = fglwb; cb.M[2] = 133;     cb.K[2] = 300; cb.Kpad[2] = 320;
        int bs = 0;
        for (int i = 0; i < 3; ++i) {
            cb.bstart[i] = bs;
            bs += (int)(((long)cb.M[i] * cb.Kpad[i] + 255) / 256);
        }
        cb.bstart[3] = bs;
        cvt_batch_kernel<<<bs, 256, 0, stream>>>(cb);
    }

    // ---- GCN layers: agg(input) -> XCD-swizzled 128x64 MFMA GEMM ----
    int agrid = (NNODES + 3) / 4;
    gcn_agg2<<<agrid, 256, 0, stream>>>(xb, off, csr_src, csr_w, selfc, T, 24);
    launch_gemm_swz(T, w1t, b1, H, NNODES, 78, 96, 96, 96, 96, stream);

    gcn_agg2<<<agrid, 256, 0, stream>>>(H, off, csr_src, csr_w, selfc, T, 24);
    launch_gemm_swz(T, w2t, b2, H, NNODES, 156, 96, 96, 160, 160, stream);

    gcn_agg2<<<agrid, 256, 0, stream>>>(H, off, csr_src, csr_w, selfc, T, 40);
    launch_gemm_swz(T, w3t, b3, H, NNODES, 312, 160, 160, 320, 320, stream);

    // ---- global max pool + graph MLP ----
    pool_max_bf16<<<NB, 256, 0, stream>>>(H, batch, g);
    launch_gemm_bf16(g, fcg1t, fc_g1_b, G1b, NB, 1024, 320, 320, 1024, 1024, 1, 1, 1, stream);
    launch_gemm_bf16(G1b, fcg2t, fc_g2_b, xc, NB, 128, 1024, 1024, 384, 128, 0, 0, 1, stream);

    // ---- conv branch (folded; split-K MFMA accumulates into xc cols 128..255) ----
    conv_transpose_kernel<<<(256000 + 255) / 256, 256, 0, stream>>>(conv_w, cwt);
    conv_agg_kernel<<<NB, 256, 0, stream>>>(cwt, target, aggwb);
    conv_wc_kernel<<<dim3(32, 208), 128, 0, stream>>>(emb_xt, fc1xt_w, Wc);
    transpose_cvt_kernel<<<((long)128 * 6656 + 255) / 256, 256, 0, stream>>>(Wc, Wct, 6656, 128, 6656);
    convb_fold2_kernel<<<128, 256, 0, stream>>>(fc1xt_w, conv_b, fc1xt_b, xtb);
    xc_convbias_kernel<<<(NB * 128 + 255) / 256, 256, 0, stream>>>(xtb, xc);
    launch_gemm_bf16(aggwb, Wct, nullptr, xc + 128, NB, 128, 6656, 6656, 384, 128, 0, 0, 8, stream);

    // ---- FG branch (batched folded-weight GEMMs) ----
    {
        GB3 p;
        for (int z = 0; z < 3; ++z) {
            p.g[z].Bt = fglwb; p.g[z].bias = nullptr;
            p.g[z].M = 300; p.g[z].N = 133; p.g[z].Kpad = 320;
            p.g[z].lda = 320; p.g[z].ldc = 160; p.g[z].Npad = 160;
        }
        p.g[0].A = wkt; p.g[0].C = wk2t;
        p.g[1].A = wvt; p.g[1].C = wv2t;
        p.g[2].A = wqt; p.g[2].C = wq2t;
        gemm_batch64_kernel<<<dim3(3, 5, 3), 256, 0, stream>>>(p);
    }
    {
        BF3 p;
        p.Wt[0] = wkt; p.out[0] = bk2;
        p.Wt[1] = wvt; p.out[1] = bv2;
        p.Wt[2] = wqt; p.out[2] = bq2;
        bias_fold3_kernel<<<900, 256, 0, stream>>>(fg_lin_b, p);
    }
    {
        GB3 p;
        p.g[0].A = embsb; p.g[0].Bt = fglint; p.g[0].bias = fg_lin_b; p.g[0].C = Fbuf;
        p.g[0].M = NB; p.g[0].N = 300; p.g[0].Kpad = 160; p.g[0].lda = 13 * 160;
        p.g[0].ldc = 13 * 320; p.g[0].Npad = 320;
        p.g[1] = p.g[0];
        p.g[1].Bt = wq2t; p.g[1].bias = bq2; p.g[1].C = Qbuf; p.g[1].ldc = 320;
        p.g[2] = p.g[1];
        gemm_batch64_kernel<<<dim3(5, 16, 2), 256, 0, stream>>>(p);
    }
    {
        GB3 p;
        p.g[0].A = embsb; p.g[0].Bt = wk2t; p.g[0].bias = bk2; p.g[0].C = Kbuf;
        p.g[0].M = NB * 13; p.g[0].N = 300; p.g[0].Kpad = 160; p.g[0].lda = 160;
        p.g[0].ldc = 320; p.g[0].Npad = 320;
        p.g[1] = p.g[0];
        p.g[1].Bt = wv2t; p.g[1].bias = bv2; p.g[1].C = Vbuf;
        p.g[2] = p.g[1];
        gemm_mtb_kernel<<<dim3(5, (NB * 13 + 127) / 128, 2), 256, 0, stream>>>(p);
    }
    attn_ln_kernel<<<NB, 256, 0, stream>>>(Fbuf, Kbuf, Vbuf, Qbuf, ln_g, ln_b, f2row);
    launch_gemm_bf16(f2row, fgoutt, fg_out_b, xc + 256, NB, 128, 320, 320, 384, 128, 0, 0, 1, stream);

    // ---- head ----
    cvt_pad_kernel<<<((long)NB * 384 + 255) / 256, 256, 0, stream>>>(xc, xcb, NB, 384, 384);
    launch_gemm_bf16(xcb, fc1t, fc1_b, G1b, NB, 1024, 384, 384, 1024, 1024, 1, 1, 1, stream);
    launch_gemm_bf16(G1b, fc2t, fc2_b, F2, NB, 512, 1024, 1024, 512, 512, 1, 0, 1, stream);
    final_out_kernel<<<NB, 256, 0, stream>>>(F2, out_w, out_b, (float*)d_out);
}

// Round 18
// 670.103 us; speedup vs baseline: 1.1674x; 1.0349x over previous
//
#include <hip/hip_runtime.h>
#include <hip/hip_bf16.h>
#include <math.h>

// ---------------------------------------------------------------------------
// Problem constants
// ---------------------------------------------------------------------------
#define NNODES 100000
#define NEDGES 400000
#define NB     1024
#define SEQ    1000
#define HID    300
#define NBLK1  ((NNODES + 255) / 256)   // 391

typedef __attribute__((ext_vector_type(8))) short short8;   // 8 bf16 (4 VGPRs)
typedef __attribute__((ext_vector_type(4))) float f32x4;    // MFMA acc

__device__ __forceinline__ float bf_lo(unsigned int v) { return __uint_as_float(v << 16); }
__device__ __forceinline__ float bf_hi(unsigned int v) { return __uint_as_float(v & 0xffff0000u); }
__device__ __forceinline__ unsigned int bf_pack(float lo, float hi) {
    __hip_bfloat16 a = __float2bfloat16(lo), b = __float2bfloat16(hi);
    unsigned short ua = *(unsigned short*)&a, ub = *(unsigned short*)&b;
    return (unsigned int)ua | ((unsigned int)ub << 16);
}

// ---------------------------------------------------------------------------
// fp32 [M][K] -> bf16 [M][Kpad] (zero-padded)
// ---------------------------------------------------------------------------
__global__ void cvt_pad_kernel(const float* __restrict__ in, __hip_bfloat16* __restrict__ out,
                               int M, int K, int Kpad)
{
    long idx = (long)blockIdx.x * 256 + threadIdx.x;
    if (idx >= (long)M * Kpad) return;
    int m = idx / Kpad, k = idx % Kpad;
    out[idx] = __float2bfloat16(k < K ? in[(long)m * K + k] : 0.f);
}

// batched cvt_pad: 3 descriptors, one launch
struct CBatch {
    const float* src[3];
    __hip_bfloat16* dst[3];
    int M[3]; int K[3]; int Kpad[3];
    int bstart[4];
};

__global__ __launch_bounds__(256) void cvt_batch_kernel(CBatch cb)
{
    int blk = blockIdx.x;
    int d = 0;
    while (d < 2 && blk >= cb.bstart[d + 1]) ++d;
    long idx = (long)(blk - cb.bstart[d]) * 256 + threadIdx.x;
    long tot = (long)cb.M[d] * cb.Kpad[d];
    if (idx >= tot) return;
    int Kpad = cb.Kpad[d];
    int m = idx / Kpad, k = idx % Kpad;
    cb.dst[d][idx] = __float2bfloat16(k < cb.K[d] ? cb.src[d][(long)m * cb.K[d] + k] : 0.f);
}

// fp32 [K][N] row-major -> bf16 Bt [N][Kpad] (zero-padded)
__global__ void transpose_cvt_kernel(const float* __restrict__ in, __hip_bfloat16* __restrict__ out,
                                     int K, int N, int Kpad)
{
    long idx = (long)blockIdx.x * 256 + threadIdx.x;
    if (idx >= (long)N * Kpad) return;
    int n = idx / Kpad, k = idx % Kpad;
    out[idx] = __float2bfloat16(k < K ? in[(long)k * N + n] : 0.f);
}

// Batched weight transpose: 12 descriptors in one launch
struct TBatch {
    const float* src[12];
    __hip_bfloat16* dst[12];
    int K[12]; int N[12]; int Kpad[12];
    int bstart[13];
};

__global__ __launch_bounds__(256) void transpose_batch_kernel(TBatch tb)
{
    int blk = blockIdx.x;
    int d = 0;
    while (d < 11 && blk >= tb.bstart[d + 1]) ++d;
    long idx = (long)(blk - tb.bstart[d]) * 256 + threadIdx.x;
    long tot = (long)tb.N[d] * tb.Kpad[d];
    if (idx >= tot) return;
    int Kpad = tb.Kpad[d];
    int n = idx / Kpad, k = idx % Kpad;
    tb.dst[d][idx] = __float2bfloat16(k < tb.K[d] ? tb.src[d][(long)k * tb.N[d] + n] : 0.f);
}

// batched bias fold from TRANSPOSED bf16 weights: out_d[n] = sum_k b[k] * Wt_d[n][k]
struct BF3 { const __hip_bfloat16* Wt[3]; float* out[3]; };

__global__ __launch_bounds__(256) void bias_fold3_kernel(const float* __restrict__ b, BF3 p)
{
    int d = blockIdx.x / 300;
    int n = blockIdx.x % 300;
    __shared__ float red[256];
    int tid = threadIdx.x;
    const __hip_bfloat16* Wt = p.Wt[d];
    float s = 0.f;
    for (int k = tid; k < 300; k += 256)
        s += b[k] * __bfloat162float(Wt[(size_t)n * 320 + k]);
    red[tid] = s;
    __syncthreads();
    #pragma unroll
    for (int st = 128; st > 0; st >>= 1) {
        if (tid < st) red[tid] += red[tid + st];
        __syncthreads();
    }
    if (tid == 0) p.out[d][n] = red[0];
}

// ---------------------------------------------------------------------------
// BF16 MFMA GEMM (TN), 64x64 tile: C = act(A @ Bt^T + bias)
// ---------------------------------------------------------------------------
__global__ __launch_bounds__(256) void gemm_bf16_kernel(
    const __hip_bfloat16* __restrict__ A, const __hip_bfloat16* __restrict__ Bt,
    const float* __restrict__ bias, void* __restrict__ C,
    int M, int N, int Kpad, int lda, int ldc, int Npad_out,
    int relu, int outbf, int chunk)
{
    __shared__ __align__(16) __hip_bfloat16 As[64][40];
    __shared__ __align__(16) __hip_bfloat16 Bs[64][40];
    int tid = threadIdx.x;
    int wave = tid >> 6, lane = tid & 63;
    int wm = wave >> 1, wn = wave & 1;
    int quad = lane >> 4, l16 = lane & 15;
    int row0 = blockIdx.y * 64, col0 = blockIdx.x * 64;

    int kbeg = 0, kend = Kpad;
    if (chunk > 0) { kbeg = blockIdx.z * chunk; kend = kbeg + chunk; if (kend > Kpad) kend = Kpad; }

    f32x4 acc[2][2];
    #pragma unroll
    for (int i = 0; i < 2; ++i)
        #pragma unroll
        for (int j = 0; j < 2; ++j) acc[i][j] = (f32x4){0.f, 0.f, 0.f, 0.f};

    int r = tid >> 2, cch = (tid & 3) * 8;

    for (int k0 = kbeg; k0 < kend; k0 += 32) {
        uint4 av = {0u, 0u, 0u, 0u};
        if (row0 + r < M) av = *(const uint4*)(A + (size_t)(row0 + r) * lda + k0 + cch);
        *(uint4*)(&As[r][cch]) = av;
        uint4 bv = {0u, 0u, 0u, 0u};
        if (col0 + r < N) bv = *(const uint4*)(Bt + (size_t)(col0 + r) * Kpad + k0 + cch);
        *(uint4*)(&Bs[r][cch]) = bv;
        __syncthreads();

        short8 a0 = *(const short8*)(&As[wm * 32 + l16][quad * 8]);
        short8 a1 = *(const short8*)(&As[wm * 32 + 16 + l16][quad * 8]);
        short8 b0 = *(const short8*)(&Bs[wn * 32 + l16][quad * 8]);
        short8 b1 = *(const short8*)(&Bs[wn * 32 + 16 + l16][quad * 8]);
        acc[0][0] = __builtin_amdgcn_mfma_f32_16x16x32_bf16(a0, b0, acc[0][0], 0, 0, 0);
        acc[0][1] = __builtin_amdgcn_mfma_f32_16x16x32_bf16(a0, b1, acc[0][1], 0, 0, 0);
        acc[1][0] = __builtin_amdgcn_mfma_f32_16x16x32_bf16(a1, b0, acc[1][0], 0, 0, 0);
        acc[1][1] = __builtin_amdgcn_mfma_f32_16x16x32_bf16(a1, b1, acc[1][1], 0, 0, 0);
        __syncthreads();
    }

    #pragma unroll
    for (int ti = 0; ti < 2; ++ti) {
        int rbase = row0 + wm * 32 + ti * 16 + quad * 4;
        #pragma unroll
        for (int tj = 0; tj < 2; ++tj) {
            int cc = col0 + wn * 32 + tj * 16 + l16;
            if (cc >= Npad_out) continue;
            #pragma unroll
            for (int reg = 0; reg < 4; ++reg) {
                int rr = rbase + reg;
                if (rr >= M) continue;
                float v = acc[ti][tj][reg];
                if (chunk > 0) {
                    if (cc < N) atomicAdd((float*)C + (size_t)rr * ldc + cc, v);
                } else {
                    float ov = 0.f;
                    if (cc < N) {
                        if (bias) v += bias[cc];
                        if (relu) v = fmaxf(v, 0.f);
                        ov = v;
                    }
                    if (outbf) ((__hip_bfloat16*)C)[(size_t)rr * ldc + cc] = __float2bfloat16(ov);
                    else       ((float*)C)[(size_t)rr * ldc + cc] = ov;
                }
            }
        }
    }
}

static void launch_gemm_bf16(const __hip_bfloat16* A, const __hip_bfloat16* Bt, const float* bias,
                             void* C, int M, int N, int Kpad, int lda, int ldc, int Npad_out,
                             int relu, int outbf, int splitz, hipStream_t stream)
{
    int cover = N > Npad_out ? N : Npad_out;
    int chunk = (splitz > 1) ? (Kpad / splitz) : 0;
    dim3 grid((cover + 63) / 64, (M + 63) / 64, splitz > 1 ? splitz : 1);
    gemm_bf16_kernel<<<grid, 256, 0, stream>>>(A, Bt, bias, C, M, N, Kpad, lda, ldc, Npad_out,
                                               relu, outbf, chunk);
}

// ---------------------------------------------------------------------------
// Batched 64x64 GEMM (z selects descriptor). bf16 out, no relu.
// ---------------------------------------------------------------------------
struct GB { const __hip_bfloat16* A; const __hip_bfloat16* Bt; const float* bias;
            __hip_bfloat16* C; int M, N, Kpad, lda, ldc, Npad; };
struct GB3 { GB g[3]; };

__global__ __launch_bounds__(256) void gemm_batch64_kernel(GB3 p)
{
    GB gb = p.g[blockIdx.z];
    __shared__ __align__(16) __hip_bfloat16 As[64][40];
    __shared__ __align__(16) __hip_bfloat16 Bs[64][40];
    int tid = threadIdx.x;
    int wave = tid >> 6, lane = tid & 63;
    int wm = wave >> 1, wn = wave & 1;
    int quad = lane >> 4, l16 = lane & 15;
    int row0 = blockIdx.y * 64, col0 = blockIdx.x * 64;

    f32x4 acc[2][2];
    #pragma unroll
    for (int i = 0; i < 2; ++i)
        #pragma unroll
        for (int j = 0; j < 2; ++j) acc[i][j] = (f32x4){0.f, 0.f, 0.f, 0.f};

    int r = tid >> 2, cch = (tid & 3) * 8;

    for (int k0 = 0; k0 < gb.Kpad; k0 += 32) {
        uint4 av = {0u, 0u, 0u, 0u};
        if (row0 + r < gb.M) av = *(const uint4*)(gb.A + (size_t)(row0 + r) * gb.lda + k0 + cch);
        *(uint4*)(&As[r][cch]) = av;
        uint4 bv = {0u, 0u, 0u, 0u};
        if (col0 + r < gb.N) bv = *(const uint4*)(gb.Bt + (size_t)(col0 + r) * gb.Kpad + k0 + cch);
        *(uint4*)(&Bs[r][cch]) = bv;
        __syncthreads();

        short8 a0 = *(const short8*)(&As[wm * 32 + l16][quad * 8]);
        short8 a1 = *(const short8*)(&As[wm * 32 + 16 + l16][quad * 8]);
        short8 b0 = *(const short8*)(&Bs[wn * 32 + l16][quad * 8]);
        short8 b1 = *(const short8*)(&Bs[wn * 32 + 16 + l16][quad * 8]);
        acc[0][0] = __builtin_amdgcn_mfma_f32_16x16x32_bf16(a0, b0, acc[0][0], 0, 0, 0);
        acc[0][1] = __builtin_amdgcn_mfma_f32_16x16x32_bf16(a0, b1, acc[0][1], 0, 0, 0);
        acc[1][0] = __builtin_amdgcn_mfma_f32_16x16x32_bf16(a1, b0, acc[1][0], 0, 0, 0);
        acc[1][1] = __builtin_amdgcn_mfma_f32_16x16x32_bf16(a1, b1, acc[1][1], 0, 0, 0);
        __syncthreads();
    }

    #pragma unroll
    for (int ti = 0; ti < 2; ++ti) {
        int rbase = row0 + wm * 32 + ti * 16 + quad * 4;
        #pragma unroll
        for (int tj = 0; tj < 2; ++tj) {
            int cc = col0 + wn * 32 + tj * 16 + l16;
            if (cc >= gb.Npad) continue;
            #pragma unroll
            for (int reg = 0; reg < 4; ++reg) {
                int rr = rbase + reg;
                if (rr >= gb.M) continue;
                float ov = 0.f;
                if (cc < gb.N) {
                    float v = acc[ti][tj][reg];
                    if (gb.bias) v += gb.bias[cc];
                    ov = v;
                }
                gb.C[(size_t)rr * gb.ldc + cc] = __float2bfloat16(ov);
            }
        }
    }
}

// ---------------------------------------------------------------------------
// Batched 128x64 GEMM (z selects descriptor). bf16 out, no relu. (K/V)
// ---------------------------------------------------------------------------
__global__ __launch_bounds__(256) void gemm_mtb_kernel(GB3 p)
{
    GB gb = p.g[blockIdx.z];
    __shared__ __align__(16) __hip_bfloat16 As[128][40];
    __shared__ __align__(16) __hip_bfloat16 Bs[64][40];
    int tid = threadIdx.x;
    int wave = tid >> 6, lane = tid & 63;
    int wm = wave >> 1, wn = wave & 1;
    int quad = lane >> 4, l16 = lane & 15;
    int row0 = blockIdx.y * 128, col0 = blockIdx.x * 64;

    f32x4 acc[4][2];
    #pragma unroll
    for (int i = 0; i < 4; ++i)
        #pragma unroll
        for (int j = 0; j < 2; ++j) acc[i][j] = (f32x4){0.f, 0.f, 0.f, 0.f};

    int r = tid >> 2, cch = (tid & 3) * 8;

    for (int k0 = 0; k0 < gb.Kpad; k0 += 32) {
        uint4 av0 = {0u, 0u, 0u, 0u}, av1 = {0u, 0u, 0u, 0u}, bv = {0u, 0u, 0u, 0u};
        if (row0 + r < gb.M)      av0 = *(const uint4*)(gb.A + (size_t)(row0 + r) * gb.lda + k0 + cch);
        if (row0 + r + 64 < gb.M) av1 = *(const uint4*)(gb.A + (size_t)(row0 + r + 64) * gb.lda + k0 + cch);
        if (col0 + r < gb.N)      bv  = *(const uint4*)(gb.Bt + (size_t)(col0 + r) * gb.Kpad + k0 + cch);
        *(uint4*)(&As[r][cch]) = av0;
        *(uint4*)(&As[r + 64][cch]) = av1;
        *(uint4*)(&Bs[r][cch]) = bv;
        __syncthreads();

        short8 af[4], bfr[2];
        #pragma unroll
        for (int i = 0; i < 4; ++i)
            af[i] = *(const short8*)(&As[wm * 64 + i * 16 + l16][quad * 8]);
        #pragma unroll
        for (int j = 0; j < 2; ++j)
            bfr[j] = *(const short8*)(&Bs[wn * 32 + j * 16 + l16][quad * 8]);
        #pragma unroll
        for (int i = 0; i < 4; ++i)
            #pragma unroll
            for (int j = 0; j < 2; ++j)
                acc[i][j] = __builtin_amdgcn_mfma_f32_16x16x32_bf16(af[i], bfr[j], acc[i][j], 0, 0, 0);
        __syncthreads();
    }

    #pragma unroll
    for (int ti = 0; ti < 4; ++ti) {
        int rbase = row0 + wm * 64 + ti * 16 + quad * 4;
        #pragma unroll
        for (int tj = 0; tj < 2; ++tj) {
            int cc = col0 + wn * 32 + tj * 16 + l16;
            if (cc >= gb.Npad) continue;
            #pragma unroll
            for (int reg = 0; reg < 4; ++reg) {
                int rr = rbase + reg;
                if (rr >= gb.M) continue;
                float ov = 0.f;
                if (cc < gb.N) {
                    float v = acc[ti][tj][reg];
                    if (gb.bias) v += gb.bias[cc];
                    ov = v;
                }
                gb.C[(size_t)rr * gb.ldc + cc] = __float2bfloat16(ov);
            }
        }
    }
}

// ---------------------------------------------------------------------------
// Node-layer GEMM: 128x64 staged tile + XCD-aware mod-8 swizzle
// ---------------------------------------------------------------------------
__global__ __launch_bounds__(256) void gemm_swz_kernel(
    const __hip_bfloat16* __restrict__ A, const __hip_bfloat16* __restrict__ Bt,
    const float* __restrict__ bias, __hip_bfloat16* __restrict__ C,
    int M, int N, int Kpad, int lda, int ldc, int Npad_out, int nct, int nstrips)
{
    int id = blockIdx.x;
    int rr8 = id & 7, q = id >> 3;
    int c = q % nct, sgrp = q / nct;
    int s = sgrp * 8 + rr8;
    if (s >= nstrips) return;
    int row0 = s * 128, col0 = c * 64;

    __shared__ __align__(16) __hip_bfloat16 As[128][40];
    __shared__ __align__(16) __hip_bfloat16 Bs[64][40];
    int tid = threadIdx.x;
    int wave = tid >> 6, lane = tid & 63;
    int wm = wave >> 1, wn = wave & 1;
    int quad = lane >> 4, l16 = lane & 15;

    f32x4 acc[4][2];
    #pragma unroll
    for (int i = 0; i < 4; ++i)
        #pragma unroll
        for (int j = 0; j < 2; ++j) acc[i][j] = (f32x4){0.f, 0.f, 0.f, 0.f};

    int r = tid >> 2, cch = (tid & 3) * 8;

    for (int k0 = 0; k0 < Kpad; k0 += 32) {
        uint4 av0 = {0u, 0u, 0u, 0u}, av1 = {0u, 0u, 0u, 0u}, bv = {0u, 0u, 0u, 0u};
        if (row0 + r < M)      av0 = *(const uint4*)(A + (size_t)(row0 + r) * lda + k0 + cch);
        if (row0 + r + 64 < M) av1 = *(const uint4*)(A + (size_t)(row0 + r + 64) * lda + k0 + cch);
        if (col0 + r < N)      bv  = *(const uint4*)(Bt + (size_t)(col0 + r) * Kpad + k0 + cch);
        *(uint4*)(&As[r][cch]) = av0;
        *(uint4*)(&As[r + 64][cch]) = av1;
        *(uint4*)(&Bs[r][cch]) = bv;
        __syncthreads();

        short8 af[4], bfr[2];
        #pragma unroll
        for (int i = 0; i < 4; ++i)
            af[i] = *(const short8*)(&As[wm * 64 + i * 16 + l16][quad * 8]);
        #pragma unroll
        for (int j = 0; j < 2; ++j)
            bfr[j] = *(const short8*)(&Bs[wn * 32 + j * 16 + l16][quad * 8]);
        #pragma unroll
        for (int i = 0; i < 4; ++i)
            #pragma unroll
            for (int j = 0; j < 2; ++j)
                acc[i][j] = __builtin_amdgcn_mfma_f32_16x16x32_bf16(af[i], bfr[j], acc[i][j], 0, 0, 0);
        __syncthreads();
    }

    #pragma unroll
    for (int ti = 0; ti < 4; ++ti) {
        int rbase = row0 + wm * 64 + ti * 16 + quad * 4;
        #pragma unroll
        for (int tj = 0; tj < 2; ++tj) {
            int cc = col0 + wn * 32 + tj * 16 + l16;
            if (cc >= Npad_out) continue;
            #pragma unroll
            for (int reg = 0; reg < 4; ++reg) {
                int rrow = rbase + reg;
                if (rrow >= M) continue;
                float ov = 0.f;
                if (cc < N) ov = fmaxf(acc[ti][tj][reg] + bias[cc], 0.f);
                C[(size_t)rrow * ldc + cc] = __float2bfloat16(ov);
            }
        }
    }
}

static void launch_gemm_swz(const __hip_bfloat16* A, const __hip_bfloat16* Bt, const float* bias,
                            __hip_bfloat16* C, int M, int N, int Kpad, int lda, int ldc,
                            int Npad_out, hipStream_t stream)
{
    int nct = (Npad_out + 63) / 64;
    int nstrips = (M + 127) / 128;
    int G = 8 * nct * ((nstrips + 7) / 8);
    gemm_swz_kernel<<<G, 256, 0, stream>>>(A, Bt, bias, C, M, N, Kpad, lda, ldc, Npad_out,
                                           nct, nstrips);
}

// ---------------------------------------------------------------------------
// GCN: degree, norms(+scan p1 fused), multi-block scan, CSR build
// ---------------------------------------------------------------------------
__global__ void deg_kernel(const int* __restrict__ dst, int* __restrict__ deg, int E)
{
    int e = blockIdx.x * 256 + threadIdx.x;
    if (e < E) atomicAdd(&deg[dst[e]], 1);
}

__global__ __launch_bounds__(256) void scan_p1(const int* __restrict__ deg,
                                               int* __restrict__ off, int* __restrict__ bsum,
                                               float* __restrict__ dis, float* __restrict__ selfc)
{
    __shared__ int s[256];
    int tid = threadIdx.x;
    int i = blockIdx.x * 256 + tid;
    int v = (i < NNODES) ? deg[i] : 0;
    if (i < NNODES) {
        float d = (float)v + 1.0f;
        float r = 1.0f / sqrtf(d);
        dis[i] = r;
        selfc[i] = r * r;
    }
    s[tid] = v;
    __syncthreads();
    #pragma unroll
    for (int d = 1; d < 256; d <<= 1) {
        int t = (tid >= d) ? s[tid - d] : 0;
        __syncthreads();
        s[tid] += t;
        __syncthreads();
    }
    if (i < NNODES) off[i] = s[tid] - v;
    if (tid == 255) bsum[blockIdx.x] = s[255];
}

__global__ __launch_bounds__(512) void scan_p2(int* __restrict__ bsum)
{
    __shared__ int s[512];
    int tid = threadIdx.x;
    int v = (tid < NBLK1) ? bsum[tid] : 0;
    s[tid] = v;
    __syncthreads();
    #pragma unroll
    for (int d = 1; d < 512; d <<= 1) {
        int t = (tid >= d) ? s[tid - d] : 0;
        __syncthreads();
        s[tid] += t;
        __syncthreads();
    }
    if (tid < NBLK1) bsum[tid] = s[tid] - v;
}

__global__ __launch_bounds__(256) void scan_p3(int* __restrict__ off, const int* __restrict__ bsum,
                                               int* __restrict__ cur)
{
    int i = blockIdx.x * 256 + threadIdx.x;
    if (i < NNODES) {
        int v = off[i] + bsum[blockIdx.x];
        off[i] = v;
        cur[i] = v;
    }
    if (i == NNODES) off[NNODES] = NEDGES;
}

__global__ void fill_csr_kernel(const int* __restrict__ src, const int* __restrict__ dst,
                                const float* __restrict__ dis, int* __restrict__ cur,
                                int* __restrict__ csr_src, float* __restrict__ csr_w, int E)
{
    int e = blockIdx.x * 256 + threadIdx.x;
    if (e >= E) return;
    int s = src[e], d = dst[e];
    int p = atomicAdd(&cur[d], 1);
    csr_src[p] = s;
    csr_w[p] = dis[s] * dis[d];
}

// ---------------------------------------------------------------------------
// Pre-GEMM GCN aggregation: out[i] = selfc[i]*T[i] + sum_e w_e * T[src_e]
// uint2 (4 bf16) per lane: full row in ONE load per edge; 4-edge unroll.
// ---------------------------------------------------------------------------
__global__ __launch_bounds__(256) void gcn_agg2(
    const __hip_bfloat16* __restrict__ Tin, const int* __restrict__ off,
    const int* __restrict__ csr_src, const float* __restrict__ csr_w,
    const float* __restrict__ selfc, __hip_bfloat16* __restrict__ out,
    int halfq)
{
    int wave = threadIdx.x >> 6, lane = threadIdx.x & 63;
    int node = blockIdx.x * 4 + wave;
    if (node >= NNODES) return;
    const uint2* Tp = (const uint2*)Tin;
    uint2* Op = (uint2*)out;
    size_t rb = (size_t)node * halfq;
    bool m = lane < halfq;
    float sc = selfc[node];
    float a0 = 0.f, a1 = 0.f, a2 = 0.f, a3 = 0.f;
    float b0 = 0.f, b1 = 0.f, b2 = 0.f, b3 = 0.f;
    float c0 = 0.f, c1 = 0.f, c2 = 0.f, c3 = 0.f;
    float d0 = 0.f, d1 = 0.f, d2 = 0.f, d3 = 0.f;
    if (m) {
        uint2 v = Tp[rb + lane];
        a0 = bf_lo(v.x) * sc; a1 = bf_hi(v.x) * sc;
        a2 = bf_lo(v.y) * sc; a3 = bf_hi(v.y) * sc;
    }
    int s0 = off[node], s1 = off[node + 1];
    int e = s0;
    for (; e + 4 <= s1; e += 4) {
        int i0 = csr_src[e], i1 = csr_src[e + 1], i2 = csr_src[e + 2], i3 = csr_src[e + 3];
        float w0 = csr_w[e], w1 = csr_w[e + 1], w2 = csr_w[e + 2], w3 = csr_w[e + 3];
        if (m) {
            uint2 v0 = Tp[(size_t)i0 * halfq + lane];
            uint2 v1 = Tp[(size_t)i1 * halfq + lane];
            uint2 v2 = Tp[(size_t)i2 * halfq + lane];
            uint2 v3 = Tp[(size_t)i3 * halfq + lane];
            a0 += bf_lo(v0.x) * w0; a1 += bf_hi(v0.x) * w0;
            a2 += bf_lo(v0.y) * w0; a3 += bf_hi(v0.y) * w0;
            b0 += bf_lo(v1.x) * w1; b1 += bf_hi(v1.x) * w1;
            b2 += bf_lo(v1.y) * w1; b3 += bf_hi(v1.y) * w1;
            c0 += bf_lo(v2.x) * w2; c1 += bf_hi(v2.x) * w2;
            c2 += bf_lo(v2.y) * w2; c3 += bf_hi(v2.y) * w2;
            d0 += bf_lo(v3.x) * w3; d1 += bf_hi(v3.x) * w3;
            d2 += bf_lo(v3.y) * w3; d3 += bf_hi(v3.y) * w3;
        }
    }
    for (; e + 2 <= s1; e += 2) {
        int i0 = csr_src[e], i1 = csr_src[e + 1];
        float w0 = csr_w[e], w1 = csr_w[e + 1];
        if (m) {
            uint2 v0 = Tp[(size_t)i0 * halfq + lane];
            uint2 v1 = Tp[(size_t)i1 * halfq + lane];
            a0 += bf_lo(v0.x) * w0; a1 += bf_hi(v0.x) * w0;
            a2 += bf_lo(v0.y) * w0; a3 += bf_hi(v0.y) * w0;
            b0 += bf_lo(v1.x) * w1; b1 += bf_hi(v1.x) * w1;
            b2 += bf_lo(v1.y) * w1; b3 += bf_hi(v1.y) * w1;
        }
    }
    if (e < s1) {
        int i0 = csr_src[e];
        float w0 = csr_w[e];
        if (m) {
            uint2 v0 = Tp[(size_t)i0 * halfq + lane];
            a0 += bf_lo(v0.x) * w0; a1 += bf_hi(v0.x) * w0;
            a2 += bf_lo(v0.y) * w0; a3 += bf_hi(v0.y) * w0;
        }
    }
    if (m) {
        uint2 o;
        o.x = bf_pack((a0 + b0) + (c0 + d0), (a1 + b1) + (c1 + d1));
        o.y = bf_pack((a2 + b2) + (c2 + d2), (a3 + b3) + (c3 + d3));
        Op[rb + lane] = o;
    }
}

// ---------------------------------------------------------------------------
// segment max pool (bf16 [NNODES][320] -> bf16 [NB][320]); batch sorted.
// 4-row unroll with independent accumulators for memory-level parallelism.
// ---------------------------------------------------------------------------
__global__ __launch_bounds__(256) void pool_max_bf16(
    const __hip_bfloat16* __restrict__ H, const int* __restrict__ batch,
    __hip_bfloat16* __restrict__ g)
{
    int b = blockIdx.x;
    int lo = 0, hi = NNODES;
    while (lo < hi) { int mid = (lo + hi) >> 1; if (batch[mid] < b) lo = mid + 1; else hi = mid; }
    int s = lo;
    hi = NNODES;
    while (lo < hi) { int mid = (lo + hi) >> 1; if (batch[mid] < b + 1) lo = mid + 1; else hi = mid; }
    int e = lo;
    int tid = threadIdx.x;
    if (tid >= 160) return;
    const unsigned int* Hp = (const unsigned int*)H;
    float x0 = 0.f, y0 = 0.f, x1 = 0.f, y1 = 0.f;
    float x2 = 0.f, y2 = 0.f, x3 = 0.f, y3 = 0.f;
    int i = s;
    for (; i + 4 <= e; i += 4) {
        unsigned int v0 = Hp[(size_t)i * 160 + tid];
        unsigned int v1 = Hp[(size_t)(i + 1) * 160 + tid];
        unsigned int v2 = Hp[(size_t)(i + 2) * 160 + tid];
        unsigned int v3 = Hp[(size_t)(i + 3) * 160 + tid];
        x0 = fmaxf(x0, bf_lo(v0)); y0 = fmaxf(y0, bf_hi(v0));
        x1 = fmaxf(x1, bf_lo(v1)); y1 = fmaxf(y1, bf_hi(v1));
        x2 = fmaxf(x2, bf_lo(v2)); y2 = fmaxf(y2, bf_hi(v2));
        x3 = fmaxf(x3, bf_lo(v3)); y3 = fmaxf(y3, bf_hi(v3));
    }
    for (; i < e; ++i) {
        unsigned int v = Hp[(size_t)i * 160 + tid];
        x0 = fmaxf(x0, bf_lo(v)); y0 = fmaxf(y0, bf_hi(v));
    }
    float mx = fmaxf(fmaxf(x0, x1), fmaxf(x2, x3));
    float my = fmaxf(fmaxf(y0, y1), fmaxf(y2, y3));
    ((unsigned int*)g)[(size_t)b * 160 + tid] = bf_pack(mx, my);
}

// ---------------------------------------------------------------------------
// Conv branch: transpose to bf16, letter-partitioned bucketed aggregation
// ---------------------------------------------------------------------------
__global__ void conv_transpose_kernel(const float* __restrict__ w, __hip_bfloat16* __restrict__ wt)
{
    int idx = blockIdx.x * 256 + threadIdx.x;
    if (idx >= 256000) return;
    int o = idx / 8000;
    int rem = idx - o * 8000;
    int i = rem >> 3, k = rem & 7;
    wt[i * 256 + o * 8 + k] = __float2bfloat16(w[idx]);
}

__global__ __launch_bounds__(256) void conv_agg_kernel(
    const __hip_bfloat16* __restrict__ cwt, const int* __restrict__ target,
    __hip_bfloat16* __restrict__ aggw)
{
    __shared__ int tb_s[SEQ];
    __shared__ int cnt[26];
    __shared__ int boff[27];
    __shared__ int curs[26];
    __shared__ int bucket[SEQ];
    __shared__ int wsplit[5];
    int b = blockIdx.x, tid = threadIdx.x;
    int wave = tid >> 6, lane = tid & 63;
    const int* tb = target + b * SEQ;
    if (tid < 26) cnt[tid] = 0;
    __syncthreads();
    for (int i = tid; i < SEQ; i += 256) {
        int a = tb[i];
        tb_s[i] = a;
        atomicAdd(&cnt[a], 1);
    }
    __syncthreads();
    if (tid == 0) {
        int run = 0;
        for (int a = 0; a < 26; ++a) { boff[a] = run; curs[a] = run; run += cnt[a]; }
        boff[26] = run;
        wsplit[0] = 0; wsplit[4] = 26;
        for (int w = 1; w < 4; ++w) {
            int a = 0;
            while (a < 26 && boff[a] < (w * SEQ) / 4) ++a;
            wsplit[w] = a;
        }
    }
    __syncthreads();
    for (int i = tid; i < SEQ; i += 256) {
        int a = tb_s[i];
        int p = atomicAdd(&curs[a], 1);
        bucket[p] = i;
    }
    __syncthreads();

    const uint2* cw = (const uint2*)cwt;
    uint2* aw = (uint2*)aggw;
    int aBeg = wsplit[wave], aEnd = wsplit[wave + 1];
    for (int a = aBeg; a < aEnd; ++a) {
        int s = boff[a], e = boff[a + 1];
        float x0 = 0.f, x1 = 0.f, x2 = 0.f, x3 = 0.f;
        float y0 = 0.f, y1 = 0.f, y2 = 0.f, y3 = 0.f;
        float z0 = 0.f, z1 = 0.f, z2 = 0.f, z3 = 0.f;
        float u0 = 0.f, u1 = 0.f, u2 = 0.f, u3 = 0.f;
        int j = s;
        for (; j + 4 <= e; j += 4) {
            uint2 v0 = cw[(size_t)bucket[j]     * 64 + lane];
            uint2 v1 = cw[(size_t)bucket[j + 1] * 64 + lane];
            uint2 v2 = cw[(size_t)bucket[j + 2] * 64 + lane];
            uint2 v3 = cw[(size_t)bucket[j + 3] * 64 + lane];
            x0 += bf_lo(v0.x); x1 += bf_hi(v0.x); x2 += bf_lo(v0.y); x3 += bf_hi(v0.y);
            y0 += bf_lo(v1.x); y1 += bf_hi(v1.x); y2 += bf_lo(v1.y); y3 += bf_hi(v1.y);
            z0 += bf_lo(v2.x); z1 += bf_hi(v2.x); z2 += bf_lo(v2.y); z3 += bf_hi(v2.y);
            u0 += bf_lo(v3.x); u1 += bf_hi(v3.x); u2 += bf_lo(v3.y); u3 += bf_hi(v3.y);
        }
        for (; j < e; ++j) {
            uint2 v = cw[(size_t)bucket[j] * 64 + lane];
            x0 += bf_lo(v.x); x1 += bf_hi(v.x); x2 += bf_lo(v.y); x3 += bf_hi(v.y);
        }
        uint2 o;
        o.x = bf_pack((x0 + y0) + (z0 + u0), (x1 + y1) + (z1 + u1));
        o.y = bf_pack((x2 + y2) + (z2 + u2), (x3 + y3) + (z3 + u3));
        aw[(size_t)b * 1664 + a * 64 + lane] = o;
    }
}

__global__ __launch_bounds__(128) void conv_wc_kernel(
    const float* __restrict__ emb, const float* __restrict__ w_fc, float* __restrict__ Wc)
{
    int o = blockIdx.x;
    int ak = blockIdx.y;
    int a = ak >> 3, k = ak & 7;
    int j = threadIdx.x;
    const float* wp = w_fc + (long)(o * 121) * 128 + j;
    const float* ep = emb + a * 128 + k;
    float s = 0.f;
    #pragma unroll 11
    for (int t = 0; t < 121; ++t) s += ep[t] * wp[t * 128];
    Wc[(long)(a * 256 + o * 8 + k) * 128 + j] = s;
}

__global__ __launch_bounds__(256) void convb_fold2_kernel(
    const float* __restrict__ w_fc, const float* __restrict__ conv_b,
    const float* __restrict__ b_fc, float* __restrict__ xtb)
{
    int j = blockIdx.x;
    __shared__ float red[256];
    __shared__ float cb[32];
    int tid = threadIdx.x;
    if (tid < 32) cb[tid] = conv_b[tid];
    __syncthreads();
    float s = 0.f;
    for (int p = tid; p < 3872; p += 256)
        s += cb[p / 121] * w_fc[(size_t)p * 128 + j];
    red[tid] = s;
    __syncthreads();
    #pragma unroll
    for (int st = 128; st > 0; st >>= 1) {
        if (tid < st) red[tid] += red[tid + st];
        __syncthreads();
    }
    if (tid == 0) xtb[j] = b_fc[j] + red[0];
}

__global__ void xc_convbias_kernel(const float* __restrict__ xtb, float* __restrict__ xc)
{
    int idx = blockIdx.x * 256 + threadIdx.x;
    if (idx >= NB * 128) return;
    int b = idx >> 7, j = idx & 127;
    xc[(long)b * 384 + 128 + j] = xtb[j];
}

// ---------------------------------------------------------------------------
// FG branch: attention row 0 + LayerNorm (bf16 in, bf16 padded out)
// ---------------------------------------------------------------------------
__global__ __launch_bounds__(256) void attn_ln_kernel(
    const __hip_bfloat16* __restrict__ Fb, const __hip_bfloat16* __restrict__ Kf,
    const __hip_bfloat16* __restrict__ Vf, const __hip_bfloat16* __restrict__ q0,
    const float* __restrict__ ln_g, const float* __restrict__ ln_b,
    __hip_bfloat16* __restrict__ out)
{
    int b = blockIdx.x, tid = threadIdx.x;
    __shared__ float qs[HID];
    __shared__ float sc[13];
    __shared__ float red[256];
    __shared__ float red2[256];
    __shared__ float rowv[HID];
    __shared__ float mean_s, inv_s;

    for (int d = tid; d < HID; d += 256) qs[d] = __bfloat162float(q0[(size_t)b * 320 + d]);
    __syncthreads();
    if (tid < 208) {
        int k = tid >> 4, sub = tid & 15;
        const __hip_bfloat16* kr = Kf + ((size_t)b * 13 + k) * 320;
        float p = 0.f;
        for (int d = sub; d < HID; d += 16) p += qs[d] * __bfloat162float(kr[d]);
        red[tid] = p;
    }
    __syncthreads();
    if (tid < 208 && (tid & 15) == 0) {
        float s = 0.f;
        #pragma unroll
        for (int j = 0; j < 16; ++j) s += red[tid + j];
        sc[tid >> 4] = s * 0.0577350269189626f;  // 1/sqrt(300)
    }
    __syncthreads();
    if (tid == 0) {
        float mx = sc[0];
        for (int k = 1; k < 13; ++k) mx = fmaxf(mx, sc[k]);
        float ssum = 0.f;
        for (int k = 0; k < 13; ++k) { float e = expf(sc[k] - mx); sc[k] = e; ssum += e; }
        float inv = 1.0f / ssum;
        for (int k = 0; k < 13; ++k) sc[k] *= inv;
    }
    __syncthreads();
    for (int d = tid; d < HID; d += 256) {
        float v = __bfloat162float(Fb[((size_t)b * 13) * 320 + d]);
        #pragma unroll
        for (int k = 0; k < 13; ++k)
            v += sc[k] * __bfloat162float(Vf[((size_t)b * 13 + k) * 320 + d]);
        rowv[d] = v;
    }
    __syncthreads();
    float s1 = 0.f, s2 = 0.f;
    for (int d = tid; d < HID; d += 256) { float v = rowv[d]; s1 += v; s2 += v * v; }
    red[tid] = s1; red2[tid] = s2;
    __syncthreads();
    for (int s = 128; s > 0; s >>= 1) {
        if (tid < s) { red[tid] += red[tid + s]; red2[tid] += red2[tid + s]; }
        __syncthreads();
    }
    if (tid == 0) {
        float mean = red[0] / (float)HID;
        float var = red2[0] / (float)HID - mean * mean;
        mean_s = mean;
        inv_s = 1.0f / sqrtf(var + 1e-5f);
    }
    __syncthreads();
    for (int d = tid; d < 320; d += 256) {
        float v = 0.f;
        if (d < HID) v = (rowv[d] - mean_s) * inv_s * ln_g[d] + ln_b[d];
        out[(size_t)b * 320 + d] = __float2bfloat16(v);
    }
}

// ---------------------------------------------------------------------------
// final: out[b] = X[b,:512] . out_w + out_b   (fp32)
// ---------------------------------------------------------------------------
__global__ __launch_bounds__(256) void final_out_kernel(
    const float* __restrict__ X, const float* __restrict__ w,
    const float* __restrict__ bias, float* __restrict__ out)
{
    int b = blockIdx.x, tid = threadIdx.x;
    __shared__ float red[256];
    float p = X[(long)b * 512 + tid] * w[tid] + X[(long)b * 512 + tid + 256] * w[tid + 256];
    red[tid] = p;
    __syncthreads();
    for (int s = 128; s > 0; s >>= 1) {
        if (tid < s) red[tid] += red[tid + s];
        __syncthreads();
    }
    if (tid == 0) out[b] = red[0] + bias[0];
}

// ---------------------------------------------------------------------------
// Host launcher
// ---------------------------------------------------------------------------
extern "C" void kernel_launch(void* const* d_in, const int* in_sizes, int n_in,
                              void* d_out, int out_size, void* d_ws, size_t ws_size,
                              hipStream_t stream)
{
    const float* x        = (const float*)d_in[0];
    const int*   ei       = (const int*)d_in[1];
    const int*   batch    = (const int*)d_in[2];
    const int*   target   = (const int*)d_in[3];
    const float* embs     = (const float*)d_in[4];
    const float* W1       = (const float*)d_in[5];
    const float* b1       = (const float*)d_in[6];
    const float* W2       = (const float*)d_in[7];
    const float* b2       = (const float*)d_in[8];
    const float* W3       = (const float*)d_in[9];
    const float* b3       = (const float*)d_in[10];
    const float* fc_g1_w  = (const float*)d_in[11];
    const float* fc_g1_b  = (const float*)d_in[12];
    const float* fc_g2_w  = (const float*)d_in[13];
    const float* fc_g2_b  = (const float*)d_in[14];
    const float* emb_xt   = (const float*)d_in[15];
    const float* conv_w   = (const float*)d_in[16];
    const float* conv_b   = (const float*)d_in[17];
    const float* fc1xt_w  = (const float*)d_in[18];
    const float* fc1xt_b  = (const float*)d_in[19];
    const float* fg_lin_w = (const float*)d_in[20];
    const float* fg_lin_b = (const float*)d_in[21];
    const float* Wq       = (const float*)d_in[22];
    const float* Wk       = (const float*)d_in[23];
    const float* Wv       = (const float*)d_in[24];
    const float* ln_g     = (const float*)d_in[25];
    const float* ln_b     = (const float*)d_in[26];
    const float* fg_out_w = (const float*)d_in[27];
    const float* fg_out_b = (const float*)d_in[28];
    const float* fc1_w    = (const float*)d_in[29];
    const float* fc1_b    = (const float*)d_in[30];
    const float* fc2_w    = (const float*)d_in[31];
    const float* fc2_b    = (const float*)d_in[32];
    const float* out_w    = (const float*)d_in[33];
    const float* out_b    = (const float*)d_in[34];

    const int* src = ei;
    const int* dst = ei + NEDGES;
    typedef __hip_bfloat16 bf;

    // ---- workspace carve (256-B aligned bump allocator) ----
    char* p = (char*)d_ws;
    auto alloc = [&](size_t bytes) { char* r = p; p += (bytes + 255) & ~(size_t)255; return r; };
    bf*   xb      = (bf*)alloc((size_t)NNODES * 96 * 2);
    bf*   T       = (bf*)alloc((size_t)NNODES * 160 * 2);
    bf*   H       = (bf*)alloc((size_t)NNODES * 320 * 2);
    int*  deg     = (int*)alloc(NNODES * 4);                // reused as CSR cursor
    float* dis    = (float*)alloc(NNODES * 4);
    float* selfc  = (float*)alloc(NNODES * 4);
    int*  off     = (int*)alloc((NNODES + 1) * 4);
    int*  bsum    = (int*)alloc(512 * 4);
    int*  csr_src = (int*)alloc(NEDGES * 4);
    float* csr_w  = (float*)alloc(NEDGES * 4);
    bf*   w1t     = (bf*)alloc(78 * 96 * 2);
    bf*   w2t     = (bf*)alloc(156 * 96 * 2);
    bf*   w3t     = (bf*)alloc(312 * 160 * 2);
    bf*   fcg1t   = (bf*)alloc(1024 * 320 * 2);
    bf*   fcg2t   = (bf*)alloc(128 * 1024 * 2);
    bf*   fglint  = (bf*)alloc(300 * 160 * 2);
    bf*   wkt     = (bf*)alloc(300 * 320 * 2);
    bf*   wvt     = (bf*)alloc(300 * 320 * 2);
    bf*   wqt     = (bf*)alloc(300 * 320 * 2);
    bf*   fgoutt  = (bf*)alloc(128 * 320 * 2);
    bf*   fc1t    = (bf*)alloc(1024 * 384 * 2);
    bf*   fc2t    = (bf*)alloc(512 * 1024 * 2);
    bf*   fglwb   = (bf*)alloc(133 * 320 * 2);
    bf*   wk2t    = (bf*)alloc(300 * 160 * 2);
    bf*   wv2t    = (bf*)alloc(300 * 160 * 2);
    bf*   wq2t    = (bf*)alloc(300 * 160 * 2);
    float* bk2    = (float*)alloc(300 * 4);
    float* bv2    = (float*)alloc(300 * 4);
    float* bq2    = (float*)alloc(300 * 4);
    bf*   g       = (bf*)alloc((size_t)NB * 320 * 2);
    bf*   G1b     = (bf*)alloc((size_t)NB * 1024 * 2);
    bf*   embsb   = (bf*)alloc((size_t)NB * 13 * 160 * 2);
    bf*   Fbuf    = (bf*)alloc((size_t)NB * 13 * 320 * 2);
    bf*   Kbuf    = (bf*)alloc((size_t)NB * 13 * 320 * 2);
    bf*   Vbuf    = (bf*)alloc((size_t)NB * 13 * 320 * 2);
    bf*   Qbuf    = (bf*)alloc((size_t)NB * 320 * 2);
    bf*   f2row   = (bf*)alloc((size_t)NB * 320 * 2);
    float* xc     = (float*)alloc((size_t)NB * 384 * 4);
    bf*   xcb     = (bf*)alloc((size_t)NB * 384 * 2);
    float* F2     = (float*)alloc((size_t)NB * 512 * 4);
    bf*   cwt     = (bf*)alloc(256000 * 2);
    bf*   aggwb   = (bf*)alloc((size_t)NB * 6656 * 2);
    float* Wc     = (float*)alloc((size_t)6656 * 128 * 4);
    bf*   Wct     = (bf*)alloc((size_t)128 * 6656 * 2);
    float* xtb    = (float*)alloc(128 * 4);

    // ---- degree / norms / CSR ----
    hipMemsetAsync(deg, 0, NNODES * sizeof(int), stream);
    deg_kernel<<<(NEDGES + 255) / 256, 256, 0, stream>>>(dst, deg, NEDGES);
    scan_p1<<<NBLK1, 256, 0, stream>>>(deg, off, bsum, dis, selfc);
    scan_p2<<<1, 512, 0, stream>>>(bsum);
    scan_p3<<<NBLK1, 256, 0, stream>>>(off, bsum, deg);   // deg becomes cursor
    fill_csr_kernel<<<(NEDGES + 255) / 256, 256, 0, stream>>>(src, dst, dis, deg, csr_src, csr_w, NEDGES);

    // ---- weight transposes (one batched launch) + batched input converts ----
    {
        TBatch tb;
        const float* srcs[12] = {W1, W2, W3, fc_g1_w, fc_g2_w, fg_lin_w, Wk, Wv, Wq, fg_out_w, fc1_w, fc2_w};
        bf* dsts[12]          = {w1t, w2t, w3t, fcg1t, fcg2t, fglint, wkt, wvt, wqt, fgoutt, fc1t, fc2t};
        int Ks[12]    = {78, 78, 156, 312, 1024, 133, 300, 300, 300, 300, 384, 1024};
        int Ns[12]    = {78, 156, 312, 1024, 128, 300, 300, 300, 300, 128, 1024, 512};
        int Kpads[12] = {96, 96, 160, 320, 1024, 160, 320, 320, 320, 320, 384, 1024};
        int bs = 0;
        for (int i = 0; i < 12; ++i) {
            tb.src[i] = srcs[i]; tb.dst[i] = dsts[i];
            tb.K[i] = Ks[i]; tb.N[i] = Ns[i]; tb.Kpad[i] = Kpads[i];
            tb.bstart[i] = bs;
            bs += (int)(((long)Ns[i] * Kpads[i] + 255) / 256);
        }
        tb.bstart[12] = bs;
        transpose_batch_kernel<<<bs, 256, 0, stream>>>(tb);
    }
    {
        CBatch cb;
        cb.src[0] = x;       cb.dst[0] = xb;    cb.M[0] = NNODES;  cb.K[0] = 78;  cb.Kpad[0] = 96;
        cb.src[1] = embs;    cb.dst[1] = embsb; cb.M[1] = NB * 13; cb.K[1] = 133; cb.Kpad[1] = 160;
        cb.src[2] = fg_lin_w;cb.dst[2] = fglwb; cb.M[2] = 133;     cb.K[2] = 300; cb.Kpad[2] = 320;
        int bs = 0;
        for (int i = 0; i < 3; ++i) {
            cb.bstart[i] = bs;
            bs += (int)(((long)cb.M[i] * cb.Kpad[i] + 255) / 256);
        }
        cb.bstart[3] = bs;
        cvt_batch_kernel<<<bs, 256, 0, stream>>>(cb);
    }

    // ---- GCN layers: agg(input) -> XCD-swizzled 128x64 MFMA GEMM ----
    int agrid = (NNODES + 3) / 4;
    gcn_agg2<<<agrid, 256, 0, stream>>>(xb, off, csr_src, csr_w, selfc, T, 24);
    launch_gemm_swz(T, w1t, b1, H, NNODES, 78, 96, 96, 96, 96, stream);

    gcn_agg2<<<agrid, 256, 0, stream>>>(H, off, csr_src, csr_w, selfc, T, 24);
    launch_gemm_swz(T, w2t, b2, H, NNODES, 156, 96, 96, 160, 160, stream);

    gcn_agg2<<<agrid, 256, 0, stream>>>(H, off, csr_src, csr_w, selfc, T, 40);
    launch_gemm_swz(T, w3t, b3, H, NNODES, 312, 160, 160, 320, 320, stream);

    // ---- global max pool + graph MLP ----
    pool_max_bf16<<<NB, 256, 0, stream>>>(H, batch, g);
    launch_gemm_bf16(g, fcg1t, fc_g1_b, G1b, NB, 1024, 320, 320, 1024, 1024, 1, 1, 1, stream);
    launch_gemm_bf16(G1b, fcg2t, fc_g2_b, xc, NB, 128, 1024, 1024, 384, 128, 0, 0, 1, stream);

    // ---- conv branch (folded; split-K MFMA accumulates into xc cols 128..255) ----
    conv_transpose_kernel<<<(256000 + 255) / 256, 256, 0, stream>>>(conv_w, cwt);
    conv_agg_kernel<<<NB, 256, 0, stream>>>(cwt, target, aggwb);
    conv_wc_kernel<<<dim3(32, 208), 128, 0, stream>>>(emb_xt, fc1xt_w, Wc);
    transpose_cvt_kernel<<<((long)128 * 6656 + 255) / 256, 256, 0, stream>>>(Wc, Wct, 6656, 128, 6656);
    convb_fold2_kernel<<<128, 256, 0, stream>>>(fc1xt_w, conv_b, fc1xt_b, xtb);
    xc_convbias_kernel<<<(NB * 128 + 255) / 256, 256, 0, stream>>>(xtb, xc);
    launch_gemm_bf16(aggwb, Wct, nullptr, xc + 128, NB, 128, 6656, 6656, 384, 128, 0, 0, 8, stream);

    // ---- FG branch (batched folded-weight GEMMs) ----
    {
        GB3 p;
        for (int z = 0; z < 3; ++z) {
            p.g[z].Bt = fglwb; p.g[z].bias = nullptr;
            p.g[z].M = 300; p.g[z].N = 133; p.g[z].Kpad = 320;
            p.g[z].lda = 320; p.g[z].ldc = 160; p.g[z].Npad = 160;
        }
        p.g[0].A = wkt; p.g[0].C = wk2t;
        p.g[1].A = wvt; p.g[1].C = wv2t;
        p.g[2].A = wqt; p.g[2].C = wq2t;
        gemm_batch64_kernel<<<dim3(3, 5, 3), 256, 0, stream>>>(p);
    }
    {
        BF3 p;
        p.Wt[0] = wkt; p.out[0] = bk2;
        p.Wt[1] = wvt; p.out[1] = bv2;
        p.Wt[2] = wqt; p.out[2] = bq2;
        bias_fold3_kernel<<<900, 256, 0, stream>>>(fg_lin_b, p);
    }
    {
        GB3 p;
        p.g[0].A = embsb; p.g[0].Bt = fglint; p.g[0].bias = fg_lin_b; p.g[0].C = Fbuf;
        p.g[0].M = NB; p.g[0].N = 300; p.g[0].Kpad = 160; p.g[0].lda = 13 * 160;
        p.g[0].ldc = 13 * 320; p.g[0].Npad = 320;
        p.g[1] = p.g[0];
        p.g[1].Bt = wq2t; p.g[1].bias = bq2; p.g[1].C = Qbuf; p.g[1].ldc = 320;
        p.g[2] = p.g[1];
        gemm_batch64_kernel<<<dim3(5, 16, 2), 256, 0, stream>>>(p);
    }
    {
        GB3 p;
        p.g[0].A = embsb; p.g[0].Bt = wk2t; p.g[0].bias = bk2; p.g[0].C = Kbuf;
        p.g[0].M = NB * 13; p.g[0].N = 300; p.g[0].Kpad = 160; p.g[0].lda = 160;
        p.g[0].ldc = 320; p.g[0].Npad = 320;
        p.g[1] = p.g[0];
        p.g[1].Bt = wv2t; p.g[1].bias = bv2; p.g[1].C = Vbuf;
        p.g[2] = p.g[1];
        gemm_mtb_kernel<<<dim3(5, (NB * 13 + 127) / 128, 2), 256, 0, stream>>>(p);
    }
    attn_ln_kernel<<<NB, 256, 0, stream>>>(Fbuf, Kbuf, Vbuf, Qbuf, ln_g, ln_b, f2row);
    launch_gemm_bf16(f2row, fgoutt, fg_out_b, xc + 256, NB, 128, 320, 320, 384, 128, 0, 0, 1, stream);

    // ---- head ----
    cvt_pad_kernel<<<((long)NB * 384 + 255) / 256, 256, 0, stream>>>(xc, xcb, NB, 384, 384);
    launch_gemm_bf16(xcb, fc1t, fc1_b, G1b, NB, 1024, 384, 384, 1024, 1024, 1, 1, 1, stream);
    launch_gemm_bf16(G1b, fc2t, fc2_b, F2, NB, 512, 1024, 1024, 512, 512, 1, 0, 1, stream);
    final_out_kernel<<<NB, 256, 0, stream>>>(F2, out_w, out_b, (float*)d_out);
}